// Round 5
// baseline (253.171 us; speedup 1.0000x reference)
//
#include <hip/hip_runtime.h>
#include <math.h>

#define BETA 0.9f
#define THR 1.0f

constexpr int B_ = 64, T_ = 256, F_ = 1024, H_ = 512;
constexpr int M_ = B_ * T_;  // 16384 rows

typedef float f32x4 __attribute__((ext_vector_type(4)));
typedef short short8 __attribute__((ext_vector_type(8)));
typedef unsigned short us4 __attribute__((ext_vector_type(4)));
typedef unsigned short ushort_t;

// ---- bf16 helpers (RNE) ----------------------------------------------------
static __device__ __forceinline__ unsigned short f2bf(float x) {
    unsigned b = __builtin_bit_cast(unsigned, x);
    unsigned r = (b + 0x7FFFu + ((b >> 16) & 1u)) >> 16;
    return (unsigned short)r;
}
static __device__ __forceinline__ float bf2f(unsigned short u) {
    unsigned v = ((unsigned)u) << 16;
    return __builtin_bit_cast(float, v);
}
// XOR swizzle on 16B chunks within a 64B row; involution applied on the
// pre-swizzled GLDS source AND the ds_read (rule #21).
static __device__ __forceinline__ int swz(int r) {
    return ((r >> 2) & 3) ^ (r & 3);
}

#define GLDS(srcp, dstp)                                                      \
    __builtin_amdgcn_global_load_lds(                                         \
        (const __attribute__((address_space(1))) unsigned int*)(srcp),        \
        (__attribute__((address_space(3))) unsigned int*)(dstp), 16, 0, 0)

// ---------------------------------------------------------------------------
// Pure-GLDS split-bf16 MFMA GEMM (m97 structure: single buffer, 2 barriers).
// C[i,j] = sum_k A[i,k]*Bw[j,k] + bias[j].
// APL=2: A = hi/lo bf16 planes, 3 MFMA products.
// APL=1: A = single bf16 plane (exact spikes), 2 products.
// OUTMODE 0: f32 C. OUTMODE 1: hi/lo bf16 plane C.
// Tile 128x128, BK=32, 4 waves (2x2). Grid (N/128, M/128), nwg%8==0.
// ---------------------------------------------------------------------------
template <int APL, int RELU, int OUTMODE>
__global__ __launch_bounds__(256) void gemm_m97(
    const ushort_t* __restrict__ Ah, const ushort_t* __restrict__ Al,
    const ushort_t* __restrict__ Bh, const ushort_t* __restrict__ Bl,
    const float* __restrict__ bias, float* __restrict__ Cf,
    ushort_t* __restrict__ Ch, ushort_t* __restrict__ Cl, int N, int K) {
    constexpr int NP = APL + 2;
    __shared__ ushort_t lds[NP * 4096];

    const int tid = threadIdx.x;
    const int w = tid >> 6, l = tid & 63;
    // bijective XCD swizzle (nwg % 8 == 0 for all our grids)
    const int nwg = gridDim.x * gridDim.y;
    const int flat = blockIdx.y * gridDim.x + blockIdx.x;
    const int wg = (flat & 7) * (nwg >> 3) + (flat >> 3);
    const int n0 = (wg % gridDim.x) * 128;
    const int m0 = (wg / gridDim.x) * 128;
    const int wr = w >> 1, wc = w & 1;

    f32x4 acc[4][4];
#pragma unroll
    for (int mi = 0; mi < 4; ++mi)
#pragma unroll
        for (int ni = 0; ni < 4; ++ni) acc[mi][ni] = (f32x4){0.f, 0.f, 0.f, 0.f};

    const int c0 = l >> 4;
    for (int k0 = 0; k0 < K; k0 += 32) {
        __syncthreads();  // prior iteration's frag reads done
        // staging: NP planes x 8 segs of 1KB; pre-swizzled source addresses
#pragma unroll
        for (int j = 0; j < 2 * NP; ++j) {
            const int g = w * 2 * NP + j;  // 0 .. 8*NP-1
            const int p = g >> 3, seg = g & 7;
            const int r = seg * 16 + (l >> 2);
            const int ch = (l & 3) ^ swz(r);
            const ushort_t* pl;
            int rb;
            if constexpr (APL == 2) {
                pl = (p == 0) ? Ah : (p == 1) ? Al : (p == 2) ? Bh : Bl;
                rb = (p < 2) ? m0 : n0;
            } else {
                pl = (p == 0) ? Ah : (p == 1) ? Bh : Bl;
                rb = (p < 1) ? m0 : n0;
            }
            GLDS(pl + (size_t)(rb + r) * K + k0 + ch * 8,
                 &lds[p * 4096 + seg * 512]);
        }
        __syncthreads();  // drains vmcnt: tiles resident

        short8 ah[4], al[4], bh[4], bl[4];
#pragma unroll
        for (int mi = 0; mi < 4; ++mi) {
            const int r = wr * 64 + mi * 16 + (l & 15);
            const int off = r * 32 + ((c0 ^ swz(r)) * 8);
            ah[mi] = *(const short8*)&lds[off];
            if constexpr (APL == 2) al[mi] = *(const short8*)&lds[4096 + off];
        }
#pragma unroll
        for (int ni = 0; ni < 4; ++ni) {
            const int r = wc * 64 + ni * 16 + (l & 15);
            const int off = r * 32 + ((c0 ^ swz(r)) * 8);
            bh[ni] = *(const short8*)&lds[APL * 4096 + off];
            bl[ni] = *(const short8*)&lds[(APL + 1) * 4096 + off];
        }

#pragma unroll
        for (int mi = 0; mi < 4; ++mi)
#pragma unroll
            for (int ni = 0; ni < 4; ++ni) {
                acc[mi][ni] = __builtin_amdgcn_mfma_f32_16x16x32_bf16(
                    ah[mi], bh[ni], acc[mi][ni], 0, 0, 0);
                acc[mi][ni] = __builtin_amdgcn_mfma_f32_16x16x32_bf16(
                    ah[mi], bl[ni], acc[mi][ni], 0, 0, 0);
                if constexpr (APL == 2)
                    acc[mi][ni] = __builtin_amdgcn_mfma_f32_16x16x32_bf16(
                        al[mi], bh[ni], acc[mi][ni], 0, 0, 0);
            }
    }

    // epilogue: C/D layout col=lane&15, row=(lane>>4)*4+reg
#pragma unroll
    for (int ni = 0; ni < 4; ++ni) {
        const int col = n0 + wc * 64 + ni * 16 + (l & 15);
        const float bv = bias ? bias[col] : 0.f;
#pragma unroll
        for (int mi = 0; mi < 4; ++mi) {
            const int row0 = m0 + wr * 64 + mi * 16 + ((l >> 4) << 2);
#pragma unroll
            for (int r = 0; r < 4; ++r) {
                float v = acc[mi][ni][r] + bv;
                if (RELU) v = fmaxf(v, 0.f);
                const size_t idx = (size_t)(row0 + r) * N + col;
                if constexpr (OUTMODE == 0) {
                    Cf[idx] = v;
                } else {
                    const unsigned short h = f2bf(v);
                    Ch[idx] = h;
                    Cl[idx] = f2bf(v - bf2f(h));
                }
            }
        }
    }
}

// ---------------------------------------------------------------------------
// mil2+mil3+sigmoid fused (unchanged from R4; z from hi/lo planes).
// ---------------------------------------------------------------------------
__global__ __launch_bounds__(256) void mil2_dp(
    const ushort_t* __restrict__ zh, const ushort_t* __restrict__ zl,
    const ushort_t* __restrict__ Bh, const ushort_t* __restrict__ Bl,
    const float* __restrict__ Mb2, const float* __restrict__ Mw3,
    const float* __restrict__ Mb3, float* __restrict__ logits) {
    constexpr int BUFSZ = 2 * 4096;
    __shared__ ushort_t lds[2 * BUFSZ];
    constexpr int K = 512;

    const int tid = threadIdx.x;
    const int w = tid >> 6, l = tid & 63;
    const int m0 = blockIdx.x * 128;

    f32x4 acc[2][2];
#pragma unroll
    for (int mi = 0; mi < 2; ++mi)
#pragma unroll
        for (int ni = 0; ni < 2; ++ni) acc[mi][ni] = (f32x4){0.f, 0.f, 0.f, 0.f};

    auto stageA = [&](int buf, int k0) {
#pragma unroll
        for (int j = 0; j < 4; ++j) {
            const int g = w * 4 + j;
            const int p = g >> 3, seg = g & 7;
            const int r = seg * 16 + (l >> 2);
            const int ch = (l & 3) ^ swz(r);
            const ushort_t* src =
                (p ? zl : zh) + (size_t)(m0 + r) * K + k0 + ch * 8;
            GLDS(src, &lds[buf + p * 4096 + seg * 512]);
        }
    };

    stageA(0, 0);
    __syncthreads();

    const int c0 = l >> 4;
    for (int t = 0; t < 16; ++t) {
        const int cur = (t & 1) * BUFSZ;
        const int nxt = BUFSZ - cur;
        if (t < 15) stageA(nxt, (t + 1) * 32);
        const int k0 = t * 32;

        short8 ah[2], al[2], bh[2], bl[2];
#pragma unroll
        for (int mi = 0; mi < 2; ++mi) {
            const int r = w * 32 + mi * 16 + (l & 15);
            const int off = r * 32 + ((c0 ^ swz(r)) * 8);
            ah[mi] = *(const short8*)&lds[cur + off];
            al[mi] = *(const short8*)&lds[cur + 4096 + off];
        }
#pragma unroll
        for (int ni = 0; ni < 2; ++ni) {
            const size_t boff = (size_t)(ni * 16 + (l & 15)) * K + k0 + c0 * 8;
            bh[ni] = *(const short8*)&Bh[boff];
            bl[ni] = *(const short8*)&Bl[boff];
        }
#pragma unroll
        for (int mi = 0; mi < 2; ++mi)
#pragma unroll
            for (int ni = 0; ni < 2; ++ni) {
                acc[mi][ni] = __builtin_amdgcn_mfma_f32_16x16x32_bf16(
                    ah[mi], bh[ni], acc[mi][ni], 0, 0, 0);
                acc[mi][ni] = __builtin_amdgcn_mfma_f32_16x16x32_bf16(
                    ah[mi], bl[ni], acc[mi][ni], 0, 0, 0);
                acc[mi][ni] = __builtin_amdgcn_mfma_f32_16x16x32_bf16(
                    al[mi], bh[ni], acc[mi][ni], 0, 0, 0);
            }
        __syncthreads();
    }

    float mw3v[2], mb2v[2];
#pragma unroll
    for (int ni = 0; ni < 2; ++ni) {
        const int j = ni * 16 + (l & 15);
        mw3v[ni] = Mw3[j];
        mb2v[ni] = Mb2[j];
    }
    const float b3 = Mb3[0];
#pragma unroll
    for (int mi = 0; mi < 2; ++mi) {
        float p[4];
#pragma unroll
        for (int r = 0; r < 4; ++r) {
            float s = 0.f;
#pragma unroll
            for (int ni = 0; ni < 2; ++ni)
                s += (acc[mi][ni][r] + mb2v[ni]) * mw3v[ni];
            p[r] = s;
        }
#pragma unroll
        for (int off = 1; off <= 8; off <<= 1)
#pragma unroll
            for (int r = 0; r < 4; ++r) p[r] += __shfl_xor(p[r], off);
        if ((l & 15) == 0) {
#pragma unroll
            for (int r = 0; r < 4; ++r) {
                const int row = m0 + w * 32 + mi * 16 + ((l >> 4) << 2) + r;
                logits[row] = 1.f / (1.f + expf(-(p[r] + b3)));
            }
        }
    }
}

// ---------------------------------------------------------------------------
// Generic f32 -> hi/lo bf16 plane split (grid-stride, f32x4).
// ---------------------------------------------------------------------------
__global__ __launch_bounds__(256) void split_planes(const float* __restrict__ x,
                                                    ushort_t* __restrict__ hi,
                                                    ushort_t* __restrict__ lo,
                                                    int n4) {
    int i = blockIdx.x * 256 + threadIdx.x;
    const int stride = gridDim.x * 256;
    for (; i < n4; i += stride) {
        f32x4 v = ((const f32x4*)x)[i];
        us4 h, ll;
#pragma unroll
        for (int e = 0; e < 4; ++e) {
            const unsigned short hb = f2bf(v[e]);
            h[e] = hb;
            ll[e] = f2bf(v[e] - bf2f(hb));
        }
        ((us4*)hi)[i] = h;
        ((us4*)lo)[i] = ll;
    }
}

// ---------------------------------------------------------------------------
// Wf [512,1024] f32 -> WfT hi/lo planes [1024,512].
// ---------------------------------------------------------------------------
__global__ __launch_bounds__(256) void transpose_split(
    const float* __restrict__ Wf, ushort_t* __restrict__ th,
    ushort_t* __restrict__ tl) {
    __shared__ float tile[32][33];
    const int tx = threadIdx.x & 31;
    const int ty = threadIdx.x >> 5;  // 0..7
    const int k0 = blockIdx.x * 32;   // 0..1023 (cols of Wf)
    const int i0 = blockIdx.y * 32;   // 0..511  (rows of Wf)
#pragma unroll
    for (int e = 0; e < 4; ++e) {
        const int i = ty + e * 8;
        tile[i][tx] = Wf[(size_t)(i0 + i) * 1024 + k0 + tx];
    }
    __syncthreads();
#pragma unroll
    for (int e = 0; e < 4; ++e) {
        const int kk = ty + e * 8;
        const float v = tile[tx][kk];
        const unsigned short h = f2bf(v);
        th[(size_t)(k0 + kk) * 512 + i0 + tx] = h;
        tl[(size_t)(k0 + kk) * 512 + i0 + tx] = f2bf(v - bf2f(h));
    }
}

// ---------------------------------------------------------------------------
// bc[j] = b1[j] + sum_i W1[j,i]*bf[i]   (fp32 exact; tiny)
// ---------------------------------------------------------------------------
__global__ __launch_bounds__(256) void combine_bias(const float* __restrict__ W1,
                                                    const float* __restrict__ bfv,
                                                    const float* __restrict__ b1,
                                                    float* __restrict__ bc) {
    const int j = blockIdx.x * 256 + threadIdx.x;  // 512 total
    float a = b1[j];
    const float* row = W1 + (size_t)j * 512;
    for (int i = 0; i < 512; ++i) a += row[i] * bfv[i];
    bc[j] = a;
}

// ---------------------------------------------------------------------------
// snntorch Leaky (subtract reset) scan; x f32 [B,T,H] -> spikes bf16.
// ---------------------------------------------------------------------------
__global__ __launch_bounds__(256) void leaky_scan(const float* __restrict__ x,
                                                  ushort_t* __restrict__ s) {
    const int idx = blockIdx.x * 256 + threadIdx.x;
    const int b = idx >> 9;
    const int h = idx & (H_ - 1);
    const float* xp = x + (size_t)b * T_ * H_ + h;
    ushort_t* sp = s + (size_t)b * T_ * H_ + h;
    float m = 0.f;
#pragma unroll 8
    for (int t = 0; t < T_; ++t) {
        const float xv = xp[(size_t)t * H_];
        const float r = (m - THR > 0.f) ? THR : 0.f;
        m = BETA * m + xv - r;
        sp[(size_t)t * H_] = (m - THR > 0.f) ? (ushort_t)0x3F80 : (ushort_t)0;
    }
}

// ---------------------------------------------------------------------------
// Top-17 mean per batch row. One wave per row.
// ---------------------------------------------------------------------------
__global__ __launch_bounds__(64) void topk_mean(const float* __restrict__ logits,
                                                float* __restrict__ out) {
    const int b = blockIdx.x;
    const int lane = threadIdx.x;
    float v[4];
#pragma unroll
    for (int i = 0; i < 4; ++i) v[i] = logits[b * T_ + lane + i * 64];
    float sum = 0.f;
    for (int iter = 0; iter < 17; ++iter) {
        float mv = v[0];
        int mslot = 0;
#pragma unroll
        for (int i = 1; i < 4; ++i)
            if (v[i] > mv) { mv = v[i]; mslot = i; }
        float bv = mv;
        int bl = lane, bs = mslot;
#pragma unroll
        for (int off = 32; off >= 1; off >>= 1) {
            const float ov = __shfl_xor(bv, off);
            const int ol = __shfl_xor(bl, off);
            const int os = __shfl_xor(bs, off);
            if (ov > bv || (ov == bv && ol < bl)) { bv = ov; bl = ol; bs = os; }
        }
        sum += bv;
        if (lane == bl) v[bs] = -1e30f;
    }
    if (lane == 0) out[b] = sum * (1.f / 17.f);
}

// ---------------------------------------------------------------------------
// Orchestration (GEMM2 fused away via Wc = W1@Wf):
//   planes: W1,W2,Mw1,Mw2 split; WfT planes; f_f planes; bc = W1@bf+b1
//   (wch,wcl) <- gemm(W1planes @ WfT^T)            [combine, 32 wg]
//   xbuf <- gemm(ff planes @ Wc^T) + bc            [x1 direct]
//   sbuf <- scan(xbuf); xbuf <- gemm(sbuf @ W2^T)
//   sbuf <- scan(xbuf); (zh,zl) <- gemm(sbuf @ Mw1^T, relu)
//   logits <- mil2_dp; out <- topk
// Overlays: sbuf->none; zh/zl overlay ffh region (dead after x1-GEMM).
// ---------------------------------------------------------------------------
extern "C" void kernel_launch(void* const* d_in, const int* in_sizes, int n_in,
                              void* d_out, int out_size, void* d_ws, size_t ws_size,
                              hipStream_t stream) {
    const float* f_f = (const float*)d_in[0];
    const float* Wf  = (const float*)d_in[2];
    const float* bf  = (const float*)d_in[3];
    const float* W1  = (const float*)d_in[4];
    const float* b1  = (const float*)d_in[5];
    const float* W2  = (const float*)d_in[6];
    const float* b2  = (const float*)d_in[7];
    const float* Mw1 = (const float*)d_in[8];
    const float* Mb1 = (const float*)d_in[9];
    const float* Mw2 = (const float*)d_in[10];
    const float* Mb2 = (const float*)d_in[11];
    const float* Mw3 = (const float*)d_in[12];
    const float* Mb3 = (const float*)d_in[13];
    float* out = (float*)d_out;

    char* ws = (char*)d_ws;
    const size_t NEf = (size_t)M_ * F_;  // 16.78M elems (f_f planes)
    const size_t NE = (size_t)M_ * H_;   // 8.39M elems
    ushort_t* ffh = (ushort_t*)ws;                       // 33.55 MB
    ushort_t* ffl = ffh + NEf;                           // 33.55 MB
    float* xbuf = (float*)(ffl + NEf);                   // 33.55 MB
    ushort_t* sbuf = (ushort_t*)(xbuf + NE);             // 16.78 MB
    ushort_t* w1h = sbuf + NE;
    ushort_t* w1l = w1h + 262144;
    ushort_t* w2h = w1l + 262144;
    ushort_t* w2l = w2h + 262144;
    ushort_t* m1h = w2l + 262144;
    ushort_t* m1l = m1h + 262144;
    ushort_t* m2h = m1l + 262144;
    ushort_t* m2l = m2h + 16384;
    ushort_t* wfTh = m2l + 16384;                        // [1024,512]
    ushort_t* wfTl = wfTh + 524288;
    ushort_t* wch = wfTl + 524288;                       // [512,1024]
    ushort_t* wcl = wch + 524288;
    float* bc = (float*)(wcl + 524288);
    float* logits = bc + 512 + 128;
    ushort_t* zh = ffh;       // overlay: f_f planes dead after x1-GEMM
    ushort_t* zl = ffh + NE;  // both fit inside ffh's NEf region

    const dim3 blk(256);

    split_planes<<<dim3(256), blk, 0, stream>>>(W1, w1h, w1l, 65536);
    split_planes<<<dim3(256), blk, 0, stream>>>(W2, w2h, w2l, 65536);
    split_planes<<<dim3(256), blk, 0, stream>>>(Mw1, m1h, m1l, 65536);
    split_planes<<<dim3(16), blk, 0, stream>>>(Mw2, m2h, m2l, 4096);
    transpose_split<<<dim3(32, 16), blk, 0, stream>>>(Wf, wfTh, wfTl);
    split_planes<<<dim3(2048), blk, 0, stream>>>(f_f, ffh, ffl, 4194304);
    combine_bias<<<dim3(2), blk, 0, stream>>>(W1, bf, b1, bc);

    // Wc = W1 @ Wf  (A = W1 planes [512,512], B = WfT planes [1024,512])
    gemm_m97<2, 0, 1><<<dim3(8, 4), blk, 0, stream>>>(
        w1h, w1l, wfTh, wfTl, nullptr, nullptr, wch, wcl, 1024, 512);
    // x1 = f_f @ Wc^T + bc
    gemm_m97<2, 0, 0><<<dim3(4, 128), blk, 0, stream>>>(
        ffh, ffl, wch, wcl, bc, xbuf, nullptr, nullptr, 512, 1024);
    leaky_scan<<<dim3((B_ * H_) / 256), blk, 0, stream>>>(xbuf, sbuf);
    gemm_m97<1, 0, 0><<<dim3(4, 128), blk, 0, stream>>>(
        sbuf, nullptr, w2h, w2l, b2, xbuf, nullptr, nullptr, 512, 512);
    leaky_scan<<<dim3((B_ * H_) / 256), blk, 0, stream>>>(xbuf, sbuf);
    gemm_m97<1, 1, 1><<<dim3(4, 128), blk, 0, stream>>>(
        sbuf, nullptr, m1h, m1l, Mb1, nullptr, zh, zl, 512, 512);
    mil2_dp<<<dim3(M_ / 128), blk, 0, stream>>>(zh, zl, m2h, m2l, Mb2, Mw3,
                                                Mb3, logits);
    topk_mean<<<dim3(B_), dim3(64), 0, stream>>>(logits, out);
}

// Round 6
// 215.360 us; speedup vs baseline: 1.1756x; 1.1756x over previous
//
#include <hip/hip_runtime.h>
#include <math.h>

#define BETA 0.9f
#define THR 1.0f

constexpr int B_ = 64, T_ = 256, F_ = 1024, H_ = 512;
constexpr int M_ = B_ * T_;  // 16384 rows

typedef float f32x4 __attribute__((ext_vector_type(4)));
typedef short short8 __attribute__((ext_vector_type(8)));
typedef _Float16 half8 __attribute__((ext_vector_type(8)));
typedef unsigned short us4 __attribute__((ext_vector_type(4)));
typedef unsigned short ushort_t;

// ---- bf16 helpers (RNE) ----------------------------------------------------
static __device__ __forceinline__ unsigned short f2bf(float x) {
    unsigned b = __builtin_bit_cast(unsigned, x);
    unsigned r = (b + 0x7FFFu + ((b >> 16) & 1u)) >> 16;
    return (unsigned short)r;
}
static __device__ __forceinline__ float bf2f(unsigned short u) {
    unsigned v = ((unsigned)u) << 16;
    return __builtin_bit_cast(float, v);
}
// ---- f16 helpers (v_cvt_f16_f32, RNE) --------------------------------------
static __device__ __forceinline__ unsigned short f2h(float x) {
    _Float16 h = (_Float16)x;
    return __builtin_bit_cast(unsigned short, h);
}
static __device__ __forceinline__ float h2f(unsigned short u) {
    return (float)__builtin_bit_cast(_Float16, u);
}
// XOR swizzle on 16B chunks within a 64B row; involution applied on the
// pre-swizzled GLDS source AND the ds_read (rule #21).
static __device__ __forceinline__ int swz(int r) {
    return ((r >> 2) & 3) ^ (r & 3);
}

#define GLDS(srcp, dstp)                                                      \
    __builtin_amdgcn_global_load_lds(                                         \
        (const __attribute__((address_space(1))) unsigned int*)(srcp),        \
        (__attribute__((address_space(3))) unsigned int*)(dstp), 16, 0, 0)

// ---------------------------------------------------------------------------
// Split-f16 MFMA GEMM (m97 structure). C = A @ Bw^T + bias.
// APL=2: A = hi/lo f16 planes, B = single f16 plane -> 2 products.
// APL=1: A = single f16 plane (exact spikes), B single -> 1 product.
// OUTMODE 0: f32 C. OUTMODE 1: bf16 hi/lo plane C (for mil2).
// Tile 128x128, BK=32, 4 waves (2x2). Grid (N/128, M/128), nwg%8==0.
// ---------------------------------------------------------------------------
template <int APL, int RELU, int OUTMODE>
__global__ __launch_bounds__(256) void gemm_f16(
    const ushort_t* __restrict__ Ah, const ushort_t* __restrict__ Al,
    const ushort_t* __restrict__ Bp, const float* __restrict__ bias,
    float* __restrict__ Cf, ushort_t* __restrict__ Ch,
    ushort_t* __restrict__ Cl, int N, int K) {
    constexpr int NP = APL + 1;
    __shared__ ushort_t lds[NP * 4096];

    const int tid = threadIdx.x;
    const int w = tid >> 6, l = tid & 63;
    const int nwg = gridDim.x * gridDim.y;
    const int flat = blockIdx.y * gridDim.x + blockIdx.x;
    const int wg = (flat & 7) * (nwg >> 3) + (flat >> 3);
    const int n0 = (wg % gridDim.x) * 128;
    const int m0 = (wg / gridDim.x) * 128;
    const int wr = w >> 1, wc = w & 1;

    f32x4 acc[4][4];
#pragma unroll
    for (int mi = 0; mi < 4; ++mi)
#pragma unroll
        for (int ni = 0; ni < 4; ++ni) acc[mi][ni] = (f32x4){0.f, 0.f, 0.f, 0.f};

    const int c0 = l >> 4;
    for (int k0 = 0; k0 < K; k0 += 32) {
        __syncthreads();
#pragma unroll
        for (int j = 0; j < 2 * NP; ++j) {
            const int g = w * 2 * NP + j;  // 0 .. 8*NP-1
            const int p = g >> 3, seg = g & 7;
            const int r = seg * 16 + (l >> 2);
            const int ch = (l & 3) ^ swz(r);
            const ushort_t* pl;
            int rb;
            if constexpr (APL == 2) {
                pl = (p == 0) ? Ah : (p == 1) ? Al : Bp;
                rb = (p < 2) ? m0 : n0;
            } else {
                pl = (p == 0) ? Ah : Bp;
                rb = (p < 1) ? m0 : n0;
            }
            GLDS(pl + (size_t)(rb + r) * K + k0 + ch * 8,
                 &lds[p * 4096 + seg * 512]);
        }
        __syncthreads();

        half8 ah[4], al[4], bb[4];
#pragma unroll
        for (int mi = 0; mi < 4; ++mi) {
            const int r = wr * 64 + mi * 16 + (l & 15);
            const int off = r * 32 + ((c0 ^ swz(r)) * 8);
            ah[mi] = __builtin_bit_cast(half8, *(const short8*)&lds[off]);
            if constexpr (APL == 2)
                al[mi] =
                    __builtin_bit_cast(half8, *(const short8*)&lds[4096 + off]);
        }
#pragma unroll
        for (int ni = 0; ni < 4; ++ni) {
            const int r = wc * 64 + ni * 16 + (l & 15);
            const int off = r * 32 + ((c0 ^ swz(r)) * 8);
            bb[ni] = __builtin_bit_cast(
                half8, *(const short8*)&lds[APL * 4096 + off]);
        }

#pragma unroll
        for (int mi = 0; mi < 4; ++mi)
#pragma unroll
            for (int ni = 0; ni < 4; ++ni) {
                acc[mi][ni] = __builtin_amdgcn_mfma_f32_16x16x32_f16(
                    ah[mi], bb[ni], acc[mi][ni], 0, 0, 0);
                if constexpr (APL == 2)
                    acc[mi][ni] = __builtin_amdgcn_mfma_f32_16x16x32_f16(
                        al[mi], bb[ni], acc[mi][ni], 0, 0, 0);
            }
    }

    // epilogue: C/D layout col=lane&15, row=(lane>>4)*4+reg (dtype-indep)
#pragma unroll
    for (int ni = 0; ni < 4; ++ni) {
        const int col = n0 + wc * 64 + ni * 16 + (l & 15);
        const float bv = bias ? bias[col] : 0.f;
#pragma unroll
        for (int mi = 0; mi < 4; ++mi) {
            const int row0 = m0 + wr * 64 + mi * 16 + ((l >> 4) << 2);
#pragma unroll
            for (int r = 0; r < 4; ++r) {
                float v = acc[mi][ni][r] + bv;
                if (RELU) v = fmaxf(v, 0.f);
                const size_t idx = (size_t)(row0 + r) * N + col;
                if constexpr (OUTMODE == 0) {
                    Cf[idx] = v;
                } else {
                    const unsigned short h = f2bf(v);
                    Ch[idx] = h;
                    Cl[idx] = f2bf(v - bf2f(h));
                }
            }
        }
    }
}

// ---------------------------------------------------------------------------
// Split-bf16 3-product GEMM (m97 structure) — used only for Wc = W1 @ Wf.
// OUTMODE 2: single f16 plane out.
// ---------------------------------------------------------------------------
__global__ __launch_bounds__(256) void gemm_bf16_wc(
    const ushort_t* __restrict__ Ah, const ushort_t* __restrict__ Al,
    const ushort_t* __restrict__ Bh, const ushort_t* __restrict__ Bl,
    ushort_t* __restrict__ Cout, int N, int K) {
    __shared__ ushort_t lds[4 * 4096];

    const int tid = threadIdx.x;
    const int w = tid >> 6, l = tid & 63;
    const int nwg = gridDim.x * gridDim.y;
    const int flat = blockIdx.y * gridDim.x + blockIdx.x;
    const int wg = (flat & 7) * (nwg >> 3) + (flat >> 3);
    const int n0 = (wg % gridDim.x) * 128;
    const int m0 = (wg / gridDim.x) * 128;
    const int wr = w >> 1, wc = w & 1;

    f32x4 acc[4][4];
#pragma unroll
    for (int mi = 0; mi < 4; ++mi)
#pragma unroll
        for (int ni = 0; ni < 4; ++ni) acc[mi][ni] = (f32x4){0.f, 0.f, 0.f, 0.f};

    const int c0 = l >> 4;
    for (int k0 = 0; k0 < K; k0 += 32) {
        __syncthreads();
#pragma unroll
        for (int j = 0; j < 8; ++j) {
            const int g = w * 8 + j;
            const int p = g >> 3, seg = g & 7;
            const int r = seg * 16 + (l >> 2);
            const int ch = (l & 3) ^ swz(r);
            const ushort_t* pl = (p == 0) ? Ah : (p == 1) ? Al : (p == 2) ? Bh : Bl;
            const int rb = (p < 2) ? m0 : n0;
            GLDS(pl + (size_t)(rb + r) * K + k0 + ch * 8,
                 &lds[p * 4096 + seg * 512]);
        }
        __syncthreads();

        short8 ah[4], al[4], bh[4], bl[4];
#pragma unroll
        for (int mi = 0; mi < 4; ++mi) {
            const int r = wr * 64 + mi * 16 + (l & 15);
            const int off = r * 32 + ((c0 ^ swz(r)) * 8);
            ah[mi] = *(const short8*)&lds[off];
            al[mi] = *(const short8*)&lds[4096 + off];
        }
#pragma unroll
        for (int ni = 0; ni < 4; ++ni) {
            const int r = wc * 64 + ni * 16 + (l & 15);
            const int off = r * 32 + ((c0 ^ swz(r)) * 8);
            bh[ni] = *(const short8*)&lds[8192 + off];
            bl[ni] = *(const short8*)&lds[12288 + off];
        }
#pragma unroll
        for (int mi = 0; mi < 4; ++mi)
#pragma unroll
            for (int ni = 0; ni < 4; ++ni) {
                acc[mi][ni] = __builtin_amdgcn_mfma_f32_16x16x32_bf16(
                    ah[mi], bh[ni], acc[mi][ni], 0, 0, 0);
                acc[mi][ni] = __builtin_amdgcn_mfma_f32_16x16x32_bf16(
                    ah[mi], bl[ni], acc[mi][ni], 0, 0, 0);
                acc[mi][ni] = __builtin_amdgcn_mfma_f32_16x16x32_bf16(
                    al[mi], bh[ni], acc[mi][ni], 0, 0, 0);
            }
    }

#pragma unroll
    for (int ni = 0; ni < 4; ++ni) {
        const int col = n0 + wc * 64 + ni * 16 + (l & 15);
#pragma unroll
        for (int mi = 0; mi < 4; ++mi) {
            const int row0 = m0 + wr * 64 + mi * 16 + ((l >> 4) << 2);
#pragma unroll
            for (int r = 0; r < 4; ++r)
                Cout[(size_t)(row0 + r) * N + col] = f2h(acc[mi][ni][r]);
        }
    }
}

// ---------------------------------------------------------------------------
// mil2+mil3+sigmoid fused (bf16 split path; z from hi/lo planes). Unchanged.
// ---------------------------------------------------------------------------
__global__ __launch_bounds__(256) void mil2_dp(
    const ushort_t* __restrict__ zh, const ushort_t* __restrict__ zl,
    const ushort_t* __restrict__ Bh, const ushort_t* __restrict__ Bl,
    const float* __restrict__ Mb2, const float* __restrict__ Mw3,
    const float* __restrict__ Mb3, float* __restrict__ logits) {
    constexpr int BUFSZ = 2 * 4096;
    __shared__ ushort_t lds[2 * BUFSZ];
    constexpr int K = 512;

    const int tid = threadIdx.x;
    const int w = tid >> 6, l = tid & 63;
    const int m0 = blockIdx.x * 128;

    f32x4 acc[2][2];
#pragma unroll
    for (int mi = 0; mi < 2; ++mi)
#pragma unroll
        for (int ni = 0; ni < 2; ++ni) acc[mi][ni] = (f32x4){0.f, 0.f, 0.f, 0.f};

    auto stageA = [&](int buf, int k0) {
#pragma unroll
        for (int j = 0; j < 4; ++j) {
            const int g = w * 4 + j;
            const int p = g >> 3, seg = g & 7;
            const int r = seg * 16 + (l >> 2);
            const int ch = (l & 3) ^ swz(r);
            const ushort_t* src =
                (p ? zl : zh) + (size_t)(m0 + r) * K + k0 + ch * 8;
            GLDS(src, &lds[buf + p * 4096 + seg * 512]);
        }
    };

    stageA(0, 0);
    __syncthreads();

    const int c0 = l >> 4;
    for (int t = 0; t < 16; ++t) {
        const int cur = (t & 1) * BUFSZ;
        const int nxt = BUFSZ - cur;
        if (t < 15) stageA(nxt, (t + 1) * 32);
        const int k0 = t * 32;

        short8 ah[2], al[2], bh[2], bl[2];
#pragma unroll
        for (int mi = 0; mi < 2; ++mi) {
            const int r = w * 32 + mi * 16 + (l & 15);
            const int off = r * 32 + ((c0 ^ swz(r)) * 8);
            ah[mi] = *(const short8*)&lds[cur + off];
            al[mi] = *(const short8*)&lds[cur + 4096 + off];
        }
#pragma unroll
        for (int ni = 0; ni < 2; ++ni) {
            const size_t boff = (size_t)(ni * 16 + (l & 15)) * K + k0 + c0 * 8;
            bh[ni] = *(const short8*)&Bh[boff];
            bl[ni] = *(const short8*)&Bl[boff];
        }
#pragma unroll
        for (int mi = 0; mi < 2; ++mi)
#pragma unroll
            for (int ni = 0; ni < 2; ++ni) {
                acc[mi][ni] = __builtin_amdgcn_mfma_f32_16x16x32_bf16(
                    ah[mi], bh[ni], acc[mi][ni], 0, 0, 0);
                acc[mi][ni] = __builtin_amdgcn_mfma_f32_16x16x32_bf16(
                    ah[mi], bl[ni], acc[mi][ni], 0, 0, 0);
                acc[mi][ni] = __builtin_amdgcn_mfma_f32_16x16x32_bf16(
                    al[mi], bh[ni], acc[mi][ni], 0, 0, 0);
            }
        __syncthreads();
    }

    float mw3v[2], mb2v[2];
#pragma unroll
    for (int ni = 0; ni < 2; ++ni) {
        const int j = ni * 16 + (l & 15);
        mw3v[ni] = Mw3[j];
        mb2v[ni] = Mb2[j];
    }
    const float b3 = Mb3[0];
#pragma unroll
    for (int mi = 0; mi < 2; ++mi) {
        float p[4];
#pragma unroll
        for (int r = 0; r < 4; ++r) {
            float s = 0.f;
#pragma unroll
            for (int ni = 0; ni < 2; ++ni)
                s += (acc[mi][ni][r] + mb2v[ni]) * mw3v[ni];
            p[r] = s;
        }
#pragma unroll
        for (int off = 1; off <= 8; off <<= 1)
#pragma unroll
            for (int r = 0; r < 4; ++r) p[r] += __shfl_xor(p[r], off);
        if ((l & 15) == 0) {
#pragma unroll
            for (int r = 0; r < 4; ++r) {
                const int row = m0 + w * 32 + mi * 16 + ((l >> 4) << 2) + r;
                logits[row] = 1.f / (1.f + expf(-(p[r] + b3)));
            }
        }
    }
}

// ---------------------------------------------------------------------------
// f32 -> hi/lo f16 plane split (grid-stride, f32x4).
// ---------------------------------------------------------------------------
__global__ __launch_bounds__(256) void split_planes_f16(
    const float* __restrict__ x, ushort_t* __restrict__ hi,
    ushort_t* __restrict__ lo, int n4) {
    int i = blockIdx.x * 256 + threadIdx.x;
    const int stride = gridDim.x * 256;
    for (; i < n4; i += stride) {
        f32x4 v = ((const f32x4*)x)[i];
        us4 h, ll;
#pragma unroll
        for (int e = 0; e < 4; ++e) {
            const unsigned short hb = f2h(v[e]);
            h[e] = hb;
            ll[e] = f2h(v[e] - h2f(hb));
        }
        ((us4*)hi)[i] = h;
        ((us4*)lo)[i] = ll;
    }
}

// ---------------------------------------------------------------------------
// f32 -> single f16 plane round (for W2, Mw1).
// ---------------------------------------------------------------------------
__global__ __launch_bounds__(256) void round_f16(const float* __restrict__ x,
                                                 ushort_t* __restrict__ o,
                                                 int n4) {
    int i = blockIdx.x * 256 + threadIdx.x;
    const int stride = gridDim.x * 256;
    for (; i < n4; i += stride) {
        f32x4 v = ((const f32x4*)x)[i];
        us4 h;
#pragma unroll
        for (int e = 0; e < 4; ++e) h[e] = f2h(v[e]);
        ((us4*)o)[i] = h;
    }
}

// ---------------------------------------------------------------------------
// f32 -> hi/lo bf16 plane split (W1, Mw2).
// ---------------------------------------------------------------------------
__global__ __launch_bounds__(256) void split_planes_bf(
    const float* __restrict__ x, ushort_t* __restrict__ hi,
    ushort_t* __restrict__ lo, int n4) {
    int i = blockIdx.x * 256 + threadIdx.x;
    const int stride = gridDim.x * 256;
    for (; i < n4; i += stride) {
        f32x4 v = ((const f32x4*)x)[i];
        us4 h, ll;
#pragma unroll
        for (int e = 0; e < 4; ++e) {
            const unsigned short hb = f2bf(v[e]);
            h[e] = hb;
            ll[e] = f2bf(v[e] - bf2f(hb));
        }
        ((us4*)hi)[i] = h;
        ((us4*)lo)[i] = ll;
    }
}

// ---------------------------------------------------------------------------
// Wf [512,1024] f32 -> WfT hi/lo bf16 planes [1024,512].
// ---------------------------------------------------------------------------
__global__ __launch_bounds__(256) void transpose_split(
    const float* __restrict__ Wf, ushort_t* __restrict__ th,
    ushort_t* __restrict__ tl) {
    __shared__ float tile[32][33];
    const int tx = threadIdx.x & 31;
    const int ty = threadIdx.x >> 5;  // 0..7
    const int k0 = blockIdx.x * 32;
    const int i0 = blockIdx.y * 32;
#pragma unroll
    for (int e = 0; e < 4; ++e) {
        const int i = ty + e * 8;
        tile[i][tx] = Wf[(size_t)(i0 + i) * 1024 + k0 + tx];
    }
    __syncthreads();
#pragma unroll
    for (int e = 0; e < 4; ++e) {
        const int kk = ty + e * 8;
        const float v = tile[tx][kk];
        const unsigned short h = f2bf(v);
        th[(size_t)(k0 + kk) * 512 + i0 + tx] = h;
        tl[(size_t)(k0 + kk) * 512 + i0 + tx] = f2bf(v - bf2f(h));
    }
}

// ---------------------------------------------------------------------------
// bc[j] = b1[j] + sum_i W1[j,i]*bf[i]. One WAVE per j (coalesced), 4 waves/blk.
// ---------------------------------------------------------------------------
__global__ __launch_bounds__(256) void combine_bias(const float* __restrict__ W1,
                                                    const float* __restrict__ bfv,
                                                    const float* __restrict__ b1,
                                                    float* __restrict__ bc) {
    const int w = threadIdx.x >> 6, l = threadIdx.x & 63;
    const int j = blockIdx.x * 4 + w;  // 128 blocks x 4 waves = 512
    const float* row = W1 + (size_t)j * 512;
    float a = 0.f;
#pragma unroll
    for (int i = 0; i < 8; ++i) a += row[l + i * 64] * bfv[l + i * 64];
#pragma unroll
    for (int off = 32; off >= 1; off >>= 1) a += __shfl_xor(a, off);
    if (l == 0) bc[j] = a + b1[j];
}

// ---------------------------------------------------------------------------
// snntorch Leaky (subtract reset) scan; x f32 [B,T,H] -> spikes f16 (0x3C00).
// ---------------------------------------------------------------------------
__global__ __launch_bounds__(256) void leaky_scan(const float* __restrict__ x,
                                                  ushort_t* __restrict__ s) {
    const int idx = blockIdx.x * 256 + threadIdx.x;
    const int b = idx >> 9;
    const int h = idx & (H_ - 1);
    const float* xp = x + (size_t)b * T_ * H_ + h;
    ushort_t* sp = s + (size_t)b * T_ * H_ + h;
    float m = 0.f;
#pragma unroll 8
    for (int t = 0; t < T_; ++t) {
        const float xv = xp[(size_t)t * H_];
        const float r = (m - THR > 0.f) ? THR : 0.f;
        m = BETA * m + xv - r;
        sp[(size_t)t * H_] = (m - THR > 0.f) ? (ushort_t)0x3C00 : (ushort_t)0;
    }
}

// ---------------------------------------------------------------------------
// Top-17 mean per batch row. One wave per row.
// ---------------------------------------------------------------------------
__global__ __launch_bounds__(64) void topk_mean(const float* __restrict__ logits,
                                                float* __restrict__ out) {
    const int b = blockIdx.x;
    const int lane = threadIdx.x;
    float v[4];
#pragma unroll
    for (int i = 0; i < 4; ++i) v[i] = logits[b * T_ + lane + i * 64];
    float sum = 0.f;
    for (int iter = 0; iter < 17; ++iter) {
        float mv = v[0];
        int mslot = 0;
#pragma unroll
        for (int i = 1; i < 4; ++i)
            if (v[i] > mv) { mv = v[i]; mslot = i; }
        float bv = mv;
        int bl = lane, bs = mslot;
#pragma unroll
        for (int off = 32; off >= 1; off >>= 1) {
            const float ov = __shfl_xor(bv, off);
            const int ol = __shfl_xor(bl, off);
            const int os = __shfl_xor(bs, off);
            if (ov > bv || (ov == bv && ol < bl)) { bv = ov; bl = ol; bs = os; }
        }
        sum += bv;
        if (lane == bl) v[bs] = -1e30f;
    }
    if (lane == 0) out[b] = sum * (1.f / 17.f);
}

// ---------------------------------------------------------------------------
// Orchestration:
//   prolog: W1/Mw2 bf16 planes; WfT bf16 planes; W2/Mw1 f16; f_f f16 planes;
//           bc = W1@bf+b1 (wave-parallel)
//   wcf16  <- gemm_bf16_wc(W1 planes @ WfT^T)      [f16 out]
//   xbuf   <- gemm_f16<2>(ff planes @ wc^T) + bc
//   sbuf   <- scan; xbuf <- gemm_f16<1>(sbuf @ W2^T)
//   sbuf   <- scan; (zh,zl) <- gemm_f16<1,relu>(sbuf @ Mw1^T)  [bf16 planes]
//   logits <- mil2_dp; out <- topk
// ---------------------------------------------------------------------------
extern "C" void kernel_launch(void* const* d_in, const int* in_sizes, int n_in,
                              void* d_out, int out_size, void* d_ws, size_t ws_size,
                              hipStream_t stream) {
    const float* f_f = (const float*)d_in[0];
    const float* Wf  = (const float*)d_in[2];
    const float* bf  = (const float*)d_in[3];
    const float* W1  = (const float*)d_in[4];
    const float* b1  = (const float*)d_in[5];
    const float* W2  = (const float*)d_in[6];
    const float* b2  = (const float*)d_in[7];
    const float* Mw1 = (const float*)d_in[8];
    const float* Mb1 = (const float*)d_in[9];
    const float* Mw2 = (const float*)d_in[10];
    const float* Mb2 = (const float*)d_in[11];
    const float* Mw3 = (const float*)d_in[12];
    const float* Mb3 = (const float*)d_in[13];
    float* out = (float*)d_out;

    char* ws = (char*)d_ws;
    const size_t NEf = (size_t)M_ * F_;  // 16.78M elems
    const size_t NE = (size_t)M_ * H_;   // 8.39M elems
    ushort_t* ffh = (ushort_t*)ws;                       // f16 planes of f_f
    ushort_t* ffl = ffh + NEf;
    float* xbuf = (float*)(ffl + NEf);
    ushort_t* sbuf = (ushort_t*)(xbuf + NE);             // f16 spikes
    ushort_t* w1h = sbuf + NE;                           // bf16 (wc input)
    ushort_t* w1l = w1h + 262144;
    ushort_t* w2f = w1l + 262144;                        // f16 single
    ushort_t* m1f = w2f + 262144;                        // f16 single
    ushort_t* m2h = m1f + 262144;                        // bf16 (mil2)
    ushort_t* m2l = m2h + 16384;
    ushort_t* wfTh = m2l + 16384;                        // bf16 [1024,512]
    ushort_t* wfTl = wfTh + 524288;
    ushort_t* wcf = wfTl + 524288;                       // f16 [512,1024]
    float* bc = (float*)(wcf + 524288);
    float* logits = bc + 512 + 128;
    ushort_t* zh = ffh;       // overlay: f_f planes dead after x1-GEMM
    ushort_t* zl = ffh + NE;

    const dim3 blk(256);

    split_planes_bf<<<dim3(256), blk, 0, stream>>>(W1, w1h, w1l, 65536);
    round_f16<<<dim3(256), blk, 0, stream>>>(W2, w2f, 65536);
    round_f16<<<dim3(256), blk, 0, stream>>>(Mw1, m1f, 65536);
    split_planes_bf<<<dim3(16), blk, 0, stream>>>(Mw2, m2h, m2l, 4096);
    transpose_split<<<dim3(32, 16), blk, 0, stream>>>(Wf, wfTh, wfTl);
    split_planes_f16<<<dim3(2048), blk, 0, stream>>>(f_f, ffh, ffl, 4194304);
    combine_bias<<<dim3(128), blk, 0, stream>>>(W1, bf, b1, bc);

    // Wc = W1 @ Wf -> f16 [512,1024]
    gemm_bf16_wc<<<dim3(8, 4), blk, 0, stream>>>(w1h, w1l, wfTh, wfTl, wcf,
                                                 1024, 512);
    // x1 = f_f @ Wc^T + bc  (2-product f16)
    gemm_f16<2, 0, 0><<<dim3(4, 128), blk, 0, stream>>>(
        ffh, ffl, wcf, bc, xbuf, nullptr, nullptr, 512, 1024);
    leaky_scan<<<dim3((B_ * H_) / 256), blk, 0, stream>>>(xbuf, sbuf);
    gemm_f16<1, 0, 0><<<dim3(4, 128), blk, 0, stream>>>(
        sbuf, nullptr, w2f, b2, xbuf, nullptr, nullptr, 512, 512);
    leaky_scan<<<dim3((B_ * H_) / 256), blk, 0, stream>>>(xbuf, sbuf);
    gemm_f16<1, 1, 1><<<dim3(4, 128), blk, 0, stream>>>(
        sbuf, nullptr, m1f, Mb1, nullptr, zh, zl, 512, 512);
    mil2_dp<<<dim3(M_ / 128), blk, 0, stream>>>(zh, zl, m2h, m2l, Mb2, Mw3,
                                                Mb3, logits);
    topk_mean<<<dim3(B_), dim3(64), 0, stream>>>(logits, out);
}

// Round 7
// 197.664 us; speedup vs baseline: 1.2808x; 1.0895x over previous
//
#include <hip/hip_runtime.h>
#include <math.h>

#define BETA 0.9f
#define THR 1.0f

constexpr int B_ = 64, T_ = 256, F_ = 1024, H_ = 512;
constexpr int M_ = B_ * T_;  // 16384 rows

typedef float f32x4 __attribute__((ext_vector_type(4)));
typedef short short8 __attribute__((ext_vector_type(8)));
typedef _Float16 half8 __attribute__((ext_vector_type(8)));
typedef unsigned short us4 __attribute__((ext_vector_type(4)));
typedef unsigned short ushort_t;

// ---- bf16 helpers (RNE) ----------------------------------------------------
static __device__ __forceinline__ unsigned short f2bf(float x) {
    unsigned b = __builtin_bit_cast(unsigned, x);
    unsigned r = (b + 0x7FFFu + ((b >> 16) & 1u)) >> 16;
    return (unsigned short)r;
}
static __device__ __forceinline__ float bf2f(unsigned short u) {
    unsigned v = ((unsigned)u) << 16;
    return __builtin_bit_cast(float, v);
}
// ---- f16 helpers (v_cvt_f16_f32, RNE) --------------------------------------
static __device__ __forceinline__ unsigned short f2h(float x) {
    _Float16 h = (_Float16)x;
    return __builtin_bit_cast(unsigned short, h);
}
static __device__ __forceinline__ float h2f(unsigned short u) {
    return (float)__builtin_bit_cast(_Float16, u);
}
// XOR swizzle on 16B chunks within a 64B row; involution applied on the
// pre-swizzled GLDS source AND the ds_read (rule #21).
static __device__ __forceinline__ int swz(int r) {
    return ((r >> 2) & 3) ^ (r & 3);
}

#define GLDS(srcp, dstp)                                                      \
    __builtin_amdgcn_global_load_lds(                                         \
        (const __attribute__((address_space(1))) unsigned int*)(srcp),        \
        (__attribute__((address_space(3))) unsigned int*)(dstp), 16, 0, 0)

// ---------------------------------------------------------------------------
// f16 MFMA GEMM (m97 structure). C = A @ Bw^T + bias. Single product:
// A = single f16 plane, B = single f16 plane. 2 LDS planes, 16 MFMA/K-step.
// OUTMODE 0: f32 C. OUTMODE 1: bf16 hi/lo plane C (for mil2).
// Tile 128x128, BK=32, 4 waves (2x2). Grid (N/128, M/128), nwg%8==0.
// ---------------------------------------------------------------------------
template <int RELU, int OUTMODE>
__global__ __launch_bounds__(256) void gemm_f16(
    const ushort_t* __restrict__ Ap, const ushort_t* __restrict__ Bp,
    const float* __restrict__ bias, float* __restrict__ Cf,
    ushort_t* __restrict__ Ch, ushort_t* __restrict__ Cl, int N, int K) {
    __shared__ ushort_t lds[2 * 4096];

    const int tid = threadIdx.x;
    const int w = tid >> 6, l = tid & 63;
    const int nwg = gridDim.x * gridDim.y;
    const int flat = blockIdx.y * gridDim.x + blockIdx.x;
    const int wg = (flat & 7) * (nwg >> 3) + (flat >> 3);
    const int n0 = (wg % gridDim.x) * 128;
    const int m0 = (wg / gridDim.x) * 128;
    const int wr = w >> 1, wc = w & 1;

    f32x4 acc[4][4];
#pragma unroll
    for (int mi = 0; mi < 4; ++mi)
#pragma unroll
        for (int ni = 0; ni < 4; ++ni) acc[mi][ni] = (f32x4){0.f, 0.f, 0.f, 0.f};

    const int c0 = l >> 4;
    for (int k0 = 0; k0 < K; k0 += 32) {
        __syncthreads();
#pragma unroll
        for (int j = 0; j < 4; ++j) {
            const int g = w * 4 + j;  // 0..15
            const int p = g >> 3, seg = g & 7;
            const int r = seg * 16 + (l >> 2);
            const int ch = (l & 3) ^ swz(r);
            const ushort_t* pl = p ? Bp : Ap;
            const int rb = p ? n0 : m0;
            GLDS(pl + (size_t)(rb + r) * K + k0 + ch * 8,
                 &lds[p * 4096 + seg * 512]);
        }
        __syncthreads();

        half8 aa[4], bb[4];
#pragma unroll
        for (int mi = 0; mi < 4; ++mi) {
            const int r = wr * 64 + mi * 16 + (l & 15);
            const int off = r * 32 + ((c0 ^ swz(r)) * 8);
            aa[mi] = __builtin_bit_cast(half8, *(const short8*)&lds[off]);
        }
#pragma unroll
        for (int ni = 0; ni < 4; ++ni) {
            const int r = wc * 64 + ni * 16 + (l & 15);
            const int off = r * 32 + ((c0 ^ swz(r)) * 8);
            bb[ni] = __builtin_bit_cast(half8, *(const short8*)&lds[4096 + off]);
        }

#pragma unroll
        for (int mi = 0; mi < 4; ++mi)
#pragma unroll
            for (int ni = 0; ni < 4; ++ni)
                acc[mi][ni] = __builtin_amdgcn_mfma_f32_16x16x32_f16(
                    aa[mi], bb[ni], acc[mi][ni], 0, 0, 0);
    }

    // epilogue: C/D layout col=lane&15, row=(lane>>4)*4+reg (dtype-indep)
#pragma unroll
    for (int ni = 0; ni < 4; ++ni) {
        const int col = n0 + wc * 64 + ni * 16 + (l & 15);
        const float bv = bias ? bias[col] : 0.f;
#pragma unroll
        for (int mi = 0; mi < 4; ++mi) {
            const int row0 = m0 + wr * 64 + mi * 16 + ((l >> 4) << 2);
#pragma unroll
            for (int r = 0; r < 4; ++r) {
                float v = acc[mi][ni][r] + bv;
                if (RELU) v = fmaxf(v, 0.f);
                const size_t idx = (size_t)(row0 + r) * N + col;
                if constexpr (OUTMODE == 0) {
                    Cf[idx] = v;
                } else {
                    const unsigned short h = f2bf(v);
                    Ch[idx] = h;
                    Cl[idx] = f2bf(v - bf2f(h));
                }
            }
        }
    }
}

// ---------------------------------------------------------------------------
// Split-bf16 3-product GEMM (m97 structure) — only for Wc = W1 @ Wf.
// Emits single f16 plane (f16 split of Wc is then near-exact at 2^-12 rel).
// ---------------------------------------------------------------------------
__global__ __launch_bounds__(256) void gemm_bf16_wc(
    const ushort_t* __restrict__ Ah, const ushort_t* __restrict__ Al,
    const ushort_t* __restrict__ Bh, const ushort_t* __restrict__ Bl,
    ushort_t* __restrict__ Cout, int N, int K) {
    __shared__ ushort_t lds[4 * 4096];

    const int tid = threadIdx.x;
    const int w = tid >> 6, l = tid & 63;
    const int nwg = gridDim.x * gridDim.y;
    const int flat = blockIdx.y * gridDim.x + blockIdx.x;
    const int wg = (flat & 7) * (nwg >> 3) + (flat >> 3);
    const int n0 = (wg % gridDim.x) * 128;
    const int m0 = (wg / gridDim.x) * 128;
    const int wr = w >> 1, wc = w & 1;

    f32x4 acc[4][4];
#pragma unroll
    for (int mi = 0; mi < 4; ++mi)
#pragma unroll
        for (int ni = 0; ni < 4; ++ni) acc[mi][ni] = (f32x4){0.f, 0.f, 0.f, 0.f};

    const int c0 = l >> 4;
    for (int k0 = 0; k0 < K; k0 += 32) {
        __syncthreads();
#pragma unroll
        for (int j = 0; j < 8; ++j) {
            const int g = w * 8 + j;
            const int p = g >> 3, seg = g & 7;
            const int r = seg * 16 + (l >> 2);
            const int ch = (l & 3) ^ swz(r);
            const ushort_t* pl = (p == 0) ? Ah : (p == 1) ? Al : (p == 2) ? Bh : Bl;
            const int rb = (p < 2) ? m0 : n0;
            GLDS(pl + (size_t)(rb + r) * K + k0 + ch * 8,
                 &lds[p * 4096 + seg * 512]);
        }
        __syncthreads();

        short8 ah[4], al[4], bh[4], bl[4];
#pragma unroll
        for (int mi = 0; mi < 4; ++mi) {
            const int r = wr * 64 + mi * 16 + (l & 15);
            const int off = r * 32 + ((c0 ^ swz(r)) * 8);
            ah[mi] = *(const short8*)&lds[off];
            al[mi] = *(const short8*)&lds[4096 + off];
        }
#pragma unroll
        for (int ni = 0; ni < 4; ++ni) {
            const int r = wc * 64 + ni * 16 + (l & 15);
            const int off = r * 32 + ((c0 ^ swz(r)) * 8);
            bh[ni] = *(const short8*)&lds[8192 + off];
            bl[ni] = *(const short8*)&lds[12288 + off];
        }
#pragma unroll
        for (int mi = 0; mi < 4; ++mi)
#pragma unroll
            for (int ni = 0; ni < 4; ++ni) {
                acc[mi][ni] = __builtin_amdgcn_mfma_f32_16x16x32_bf16(
                    ah[mi], bh[ni], acc[mi][ni], 0, 0, 0);
                acc[mi][ni] = __builtin_amdgcn_mfma_f32_16x16x32_bf16(
                    ah[mi], bl[ni], acc[mi][ni], 0, 0, 0);
                acc[mi][ni] = __builtin_amdgcn_mfma_f32_16x16x32_bf16(
                    al[mi], bh[ni], acc[mi][ni], 0, 0, 0);
            }
    }

#pragma unroll
    for (int ni = 0; ni < 4; ++ni) {
        const int col = n0 + wc * 64 + ni * 16 + (l & 15);
#pragma unroll
        for (int mi = 0; mi < 4; ++mi) {
            const int row0 = m0 + wr * 64 + mi * 16 + ((l >> 4) << 2);
#pragma unroll
            for (int r = 0; r < 4; ++r)
                Cout[(size_t)(row0 + r) * N + col] = f2h(acc[mi][ni][r]);
        }
    }
}

// ---------------------------------------------------------------------------
// mil2+mil3+sigmoid fused (bf16 split path; z from hi/lo planes).
// ---------------------------------------------------------------------------
__global__ __launch_bounds__(256) void mil2_dp(
    const ushort_t* __restrict__ zh, const ushort_t* __restrict__ zl,
    const ushort_t* __restrict__ Bh, const ushort_t* __restrict__ Bl,
    const float* __restrict__ Mb2, const float* __restrict__ Mw3,
    const float* __restrict__ Mb3, float* __restrict__ logits) {
    constexpr int BUFSZ = 2 * 4096;
    __shared__ ushort_t lds[2 * BUFSZ];
    constexpr int K = 512;

    const int tid = threadIdx.x;
    const int w = tid >> 6, l = tid & 63;
    const int m0 = blockIdx.x * 128;

    f32x4 acc[2][2];
#pragma unroll
    for (int mi = 0; mi < 2; ++mi)
#pragma unroll
        for (int ni = 0; ni < 2; ++ni) acc[mi][ni] = (f32x4){0.f, 0.f, 0.f, 0.f};

    auto stageA = [&](int buf, int k0) {
#pragma unroll
        for (int j = 0; j < 4; ++j) {
            const int g = w * 4 + j;
            const int p = g >> 3, seg = g & 7;
            const int r = seg * 16 + (l >> 2);
            const int ch = (l & 3) ^ swz(r);
            const ushort_t* src =
                (p ? zl : zh) + (size_t)(m0 + r) * K + k0 + ch * 8;
            GLDS(src, &lds[buf + p * 4096 + seg * 512]);
        }
    };

    stageA(0, 0);
    __syncthreads();

    const int c0 = l >> 4;
    for (int t = 0; t < 16; ++t) {
        const int cur = (t & 1) * BUFSZ;
        const int nxt = BUFSZ - cur;
        if (t < 15) stageA(nxt, (t + 1) * 32);
        const int k0 = t * 32;

        short8 ah[2], al[2], bh[2], bl[2];
#pragma unroll
        for (int mi = 0; mi < 2; ++mi) {
            const int r = w * 32 + mi * 16 + (l & 15);
            const int off = r * 32 + ((c0 ^ swz(r)) * 8);
            ah[mi] = *(const short8*)&lds[cur + off];
            al[mi] = *(const short8*)&lds[cur + 4096 + off];
        }
#pragma unroll
        for (int ni = 0; ni < 2; ++ni) {
            const size_t boff = (size_t)(ni * 16 + (l & 15)) * K + k0 + c0 * 8;
            bh[ni] = *(const short8*)&Bh[boff];
            bl[ni] = *(const short8*)&Bl[boff];
        }
#pragma unroll
        for (int mi = 0; mi < 2; ++mi)
#pragma unroll
            for (int ni = 0; ni < 2; ++ni) {
                acc[mi][ni] = __builtin_amdgcn_mfma_f32_16x16x32_bf16(
                    ah[mi], bh[ni], acc[mi][ni], 0, 0, 0);
                acc[mi][ni] = __builtin_amdgcn_mfma_f32_16x16x32_bf16(
                    ah[mi], bl[ni], acc[mi][ni], 0, 0, 0);
                acc[mi][ni] = __builtin_amdgcn_mfma_f32_16x16x32_bf16(
                    al[mi], bh[ni], acc[mi][ni], 0, 0, 0);
            }
        __syncthreads();
    }

    float mw3v[2], mb2v[2];
#pragma unroll
    for (int ni = 0; ni < 2; ++ni) {
        const int j = ni * 16 + (l & 15);
        mw3v[ni] = Mw3[j];
        mb2v[ni] = Mb2[j];
    }
    const float b3 = Mb3[0];
#pragma unroll
    for (int mi = 0; mi < 2; ++mi) {
        float p[4];
#pragma unroll
        for (int r = 0; r < 4; ++r) {
            float s = 0.f;
#pragma unroll
            for (int ni = 0; ni < 2; ++ni)
                s += (acc[mi][ni][r] + mb2v[ni]) * mw3v[ni];
            p[r] = s;
        }
#pragma unroll
        for (int off = 1; off <= 8; off <<= 1)
#pragma unroll
            for (int r = 0; r < 4; ++r) p[r] += __shfl_xor(p[r], off);
        if ((l & 15) == 0) {
#pragma unroll
            for (int r = 0; r < 4; ++r) {
                const int row = m0 + w * 32 + mi * 16 + ((l >> 4) << 2) + r;
                logits[row] = 1.f / (1.f + expf(-(p[r] + b3)));
            }
        }
    }
}

// ---------------------------------------------------------------------------
// f32 -> single f16 plane round (f_f, W2, Mw1).
// ---------------------------------------------------------------------------
__global__ __launch_bounds__(256) void round_f16(const float* __restrict__ x,
                                                 ushort_t* __restrict__ o,
                                                 int n4) {
    int i = blockIdx.x * 256 + threadIdx.x;
    const int stride = gridDim.x * 256;
    for (; i < n4; i += stride) {
        f32x4 v = ((const f32x4*)x)[i];
        us4 h;
#pragma unroll
        for (int e = 0; e < 4; ++e) h[e] = f2h(v[e]);
        ((us4*)o)[i] = h;
    }
}

// ---------------------------------------------------------------------------
// f32 -> hi/lo bf16 plane split (W1, Mw2).
// ---------------------------------------------------------------------------
__global__ __launch_bounds__(256) void split_planes_bf(
    const float* __restrict__ x, ushort_t* __restrict__ hi,
    ushort_t* __restrict__ lo, int n4) {
    int i = blockIdx.x * 256 + threadIdx.x;
    const int stride = gridDim.x * 256;
    for (; i < n4; i += stride) {
        f32x4 v = ((const f32x4*)x)[i];
        us4 h, ll;
#pragma unroll
        for (int e = 0; e < 4; ++e) {
            const unsigned short hb = f2bf(v[e]);
            h[e] = hb;
            ll[e] = f2bf(v[e] - bf2f(hb));
        }
        ((us4*)hi)[i] = h;
        ((us4*)lo)[i] = ll;
    }
}

// ---------------------------------------------------------------------------
// Wf [512,1024] f32 -> WfT hi/lo bf16 planes [1024,512].
// ---------------------------------------------------------------------------
__global__ __launch_bounds__(256) void transpose_split(
    const float* __restrict__ Wf, ushort_t* __restrict__ th,
    ushort_t* __restrict__ tl) {
    __shared__ float tile[32][33];
    const int tx = threadIdx.x & 31;
    const int ty = threadIdx.x >> 5;  // 0..7
    const int k0 = blockIdx.x * 32;
    const int i0 = blockIdx.y * 32;
#pragma unroll
    for (int e = 0; e < 4; ++e) {
        const int i = ty + e * 8;
        tile[i][tx] = Wf[(size_t)(i0 + i) * 1024 + k0 + tx];
    }
    __syncthreads();
#pragma unroll
    for (int e = 0; e < 4; ++e) {
        const int kk = ty + e * 8;
        const float v = tile[tx][kk];
        const unsigned short h = f2bf(v);
        th[(size_t)(k0 + kk) * 512 + i0 + tx] = h;
        tl[(size_t)(k0 + kk) * 512 + i0 + tx] = f2bf(v - bf2f(h));
    }
}

// ---------------------------------------------------------------------------
// bc[j] = b1[j] + sum_i W1[j,i]*bf[i]. One WAVE per j (coalesced), 4 waves/blk.
// ---------------------------------------------------------------------------
__global__ __launch_bounds__(256) void combine_bias(const float* __restrict__ W1,
                                                    const float* __restrict__ bfv,
                                                    const float* __restrict__ b1,
                                                    float* __restrict__ bc) {
    const int w = threadIdx.x >> 6, l = threadIdx.x & 63;
    const int j = blockIdx.x * 4 + w;  // 128 blocks x 4 waves = 512
    const float* row = W1 + (size_t)j * 512;
    float a = 0.f;
#pragma unroll
    for (int i = 0; i < 8; ++i) a += row[l + i * 64] * bfv[l + i * 64];
#pragma unroll
    for (int off = 32; off >= 1; off >>= 1) a += __shfl_xor(a, off);
    if (l == 0) bc[j] = a + b1[j];
}

// ---------------------------------------------------------------------------
// snntorch Leaky (subtract reset) scan; x f32 [B,T,H] -> spikes f16 (0x3C00).
// 512 blocks x 64 threads: all 256 CUs carry the latency chain.
// ---------------------------------------------------------------------------
__global__ __launch_bounds__(64) void leaky_scan(const float* __restrict__ x,
                                                 ushort_t* __restrict__ s) {
    const int idx = blockIdx.x * 64 + threadIdx.x;  // 0 .. B*H-1
    const int b = idx >> 9;
    const int h = idx & (H_ - 1);
    const float* xp = x + (size_t)b * T_ * H_ + h;
    ushort_t* sp = s + (size_t)b * T_ * H_ + h;
    float m = 0.f;
#pragma unroll 8
    for (int t = 0; t < T_; ++t) {
        const float xv = xp[(size_t)t * H_];
        const float r = (m - THR > 0.f) ? THR : 0.f;
        m = BETA * m + xv - r;
        sp[(size_t)t * H_] = (m - THR > 0.f) ? (ushort_t)0x3C00 : (ushort_t)0;
    }
}

// ---------------------------------------------------------------------------
// Top-17 mean per batch row. One wave per row.
// ---------------------------------------------------------------------------
__global__ __launch_bounds__(64) void topk_mean(const float* __restrict__ logits,
                                                float* __restrict__ out) {
    const int b = blockIdx.x;
    const int lane = threadIdx.x;
    float v[4];
#pragma unroll
    for (int i = 0; i < 4; ++i) v[i] = logits[b * T_ + lane + i * 64];
    float sum = 0.f;
    for (int iter = 0; iter < 17; ++iter) {
        float mv = v[0];
        int mslot = 0;
#pragma unroll
        for (int i = 1; i < 4; ++i)
            if (v[i] > mv) { mv = v[i]; mslot = i; }
        float bv = mv;
        int bl = lane, bs = mslot;
#pragma unroll
        for (int off = 32; off >= 1; off >>= 1) {
            const float ov = __shfl_xor(bv, off);
            const int ol = __shfl_xor(bl, off);
            const int os = __shfl_xor(bs, off);
            if (ov > bv || (ov == bv && ol < bl)) { bv = ov; bl = ol; bs = os; }
        }
        sum += bv;
        if (lane == bl) v[bs] = -1e30f;
    }
    if (lane == 0) out[b] = sum * (1.f / 17.f);
}

// ---------------------------------------------------------------------------
// Orchestration:
//   prolog: W1/Mw2 bf16 planes; WfT bf16 planes; W2/Mw1/f_f f16 rounds;
//           bc = W1@bf+b1
//   wcf    <- gemm_bf16_wc(W1 planes @ WfT^T)          [f16 out, near-exact]
//   xbuf   <- gemm_f16(ffh @ wcf^T) + bc               [1 product]
//   sbuf   <- scan; xbuf <- gemm_f16(sbuf @ w2f^T)     [1 product]
//   sbuf   <- scan; (zh,zl) <- gemm_f16(sbuf @ m1f^T, relu)  [bf16 planes]
//   logits <- mil2_dp; out <- topk
// ---------------------------------------------------------------------------
extern "C" void kernel_launch(void* const* d_in, const int* in_sizes, int n_in,
                              void* d_out, int out_size, void* d_ws, size_t ws_size,
                              hipStream_t stream) {
    const float* f_f = (const float*)d_in[0];
    const float* Wf  = (const float*)d_in[2];
    const float* bf  = (const float*)d_in[3];
    const float* W1  = (const float*)d_in[4];
    const float* b1  = (const float*)d_in[5];
    const float* W2  = (const float*)d_in[6];
    const float* b2  = (const float*)d_in[7];
    const float* Mw1 = (const float*)d_in[8];
    const float* Mb1 = (const float*)d_in[9];
    const float* Mw2 = (const float*)d_in[10];
    const float* Mb2 = (const float*)d_in[11];
    const float* Mw3 = (const float*)d_in[12];
    const float* Mb3 = (const float*)d_in[13];
    float* out = (float*)d_out;

    char* ws = (char*)d_ws;
    const size_t NEf = (size_t)M_ * F_;  // 16.78M elems
    const size_t NE = (size_t)M_ * H_;   // 8.39M elems
    ushort_t* ffh = (ushort_t*)ws;                       // f16 f_f [M,1024]
    float* xbuf = (float*)(ffh + NEf);
    ushort_t* sbuf = (ushort_t*)(xbuf + NE);             // f16 spikes
    ushort_t* w1h = sbuf + NE;                           // bf16 (wc input)
    ushort_t* w1l = w1h + 262144;
    ushort_t* w2f = w1l + 262144;                        // f16 single
    ushort_t* m1f = w2f + 262144;                        // f16 single
    ushort_t* m2h = m1f + 262144;                        // bf16 (mil2)
    ushort_t* m2l = m2h + 16384;
    ushort_t* wfTh = m2l + 16384;                        // bf16 [1024,512]
    ushort_t* wfTl = wfTh + 524288;
    ushort_t* wcf = wfTl + 524288;                       // f16 [512,1024]
    float* bc = (float*)(wcf + 524288);
    float* logits = bc + 512 + 128;
    ushort_t* zh = ffh;       // overlay: ffh dead after x1-GEMM (NEf = 2*NE)
    ushort_t* zl = ffh + NE;

    const dim3 blk(256);

    split_planes_bf<<<dim3(256), blk, 0, stream>>>(W1, w1h, w1l, 65536);
    round_f16<<<dim3(256), blk, 0, stream>>>(W2, w2f, 65536);
    round_f16<<<dim3(256), blk, 0, stream>>>(Mw1, m1f, 65536);
    split_planes_bf<<<dim3(16), blk, 0, stream>>>(Mw2, m2h, m2l, 4096);
    transpose_split<<<dim3(32, 16), blk, 0, stream>>>(Wf, wfTh, wfTl);
    round_f16<<<dim3(2048), blk, 0, stream>>>(f_f, ffh, 4194304);
    combine_bias<<<dim3(128), blk, 0, stream>>>(W1, bf, b1, bc);

    // Wc = W1 @ Wf -> f16 [512,1024]
    gemm_bf16_wc<<<dim3(8, 4), blk, 0, stream>>>(w1h, w1l, wfTh, wfTl, wcf,
                                                 1024, 512);
    // x1 = f_f @ Wc^T + bc  (single f16 product)
    gemm_f16<0, 0><<<dim3(4, 128), blk, 0, stream>>>(
        ffh, wcf, bc, xbuf, nullptr, nullptr, 512, 1024);
    leaky_scan<<<dim3(512), dim3(64), 0, stream>>>(xbuf, sbuf);
    gemm_f16<0, 0><<<dim3(4, 128), blk, 0, stream>>>(
        sbuf, w2f, b2, xbuf, nullptr, nullptr, 512, 512);
    leaky_scan<<<dim3(512), dim3(64), 0, stream>>>(xbuf, sbuf);
    gemm_f16<1, 1><<<dim3(4, 128), blk, 0, stream>>>(
        sbuf, m1f, Mb1, nullptr, zh, zl, 512, 512);
    mil2_dp<<<dim3(M_ / 128), blk, 0, stream>>>(zh, zl, m2h, m2l, Mb2, Mw3,
                                                Mb3, logits);
    topk_mean<<<dim3(B_), dim3(64), 0, stream>>>(logits, out);
}

// Round 8
// 160.414 us; speedup vs baseline: 1.5782x; 1.2322x over previous
//
#include <hip/hip_runtime.h>
#include <math.h>

#define BETA 0.9f
#define THR 1.0f

constexpr int B_ = 64, T_ = 256, F_ = 1024, H_ = 512;
constexpr int M_ = B_ * T_;  // 16384 rows

typedef float f32x4 __attribute__((ext_vector_type(4)));
typedef short short8 __attribute__((ext_vector_type(8)));
typedef _Float16 half8 __attribute__((ext_vector_type(8)));
typedef unsigned short us4 __attribute__((ext_vector_type(4)));
typedef unsigned short ushort_t;

// ---- bf16 helpers (RNE) ----------------------------------------------------
static __device__ __forceinline__ unsigned short f2bf(float x) {
    unsigned b = __builtin_bit_cast(unsigned, x);
    unsigned r = (b + 0x7FFFu + ((b >> 16) & 1u)) >> 16;
    return (unsigned short)r;
}
static __device__ __forceinline__ float bf2f(unsigned short u) {
    unsigned v = ((unsigned)u) << 16;
    return __builtin_bit_cast(float, v);
}
// ---- f16 helpers ------------------------------------------------------------
static __device__ __forceinline__ unsigned short f2h(float x) {
    _Float16 h = (_Float16)x;
    return __builtin_bit_cast(unsigned short, h);
}
// XOR swizzle on 16B chunks within a 64B row; involution applied on the
// pre-swizzled GLDS source AND the ds_read (rule #21).
static __device__ __forceinline__ int swz(int r) {
    return ((r >> 2) & 3) ^ (r & 3);
}

#define GLDS(srcp, dstp)                                                      \
    __builtin_amdgcn_global_load_lds(                                         \
        (const __attribute__((address_space(1))) unsigned int*)(srcp),        \
        (__attribute__((address_space(3))) unsigned int*)(dstp), 16, 0, 0)

// ---------------------------------------------------------------------------
// f16 MFMA GEMM (m97 structure). C = A @ Bw^T + bias. Single product.
// OUTMODE 0: f32 C.
// OUTMODE 2: fused MIL head: p = relu(C) dot u over this wave's 64-col strip,
//            16-lane reduce, write part[strip][row]. No C materialization.
// Tile 128x128, BK=32, 4 waves (2x2). Grid (N/128, M/128), nwg%8==0.
// ---------------------------------------------------------------------------
template <int RELU, int OUTMODE>
__global__ __launch_bounds__(256) void gemm_f16(
    const ushort_t* __restrict__ Ap, const ushort_t* __restrict__ Bp,
    const float* __restrict__ bias, float* __restrict__ Cf,
    const float* __restrict__ Uv, float* __restrict__ part, int N, int K) {
    __shared__ ushort_t lds[2 * 4096];

    const int tid = threadIdx.x;
    const int w = tid >> 6, l = tid & 63;
    const int nwg = gridDim.x * gridDim.y;
    const int flat = blockIdx.y * gridDim.x + blockIdx.x;
    const int wg = (flat & 7) * (nwg >> 3) + (flat >> 3);
    const int n0 = (wg % gridDim.x) * 128;
    const int m0 = (wg / gridDim.x) * 128;
    const int wr = w >> 1, wc = w & 1;

    f32x4 acc[4][4];
#pragma unroll
    for (int mi = 0; mi < 4; ++mi)
#pragma unroll
        for (int ni = 0; ni < 4; ++ni) acc[mi][ni] = (f32x4){0.f, 0.f, 0.f, 0.f};

    const int c0 = l >> 4;
    for (int k0 = 0; k0 < K; k0 += 32) {
        __syncthreads();
#pragma unroll
        for (int j = 0; j < 4; ++j) {
            const int g = w * 4 + j;  // 0..15
            const int p = g >> 3, seg = g & 7;
            const int r = seg * 16 + (l >> 2);
            const int ch = (l & 3) ^ swz(r);
            const ushort_t* pl = p ? Bp : Ap;
            const int rb = p ? n0 : m0;
            GLDS(pl + (size_t)(rb + r) * K + k0 + ch * 8,
                 &lds[p * 4096 + seg * 512]);
        }
        __syncthreads();

        half8 aa[4], bb[4];
#pragma unroll
        for (int mi = 0; mi < 4; ++mi) {
            const int r = wr * 64 + mi * 16 + (l & 15);
            const int off = r * 32 + ((c0 ^ swz(r)) * 8);
            aa[mi] = __builtin_bit_cast(half8, *(const short8*)&lds[off]);
        }
#pragma unroll
        for (int ni = 0; ni < 4; ++ni) {
            const int r = wc * 64 + ni * 16 + (l & 15);
            const int off = r * 32 + ((c0 ^ swz(r)) * 8);
            bb[ni] = __builtin_bit_cast(half8, *(const short8*)&lds[4096 + off]);
        }

#pragma unroll
        for (int mi = 0; mi < 4; ++mi)
#pragma unroll
            for (int ni = 0; ni < 4; ++ni)
                acc[mi][ni] = __builtin_amdgcn_mfma_f32_16x16x32_f16(
                    aa[mi], bb[ni], acc[mi][ni], 0, 0, 0);
    }

    if constexpr (OUTMODE == 0) {
        // C/D layout: col=lane&15, row=(lane>>4)*4+reg (dtype-indep)
#pragma unroll
        for (int ni = 0; ni < 4; ++ni) {
            const int col = n0 + wc * 64 + ni * 16 + (l & 15);
            const float bv = bias ? bias[col] : 0.f;
#pragma unroll
            for (int mi = 0; mi < 4; ++mi) {
                const int row0 = m0 + wr * 64 + mi * 16 + ((l >> 4) << 2);
#pragma unroll
                for (int r = 0; r < 4; ++r) {
                    float v = acc[mi][ni][r] + bv;
                    if (RELU) v = fmaxf(v, 0.f);
                    Cf[(size_t)(row0 + r) * N + col] = v;
                }
            }
        }
    } else {
        // fused MIL: per row partial = sum_col relu(acc+bias)*u[col]
        float bv[4], uc[4];
#pragma unroll
        for (int ni = 0; ni < 4; ++ni) {
            const int col = n0 + wc * 64 + ni * 16 + (l & 15);
            bv[ni] = bias[col];
            uc[ni] = Uv[col];
        }
        const int strip = (n0 >> 6) + wc;  // 0..7 (64-col strips)
#pragma unroll
        for (int mi = 0; mi < 4; ++mi) {
            float p[4];
#pragma unroll
            for (int r = 0; r < 4; ++r) {
                float s = 0.f;
#pragma unroll
                for (int ni = 0; ni < 4; ++ni)
                    s += fmaxf(acc[mi][ni][r] + bv[ni], 0.f) * uc[ni];
                p[r] = s;
            }
#pragma unroll
            for (int off = 1; off <= 8; off <<= 1)
#pragma unroll
                for (int r = 0; r < 4; ++r) p[r] += __shfl_xor(p[r], off);
            if ((l & 15) == 0) {
                const int row0 = m0 + wr * 64 + mi * 16 + ((l >> 4) << 2);
#pragma unroll
                for (int r = 0; r < 4; ++r)
                    part[(size_t)strip * M_ + row0 + r] = p[r];
            }
        }
    }
}

// ---------------------------------------------------------------------------
// Split-bf16 3-product GEMM (m97 structure) — only for Wc = W1 @ Wf.
// Emits single f16 plane.
// ---------------------------------------------------------------------------
__global__ __launch_bounds__(256) void gemm_bf16_wc(
    const ushort_t* __restrict__ Ah, const ushort_t* __restrict__ Al,
    const ushort_t* __restrict__ Bh, const ushort_t* __restrict__ Bl,
    ushort_t* __restrict__ Cout, int N, int K) {
    __shared__ ushort_t lds[4 * 4096];

    const int tid = threadIdx.x;
    const int w = tid >> 6, l = tid & 63;
    const int nwg = gridDim.x * gridDim.y;
    const int flat = blockIdx.y * gridDim.x + blockIdx.x;
    const int wg = (flat & 7) * (nwg >> 3) + (flat >> 3);
    const int n0 = (wg % gridDim.x) * 128;
    const int m0 = (wg / gridDim.x) * 128;
    const int wr = w >> 1, wc = w & 1;

    f32x4 acc[4][4];
#pragma unroll
    for (int mi = 0; mi < 4; ++mi)
#pragma unroll
        for (int ni = 0; ni < 4; ++ni) acc[mi][ni] = (f32x4){0.f, 0.f, 0.f, 0.f};

    const int c0 = l >> 4;
    for (int k0 = 0; k0 < K; k0 += 32) {
        __syncthreads();
#pragma unroll
        for (int j = 0; j < 8; ++j) {
            const int g = w * 8 + j;
            const int p = g >> 3, seg = g & 7;
            const int r = seg * 16 + (l >> 2);
            const int ch = (l & 3) ^ swz(r);
            const ushort_t* pl = (p == 0) ? Ah : (p == 1) ? Al : (p == 2) ? Bh : Bl;
            const int rb = (p < 2) ? m0 : n0;
            GLDS(pl + (size_t)(rb + r) * K + k0 + ch * 8,
                 &lds[p * 4096 + seg * 512]);
        }
        __syncthreads();

        short8 ah[4], al[4], bh[4], bl[4];
#pragma unroll
        for (int mi = 0; mi < 4; ++mi) {
            const int r = wr * 64 + mi * 16 + (l & 15);
            const int off = r * 32 + ((c0 ^ swz(r)) * 8);
            ah[mi] = *(const short8*)&lds[off];
            al[mi] = *(const short8*)&lds[4096 + off];
        }
#pragma unroll
        for (int ni = 0; ni < 4; ++ni) {
            const int r = wc * 64 + ni * 16 + (l & 15);
            const int off = r * 32 + ((c0 ^ swz(r)) * 8);
            bh[ni] = *(const short8*)&lds[8192 + off];
            bl[ni] = *(const short8*)&lds[12288 + off];
        }
#pragma unroll
        for (int mi = 0; mi < 4; ++mi)
#pragma unroll
            for (int ni = 0; ni < 4; ++ni) {
                acc[mi][ni] = __builtin_amdgcn_mfma_f32_16x16x32_bf16(
                    ah[mi], bh[ni], acc[mi][ni], 0, 0, 0);
                acc[mi][ni] = __builtin_amdgcn_mfma_f32_16x16x32_bf16(
                    ah[mi], bl[ni], acc[mi][ni], 0, 0, 0);
                acc[mi][ni] = __builtin_amdgcn_mfma_f32_16x16x32_bf16(
                    al[mi], bh[ni], acc[mi][ni], 0, 0, 0);
            }
    }

#pragma unroll
    for (int ni = 0; ni < 4; ++ni) {
        const int col = n0 + wc * 64 + ni * 16 + (l & 15);
#pragma unroll
        for (int mi = 0; mi < 4; ++mi) {
            const int row0 = m0 + wr * 64 + mi * 16 + ((l >> 4) << 2);
#pragma unroll
            for (int r = 0; r < 4; ++r)
                Cout[(size_t)(row0 + r) * N + col] = f2h(acc[mi][ni][r]);
        }
    }
}

// ---------------------------------------------------------------------------
// Sectioned weight prep (one launch):
//   blocks [0,256):   W1 -> bf16 hi/lo planes        (65536 f32x4)
//   blocks [256,512): W2 -> f16                      (65536 f32x4)
//   blocks [512,768): Mw1 -> f16                     (65536 f32x4)
//   blocks [768,896): bc[j] = b1[j] + W1[j,:]@bf     (wave per j)
//   blocks [896,898): u[j] = Mw3@Mw2[:,j]; uc[512]=c = Mw3@Mb2+Mb3
// ---------------------------------------------------------------------------
__global__ __launch_bounds__(256) void prep_small(
    const float* __restrict__ W1, const float* __restrict__ W2,
    const float* __restrict__ Mw1, const float* __restrict__ bfv,
    const float* __restrict__ b1, const float* __restrict__ Mw2,
    const float* __restrict__ Mb2, const float* __restrict__ Mw3,
    const float* __restrict__ Mb3, ushort_t* __restrict__ w1h,
    ushort_t* __restrict__ w1l, ushort_t* __restrict__ w2f,
    ushort_t* __restrict__ m1f, float* __restrict__ bc,
    float* __restrict__ uc) {
    const int blk = blockIdx.x;
    const int tid = threadIdx.x;
    if (blk < 256) {
        const int i = blk * 256 + tid;
        f32x4 v = ((const f32x4*)W1)[i];
        us4 h, ll;
#pragma unroll
        for (int e = 0; e < 4; ++e) {
            const unsigned short hb = f2bf(v[e]);
            h[e] = hb;
            ll[e] = f2bf(v[e] - bf2f(hb));
        }
        ((us4*)w1h)[i] = h;
        ((us4*)w1l)[i] = ll;
    } else if (blk < 512) {
        const int i = (blk - 256) * 256 + tid;
        f32x4 v = ((const f32x4*)W2)[i];
        us4 h;
#pragma unroll
        for (int e = 0; e < 4; ++e) h[e] = f2h(v[e]);
        ((us4*)w2f)[i] = h;
    } else if (blk < 768) {
        const int i = (blk - 512) * 256 + tid;
        f32x4 v = ((const f32x4*)Mw1)[i];
        us4 h;
#pragma unroll
        for (int e = 0; e < 4; ++e) h[e] = f2h(v[e]);
        ((us4*)m1f)[i] = h;
    } else if (blk < 896) {
        const int w = tid >> 6, l = tid & 63;
        const int j = (blk - 768) * 4 + w;
        const float* row = W1 + (size_t)j * 512;
        float a = 0.f;
#pragma unroll
        for (int i = 0; i < 8; ++i) a += row[l + i * 64] * bfv[l + i * 64];
#pragma unroll
        for (int off = 32; off >= 1; off >>= 1) a += __shfl_xor(a, off);
        if (l == 0) bc[j] = a + b1[j];
    } else {
        const int j = (blk - 896) * 256 + tid;  // 0..511
        float a = 0.f;
        for (int i = 0; i < 32; ++i) a += Mw3[i] * Mw2[(size_t)i * 512 + j];
        uc[j] = a;
        if (j == 0) {
            float c = Mb3[0];
            for (int i = 0; i < 32; ++i) c += Mw3[i] * Mb2[i];
            uc[512] = c;
        }
    }
}

// ---------------------------------------------------------------------------
// f32 -> single f16 plane round (f_f).
// ---------------------------------------------------------------------------
__global__ __launch_bounds__(256) void round_f16(const float* __restrict__ x,
                                                 ushort_t* __restrict__ o,
                                                 int n4) {
    int i = blockIdx.x * 256 + threadIdx.x;
    const int stride = gridDim.x * 256;
    for (; i < n4; i += stride) {
        f32x4 v = ((const f32x4*)x)[i];
        us4 h;
#pragma unroll
        for (int e = 0; e < 4; ++e) h[e] = f2h(v[e]);
        ((us4*)o)[i] = h;
    }
}

// ---------------------------------------------------------------------------
// Wf [512,1024] f32 -> WfT hi/lo bf16 planes [1024,512].
// ---------------------------------------------------------------------------
__global__ __launch_bounds__(256) void transpose_split(
    const float* __restrict__ Wf, ushort_t* __restrict__ th,
    ushort_t* __restrict__ tl) {
    __shared__ float tile[32][33];
    const int tx = threadIdx.x & 31;
    const int ty = threadIdx.x >> 5;  // 0..7
    const int k0 = blockIdx.x * 32;
    const int i0 = blockIdx.y * 32;
#pragma unroll
    for (int e = 0; e < 4; ++e) {
        const int i = ty + e * 8;
        tile[i][tx] = Wf[(size_t)(i0 + i) * 1024 + k0 + tx];
    }
    __syncthreads();
#pragma unroll
    for (int e = 0; e < 4; ++e) {
        const int kk = ty + e * 8;
        const float v = tile[tx][kk];
        const unsigned short h = f2bf(v);
        th[(size_t)(k0 + kk) * 512 + i0 + tx] = h;
        tl[(size_t)(k0 + kk) * 512 + i0 + tx] = f2bf(v - bf2f(h));
    }
}

// ---------------------------------------------------------------------------
// snntorch Leaky (subtract reset) scan; x f32 [B,T,H] -> spikes f16 (0x3C00).
// ---------------------------------------------------------------------------
__global__ __launch_bounds__(64) void leaky_scan(const float* __restrict__ x,
                                                 ushort_t* __restrict__ s) {
    const int idx = blockIdx.x * 64 + threadIdx.x;  // 0 .. B*H-1
    const int b = idx >> 9;
    const int h = idx & (H_ - 1);
    const float* xp = x + (size_t)b * T_ * H_ + h;
    ushort_t* sp = s + (size_t)b * T_ * H_ + h;
    float m = 0.f;
#pragma unroll 8
    for (int t = 0; t < T_; ++t) {
        const float xv = xp[(size_t)t * H_];
        const float r = (m - THR > 0.f) ? THR : 0.f;
        m = BETA * m + xv - r;
        sp[(size_t)t * H_] = (m - THR > 0.f) ? (ushort_t)0x3C00 : (ushort_t)0;
    }
}

// ---------------------------------------------------------------------------
// Tail: pre[row] = sum_{s<8} part[s][row] + c; top-17 on pre (sigmoid is
// monotonic), mean of sigmoid(selected). One wave per batch row.
// ---------------------------------------------------------------------------
__global__ __launch_bounds__(64) void tail_topk(const float* __restrict__ part,
                                                const float* __restrict__ uc,
                                                float* __restrict__ out) {
    const int b = blockIdx.x;
    const int lane = threadIdx.x;
    const float c = uc[512];
    float v[4];
#pragma unroll
    for (int i = 0; i < 4; ++i) {
        const int row = b * T_ + lane + i * 64;
        float a = 0.f;
#pragma unroll
        for (int s = 0; s < 8; ++s) a += part[(size_t)s * M_ + row];
        v[i] = a + c;
    }
    float sum = 0.f;
    for (int iter = 0; iter < 17; ++iter) {
        float mv = v[0];
        int mslot = 0;
#pragma unroll
        for (int i = 1; i < 4; ++i)
            if (v[i] > mv) { mv = v[i]; mslot = i; }
        float bv = mv;
        int bl = lane, bs = mslot;
#pragma unroll
        for (int off = 32; off >= 1; off >>= 1) {
            const float ov = __shfl_xor(bv, off);
            const int ol = __shfl_xor(bl, off);
            const int os = __shfl_xor(bs, off);
            if (ov > bv || (ov == bv && ol < bl)) { bv = ov; bl = ol; bs = os; }
        }
        sum += 1.f / (1.f + expf(-bv));
        if (lane == bl) v[bs] = -1e30f;
    }
    if (lane == 0) out[b] = sum * (1.f / 17.f);
}

// ---------------------------------------------------------------------------
// Orchestration (10 launches):
//   prep_small; transpose_split; round_f16(f_f)
//   wcf  <- gemm_bf16_wc(W1 planes @ WfT^T)
//   xbuf <- gemm_f16(ffh @ wcf^T) + bc
//   sbuf <- scan; xbuf <- gemm_f16(sbuf @ w2f^T) + b2
//   sbuf <- scan; part <- gemm_f16<MIL>(sbuf @ m1f^T + Mb1, relu, dot u)
//   out  <- tail_topk(part)
// ---------------------------------------------------------------------------
extern "C" void kernel_launch(void* const* d_in, const int* in_sizes, int n_in,
                              void* d_out, int out_size, void* d_ws, size_t ws_size,
                              hipStream_t stream) {
    const float* f_f = (const float*)d_in[0];
    const float* Wf  = (const float*)d_in[2];
    const float* bf  = (const float*)d_in[3];
    const float* W1  = (const float*)d_in[4];
    const float* b1  = (const float*)d_in[5];
    const float* W2  = (const float*)d_in[6];
    const float* b2  = (const float*)d_in[7];
    const float* Mw1 = (const float*)d_in[8];
    const float* Mb1 = (const float*)d_in[9];
    const float* Mw2 = (const float*)d_in[10];
    const float* Mb2 = (const float*)d_in[11];
    const float* Mw3 = (const float*)d_in[12];
    const float* Mb3 = (const float*)d_in[13];
    float* out = (float*)d_out;

    char* ws = (char*)d_ws;
    const size_t NEf = (size_t)M_ * F_;  // 16.78M elems
    const size_t NE = (size_t)M_ * H_;   // 8.39M elems
    ushort_t* ffh = (ushort_t*)ws;                       // f16 f_f [M,1024]
    float* xbuf = (float*)(ffh + NEf);
    ushort_t* sbuf = (ushort_t*)(xbuf + NE);             // f16 spikes
    ushort_t* w1h = sbuf + NE;                           // bf16 (wc input)
    ushort_t* w1l = w1h + 262144;
    ushort_t* w2f = w1l + 262144;                        // f16 single
    ushort_t* m1f = w2f + 262144;                        // f16 single
    ushort_t* wfTh = m1f + 262144;                       // bf16 [1024,512]
    ushort_t* wfTl = wfTh + 524288;
    ushort_t* wcf = wfTl + 524288;                       // f16 [512,1024]
    float* bc = (float*)(wcf + 524288);
    float* uc = bc + 512;                                // u[512] + c
    float* part = uc + 513 + 63;                         // [8][16384] f32
    float* logits_unused = nullptr;
    (void)logits_unused;

    const dim3 blk(256);

    prep_small<<<dim3(898), blk, 0, stream>>>(W1, W2, Mw1, bf, b1, Mw2, Mb2,
                                              Mw3, Mb3, w1h, w1l, w2f, m1f,
                                              bc, uc);
    transpose_split<<<dim3(32, 16), blk, 0, stream>>>(Wf, wfTh, wfTl);
    round_f16<<<dim3(2048), blk, 0, stream>>>(f_f, ffh, 4194304);

    // Wc = W1 @ Wf -> f16 [512,1024]
    gemm_bf16_wc<<<dim3(8, 4), blk, 0, stream>>>(w1h, w1l, wfTh, wfTl, wcf,
                                                 1024, 512);
    // x1 = f_f @ Wc^T + bc
    gemm_f16<0, 0><<<dim3(4, 128), blk, 0, stream>>>(
        ffh, wcf, bc, xbuf, nullptr, nullptr, 512, 1024);
    leaky_scan<<<dim3(512), dim3(64), 0, stream>>>(xbuf, sbuf);
    gemm_f16<0, 0><<<dim3(4, 128), blk, 0, stream>>>(
        sbuf, w2f, b2, xbuf, nullptr, nullptr, 512, 512);
    leaky_scan<<<dim3(512), dim3(64), 0, stream>>>(xbuf, sbuf);
    // z-GEMM with fused MIL head -> part[8][M]
    gemm_f16<1, 2><<<dim3(4, 128), blk, 0, stream>>>(
        sbuf, m1f, Mb1, nullptr, uc, part, 512, 512);
    tail_topk<<<dim3(B_), dim3(64), 0, stream>>>(part, uc, out);
}

// Round 9
// 142.317 us; speedup vs baseline: 1.7789x; 1.1272x over previous
//
#include <hip/hip_runtime.h>
#include <math.h>

#define BETA 0.9f
#define THR 1.0f

constexpr int B_ = 64, T_ = 256, F_ = 1024, H_ = 512;
constexpr int M_ = B_ * T_;  // 16384 rows

typedef float f32x4 __attribute__((ext_vector_type(4)));
typedef short short8 __attribute__((ext_vector_type(8)));
typedef _Float16 half8 __attribute__((ext_vector_type(8)));
typedef unsigned short us4 __attribute__((ext_vector_type(4)));
typedef unsigned short ushort_t;

// ---- bf16 helpers (RNE) ----------------------------------------------------
static __device__ __forceinline__ unsigned short f2bf(float x) {
    unsigned b = __builtin_bit_cast(unsigned, x);
    unsigned r = (b + 0x7FFFu + ((b >> 16) & 1u)) >> 16;
    return (unsigned short)r;
}
static __device__ __forceinline__ float bf2f(unsigned short u) {
    unsigned v = ((unsigned)u) << 16;
    return __builtin_bit_cast(float, v);
}
// ---- f16 helpers ------------------------------------------------------------
static __device__ __forceinline__ unsigned short f2h(float x) {
    _Float16 h = (_Float16)x;
    return __builtin_bit_cast(unsigned short, h);
}
static __device__ __forceinline__ float h2f(unsigned short u) {
    return (float)__builtin_bit_cast(_Float16, u);
}
// XOR swizzle on 16B chunks within a 64B row; involution applied on the
// pre-swizzled GLDS source AND the ds_read (rule #21).
static __device__ __forceinline__ int swz(int r) {
    return ((r >> 2) & 3) ^ (r & 3);
}

#define GLDS(srcp, dstp)                                                      \
    __builtin_amdgcn_global_load_lds(                                         \
        (const __attribute__((address_space(1))) unsigned int*)(srcp),        \
        (__attribute__((address_space(3))) unsigned int*)(dstp), 16, 0, 0)

// ---------------------------------------------------------------------------
// Fused f16 GEMM + leaky scan. C = A @ Bw^T + bias -> LDS x[t][h] (f16) ->
// in-block scan over t (M-tile 256 = full T of one clip) -> spikes to Sout.
// Tile 256x128, BK=32, 8 waves (4M x 2N), 16x16x32 f16 MFMA, 1 product.
// Grid (N/128, M/256) = (4,64) = 256 wgs (nwg%8==0), XCD-bijective swizzle.
// LDS: scan buffer 256x136 f16 (69.6KB); staging aliases its first 24KB
// (A 256x32 = 16KB @ [0..8192), B 128x32 = 8KB @ [8192..12288) ushorts),
// barrier-separated from the epilogue reuse.
// ---------------------------------------------------------------------------
__global__ __launch_bounds__(512) void gemm_scan(
    const ushort_t* __restrict__ Ap, const ushort_t* __restrict__ Bp,
    const float* __restrict__ bias, ushort_t* __restrict__ Sout, int K) {
    __shared__ ushort_t lds[256 * 136];  // 69632 B

    const int tid = threadIdx.x;
    const int w = tid >> 6, l = tid & 63;
    const int nwg = gridDim.x * gridDim.y;  // 256
    const int flat = blockIdx.y * gridDim.x + blockIdx.x;
    const int wg = (flat & 7) * (nwg >> 3) + (flat >> 3);
    const int n0 = (wg % gridDim.x) * 128;
    const int bIdx = wg / gridDim.x;  // clip index, m0 = bIdx*256
    const int m0 = bIdx * 256;
    const int wr = w >> 1, wc = w & 1;  // 4M x 2N waves, 64x64 subtiles

    f32x4 acc[4][4];
#pragma unroll
    for (int mi = 0; mi < 4; ++mi)
#pragma unroll
        for (int ni = 0; ni < 4; ++ni) acc[mi][ni] = (f32x4){0.f, 0.f, 0.f, 0.f};

    const int c0 = l >> 4;
    for (int k0 = 0; k0 < K; k0 += 32) {
        __syncthreads();
        // staging: 24 segs of 1KB (A:16, B:8); 3 per wave; pre-swizzled src
#pragma unroll
        for (int j = 0; j < 3; ++j) {
            const int g = w * 3 + j;  // 0..23
            const bool isB = (g >= 16);
            const int seg = isB ? (g - 16) : g;
            const int r = seg * 16 + (l >> 2);
            const int ch = (l & 3) ^ swz(r);
            const ushort_t* pl = isB ? Bp : Ap;
            const int rb = isB ? n0 : m0;
            GLDS(pl + (size_t)(rb + r) * K + k0 + ch * 8,
                 &lds[(isB ? 8192 : 0) + seg * 512]);
        }
        __syncthreads();

        half8 aa[4], bb[4];
#pragma unroll
        for (int mi = 0; mi < 4; ++mi) {
            const int r = wr * 64 + mi * 16 + (l & 15);
            const int off = r * 32 + ((c0 ^ swz(r)) * 8);
            aa[mi] = __builtin_bit_cast(half8, *(const short8*)&lds[off]);
        }
#pragma unroll
        for (int ni = 0; ni < 4; ++ni) {
            const int r = wc * 64 + ni * 16 + (l & 15);
            const int off = r * 32 + ((c0 ^ swz(r)) * 8);
            bb[ni] = __builtin_bit_cast(half8, *(const short8*)&lds[8192 + off]);
        }

#pragma unroll
        for (int mi = 0; mi < 4; ++mi)
#pragma unroll
            for (int ni = 0; ni < 4; ++ni)
                acc[mi][ni] = __builtin_amdgcn_mfma_f32_16x16x32_f16(
                    aa[mi], bb[ni], acc[mi][ni], 0, 0, 0);
    }

    __syncthreads();  // all frag reads done before LDS reuse

    // acc(+bias) -> LDS x[t][h] f16, stride 136 (bank-spread across t)
    float bv[4];
#pragma unroll
    for (int ni = 0; ni < 4; ++ni) bv[ni] = bias[n0 + wc * 64 + ni * 16 + (l & 15)];
#pragma unroll
    for (int mi = 0; mi < 4; ++mi) {
        const int t0 = wr * 64 + mi * 16 + ((l >> 4) << 2);
#pragma unroll
        for (int ni = 0; ni < 4; ++ni) {
            const int h = wc * 64 + ni * 16 + (l & 15);
#pragma unroll
            for (int r = 0; r < 4; ++r)
                lds[(t0 + r) * 136 + h] = f2h(acc[mi][ni][r] + bv[ni]);
        }
    }
    __syncthreads();

    // scan: threads 0..127 each own one h column; snntorch Leaky subtract
    if (tid < 128) {
        const int h = tid;
        ushort_t* sp = Sout + (size_t)(m0) * 512 + n0 + h;
        float m = 0.f;
#pragma unroll 4
        for (int t = 0; t < T_; ++t) {
            const float xv = h2f(lds[t * 136 + h]);
            const float r = (m - THR > 0.f) ? THR : 0.f;
            m = BETA * m + xv - r;
            sp[(size_t)t * 512] = (m - THR > 0.f) ? (ushort_t)0x3C00 : (ushort_t)0;
        }
    }
}

// ---------------------------------------------------------------------------
// f16 MFMA GEMM (m97 structure), single product, fused MIL head epilogue:
// p = relu(C+bias) dot u over this wave's 64-col strip -> part[strip][row].
// Tile 128x128, BK=32, 4 waves (2x2). Grid (4, 128), nwg%8==0.
// ---------------------------------------------------------------------------
__global__ __launch_bounds__(256) void gemm_mil(
    const ushort_t* __restrict__ Ap, const ushort_t* __restrict__ Bp,
    const float* __restrict__ bias, const float* __restrict__ Uv,
    float* __restrict__ part, int N, int K) {
    __shared__ ushort_t lds[2 * 4096];

    const int tid = threadIdx.x;
    const int w = tid >> 6, l = tid & 63;
    const int nwg = gridDim.x * gridDim.y;
    const int flat = blockIdx.y * gridDim.x + blockIdx.x;
    const int wg = (flat & 7) * (nwg >> 3) + (flat >> 3);
    const int n0 = (wg % gridDim.x) * 128;
    const int m0 = (wg / gridDim.x) * 128;
    const int wr = w >> 1, wc = w & 1;

    f32x4 acc[4][4];
#pragma unroll
    for (int mi = 0; mi < 4; ++mi)
#pragma unroll
        for (int ni = 0; ni < 4; ++ni) acc[mi][ni] = (f32x4){0.f, 0.f, 0.f, 0.f};

    const int c0 = l >> 4;
    for (int k0 = 0; k0 < K; k0 += 32) {
        __syncthreads();
#pragma unroll
        for (int j = 0; j < 4; ++j) {
            const int g = w * 4 + j;  // 0..15
            const int p = g >> 3, seg = g & 7;
            const int r = seg * 16 + (l >> 2);
            const int ch = (l & 3) ^ swz(r);
            const ushort_t* pl = p ? Bp : Ap;
            const int rb = p ? n0 : m0;
            GLDS(pl + (size_t)(rb + r) * K + k0 + ch * 8,
                 &lds[p * 4096 + seg * 512]);
        }
        __syncthreads();

        half8 aa[4], bb[4];
#pragma unroll
        for (int mi = 0; mi < 4; ++mi) {
            const int r = wr * 64 + mi * 16 + (l & 15);
            const int off = r * 32 + ((c0 ^ swz(r)) * 8);
            aa[mi] = __builtin_bit_cast(half8, *(const short8*)&lds[off]);
        }
#pragma unroll
        for (int ni = 0; ni < 4; ++ni) {
            const int r = wc * 64 + ni * 16 + (l & 15);
            const int off = r * 32 + ((c0 ^ swz(r)) * 8);
            bb[ni] = __builtin_bit_cast(half8, *(const short8*)&lds[4096 + off]);
        }

#pragma unroll
        for (int mi = 0; mi < 4; ++mi)
#pragma unroll
            for (int ni = 0; ni < 4; ++ni)
                acc[mi][ni] = __builtin_amdgcn_mfma_f32_16x16x32_f16(
                    aa[mi], bb[ni], acc[mi][ni], 0, 0, 0);
    }

    // fused MIL: per row partial = sum_col relu(acc+bias)*u[col]
    float bv[4], uc[4];
#pragma unroll
    for (int ni = 0; ni < 4; ++ni) {
        const int col = n0 + wc * 64 + ni * 16 + (l & 15);
        bv[ni] = bias[col];
        uc[ni] = Uv[col];
    }
    const int strip = (n0 >> 6) + wc;  // 0..7
#pragma unroll
    for (int mi = 0; mi < 4; ++mi) {
        float p[4];
#pragma unroll
        for (int r = 0; r < 4; ++r) {
            float s = 0.f;
#pragma unroll
            for (int ni = 0; ni < 4; ++ni)
                s += fmaxf(acc[mi][ni][r] + bv[ni], 0.f) * uc[ni];
            p[r] = s;
        }
#pragma unroll
        for (int off = 1; off <= 8; off <<= 1)
#pragma unroll
            for (int r = 0; r < 4; ++r) p[r] += __shfl_xor(p[r], off);
        if ((l & 15) == 0) {
            const int row0 = m0 + wr * 64 + mi * 16 + ((l >> 4) << 2);
#pragma unroll
            for (int r = 0; r < 4; ++r)
                part[(size_t)strip * M_ + row0 + r] = p[r];
        }
    }
}

// ---------------------------------------------------------------------------
// Split-bf16 3-product GEMM (m97 structure) — only for Wc = W1 @ Wf.
// Emits single f16 plane.
// ---------------------------------------------------------------------------
__global__ __launch_bounds__(256) void gemm_bf16_wc(
    const ushort_t* __restrict__ Ah, const ushort_t* __restrict__ Al,
    const ushort_t* __restrict__ Bh, const ushort_t* __restrict__ Bl,
    ushort_t* __restrict__ Cout, int N, int K) {
    __shared__ ushort_t lds[4 * 4096];

    const int tid = threadIdx.x;
    const int w = tid >> 6, l = tid & 63;
    const int nwg = gridDim.x * gridDim.y;
    const int flat = blockIdx.y * gridDim.x + blockIdx.x;
    const int wg = (flat & 7) * (nwg >> 3) + (flat >> 3);
    const int n0 = (wg % gridDim.x) * 128;
    const int m0 = (wg / gridDim.x) * 128;
    const int wr = w >> 1, wc = w & 1;

    f32x4 acc[4][4];
#pragma unroll
    for (int mi = 0; mi < 4; ++mi)
#pragma unroll
        for (int ni = 0; ni < 4; ++ni) acc[mi][ni] = (f32x4){0.f, 0.f, 0.f, 0.f};

    const int c0 = l >> 4;
    for (int k0 = 0; k0 < K; k0 += 32) {
        __syncthreads();
#pragma unroll
        for (int j = 0; j < 8; ++j) {
            const int g = w * 8 + j;
            const int p = g >> 3, seg = g & 7;
            const int r = seg * 16 + (l >> 2);
            const int ch = (l & 3) ^ swz(r);
            const ushort_t* pl = (p == 0) ? Ah : (p == 1) ? Al : (p == 2) ? Bh : Bl;
            const int rb = (p < 2) ? m0 : n0;
            GLDS(pl + (size_t)(rb + r) * K + k0 + ch * 8,
                 &lds[p * 4096 + seg * 512]);
        }
        __syncthreads();

        short8 ah[4], al[4], bh[4], bl[4];
#pragma unroll
        for (int mi = 0; mi < 4; ++mi) {
            const int r = wr * 64 + mi * 16 + (l & 15);
            const int off = r * 32 + ((c0 ^ swz(r)) * 8);
            ah[mi] = *(const short8*)&lds[off];
            al[mi] = *(const short8*)&lds[4096 + off];
        }
#pragma unroll
        for (int ni = 0; ni < 4; ++ni) {
            const int r = wc * 64 + ni * 16 + (l & 15);
            const int off = r * 32 + ((c0 ^ swz(r)) * 8);
            bh[ni] = *(const short8*)&lds[8192 + off];
            bl[ni] = *(const short8*)&lds[12288 + off];
        }
#pragma unroll
        for (int mi = 0; mi < 4; ++mi)
#pragma unroll
            for (int ni = 0; ni < 4; ++ni) {
                acc[mi][ni] = __builtin_amdgcn_mfma_f32_16x16x32_bf16(
                    ah[mi], bh[ni], acc[mi][ni], 0, 0, 0);
                acc[mi][ni] = __builtin_amdgcn_mfma_f32_16x16x32_bf16(
                    ah[mi], bl[ni], acc[mi][ni], 0, 0, 0);
                acc[mi][ni] = __builtin_amdgcn_mfma_f32_16x16x32_bf16(
                    al[mi], bh[ni], acc[mi][ni], 0, 0, 0);
            }
    }

#pragma unroll
    for (int ni = 0; ni < 4; ++ni) {
        const int col = n0 + wc * 64 + ni * 16 + (l & 15);
#pragma unroll
        for (int mi = 0; mi < 4; ++mi) {
            const int row0 = m0 + wr * 64 + mi * 16 + ((l >> 4) << 2);
#pragma unroll
            for (int r = 0; r < 4; ++r)
                Cout[(size_t)(row0 + r) * N + col] = f2h(acc[mi][ni][r]);
        }
    }
}

// ---------------------------------------------------------------------------
// Sectioned prep (one launch):
//   [0,256):    W1 -> bf16 hi/lo planes
//   [256,512):  W2 -> f16
//   [512,768):  Mw1 -> f16
//   [768,896):  bc[j] = b1[j] + W1[j,:]@bf  (wave per j)
//   [896,898):  u[j] = Mw3@Mw2[:,j]; uc[512] = Mw3@Mb2+Mb3
//   [898,1410): Wf -> WfT bf16 hi/lo planes (32x32 transpose tiles)
// ---------------------------------------------------------------------------
__global__ __launch_bounds__(256) void prep_small(
    const float* __restrict__ W1, const float* __restrict__ W2,
    const float* __restrict__ Mw1, const float* __restrict__ bfv,
    const float* __restrict__ b1, const float* __restrict__ Mw2,
    const float* __restrict__ Mb2, const float* __restrict__ Mw3,
    const float* __restrict__ Mb3, const float* __restrict__ Wf,
    ushort_t* __restrict__ w1h, ushort_t* __restrict__ w1l,
    ushort_t* __restrict__ w2f, ushort_t* __restrict__ m1f,
    float* __restrict__ bc, float* __restrict__ uc,
    ushort_t* __restrict__ wfTh, ushort_t* __restrict__ wfTl) {
    __shared__ float tile[32][33];
    const int blk = blockIdx.x;
    const int tid = threadIdx.x;
    if (blk < 256) {
        const int i = blk * 256 + tid;
        f32x4 v = ((const f32x4*)W1)[i];
        us4 h, ll;
#pragma unroll
        for (int e = 0; e < 4; ++e) {
            const unsigned short hb = f2bf(v[e]);
            h[e] = hb;
            ll[e] = f2bf(v[e] - bf2f(hb));
        }
        ((us4*)w1h)[i] = h;
        ((us4*)w1l)[i] = ll;
    } else if (blk < 512) {
        const int i = (blk - 256) * 256 + tid;
        f32x4 v = ((const f32x4*)W2)[i];
        us4 h;
#pragma unroll
        for (int e = 0; e < 4; ++e) h[e] = f2h(v[e]);
        ((us4*)w2f)[i] = h;
    } else if (blk < 768) {
        const int i = (blk - 512) * 256 + tid;
        f32x4 v = ((const f32x4*)Mw1)[i];
        us4 h;
#pragma unroll
        for (int e = 0; e < 4; ++e) h[e] = f2h(v[e]);
        ((us4*)m1f)[i] = h;
    } else if (blk < 896) {
        const int w = tid >> 6, l = tid & 63;
        const int j = (blk - 768) * 4 + w;
        const float* row = W1 + (size_t)j * 512;
        float a = 0.f;
#pragma unroll
        for (int i = 0; i < 8; ++i) a += row[l + i * 64] * bfv[l + i * 64];
#pragma unroll
        for (int off = 32; off >= 1; off >>= 1) a += __shfl_xor(a, off);
        if (l == 0) bc[j] = a + b1[j];
    } else if (blk < 898) {
        const int j = (blk - 896) * 256 + tid;  // 0..511
        float a = 0.f;
        for (int i = 0; i < 32; ++i) a += Mw3[i] * Mw2[(size_t)i * 512 + j];
        uc[j] = a;
        if (j == 0) {
            float c = Mb3[0];
            for (int i = 0; i < 32; ++i) c += Mw3[i] * Mb2[i];
            uc[512] = c;
        }
    } else {
        const int idx = blk - 898;          // 0..511
        const int k0 = (idx & 31) * 32;     // Wf col tile
        const int i0 = (idx >> 5) * 32;     // Wf row tile
        const int tx = tid & 31;
        const int ty = tid >> 5;  // 0..7
#pragma unroll
        for (int e = 0; e < 4; ++e) {
            const int i = ty + e * 8;
            tile[i][tx] = Wf[(size_t)(i0 + i) * 1024 + k0 + tx];
        }
        __syncthreads();
#pragma unroll
        for (int e = 0; e < 4; ++e) {
            const int kk = ty + e * 8;
            const float v = tile[tx][kk];
            const unsigned short h = f2bf(v);
            wfTh[(size_t)(k0 + kk) * 512 + i0 + tx] = h;
            wfTl[(size_t)(k0 + kk) * 512 + i0 + tx] = f2bf(v - bf2f(h));
        }
    }
}

// ---------------------------------------------------------------------------
// f32 -> single f16 plane round (f_f).
// ---------------------------------------------------------------------------
__global__ __launch_bounds__(256) void round_f16(const float* __restrict__ x,
                                                 ushort_t* __restrict__ o,
                                                 int n4) {
    int i = blockIdx.x * 256 + threadIdx.x;
    const int stride = gridDim.x * 256;
    for (; i < n4; i += stride) {
        f32x4 v = ((const f32x4*)x)[i];
        us4 h;
#pragma unroll
        for (int e = 0; e < 4; ++e) h[e] = f2h(v[e]);
        ((us4*)o)[i] = h;
    }
}

// ---------------------------------------------------------------------------
// Tail: pre[row] = sum_{s<8} part[s][row] + c; top-17 on pre (sigmoid
// monotonic), mean of sigmoid(selected). One wave per clip.
// ---------------------------------------------------------------------------
__global__ __launch_bounds__(64) void tail_topk(const float* __restrict__ part,
                                                const float* __restrict__ uc,
                                                float* __restrict__ out) {
    const int b = blockIdx.x;
    const int lane = threadIdx.x;
    const float c = uc[512];
    float v[4];
#pragma unroll
    for (int i = 0; i < 4; ++i) {
        const int row = b * T_ + lane + i * 64;
        float a = 0.f;
#pragma unroll
        for (int s = 0; s < 8; ++s) a += part[(size_t)s * M_ + row];
        v[i] = a + c;
    }
    float sum = 0.f;
    for (int iter = 0; iter < 17; ++iter) {
        float mv = v[0];
        int mslot = 0;
#pragma unroll
        for (int i = 1; i < 4; ++i)
            if (v[i] > mv) { mv = v[i]; mslot = i; }
        float bv = mv;
        int bl = lane, bs = mslot;
#pragma unroll
        for (int off = 32; off >= 1; off >>= 1) {
            const float ov = __shfl_xor(bv, off);
            const int ol = __shfl_xor(bl, off);
            const int os = __shfl_xor(bs, off);
            if (ov > bv || (ov == bv && ol < bl)) { bv = ov; bl = ol; bs = os; }
        }
        sum += 1.f / (1.f + expf(-bv));
        if (lane == bl) v[bs] = -1e30f;
    }
    if (lane == 0) out[b] = sum * (1.f / 17.f);
}

// ---------------------------------------------------------------------------
// Orchestration (7 launches):
//   prep_small (incl. Wf transpose); round_f16(f_f)
//   wcf   <- gemm_bf16_wc(W1 planes @ WfT^T)
//   sbuf1 <- gemm_scan(ffh @ wcf^T + bc)        [x1 + scan1 fused]
//   sbuf2 <- gemm_scan(sbuf1 @ w2f^T + b2)      [x2 + scan2 fused]
//   part  <- gemm_mil(sbuf2 @ m1f^T + Mb1, relu, dot u)
//   out   <- tail_topk(part)
// ---------------------------------------------------------------------------
extern "C" void kernel_launch(void* const* d_in, const int* in_sizes, int n_in,
                              void* d_out, int out_size, void* d_ws, size_t ws_size,
                              hipStream_t stream) {
    const float* f_f = (const float*)d_in[0];
    const float* Wf  = (const float*)d_in[2];
    const float* bf  = (const float*)d_in[3];
    const float* W1  = (const float*)d_in[4];
    const float* b1  = (const float*)d_in[5];
    const float* W2  = (const float*)d_in[6];
    const float* b2  = (const float*)d_in[7];
    const float* Mw1 = (const float*)d_in[8];
    const float* Mb1 = (const float*)d_in[9];
    const float* Mw2 = (const float*)d_in[10];
    const float* Mb2 = (const float*)d_in[11];
    const float* Mw3 = (const float*)d_in[12];
    const float* Mb3 = (const float*)d_in[13];
    float* out = (float*)d_out;

    char* ws = (char*)d_ws;
    const size_t NEf = (size_t)M_ * F_;  // 16.78M elems
    const size_t NE = (size_t)M_ * H_;   // 8.39M elems
    ushort_t* ffh = (ushort_t*)ws;                       // f16 f_f [M,1024]
    ushort_t* sbuf1 = ffh + NEf;                         // f16 spikes 1
    ushort_t* sbuf2 = sbuf1 + NE;                        // f16 spikes 2
    ushort_t* w1h = sbuf2 + NE;                          // bf16 (wc input)
    ushort_t* w1l = w1h + 262144;
    ushort_t* w2f = w1l + 262144;                        // f16 single
    ushort_t* m1f = w2f + 262144;                        // f16 single
    ushort_t* wfTh = m1f + 262144;                       // bf16 [1024,512]
    ushort_t* wfTl = wfTh + 524288;
    ushort_t* wcf = wfTl + 524288;                       // f16 [512,1024]
    float* bc = (float*)(wcf + 524288);
    float* uc = bc + 512;                                // u[512] + c
    float* part = uc + 513 + 63;                         // [8][16384] f32

    const dim3 blk(256);

    prep_small<<<dim3(1410), blk, 0, stream>>>(W1, W2, Mw1, bf, b1, Mw2, Mb2,
                                               Mw3, Mb3, Wf, w1h, w1l, w2f,
                                               m1f, bc, uc, wfTh, wfTl);
    round_f16<<<dim3(2048), blk, 0, stream>>>(f_f, ffh, 4194304);

    // Wc = W1 @ Wf -> f16 [512,1024]
    gemm_bf16_wc<<<dim3(8, 4), blk, 0, stream>>>(w1h, w1l, wfTh, wfTl, wcf,
                                                 1024, 512);
    // x1 = f_f @ Wc^T + bc, fused scan1 -> sbuf1
    gemm_scan<<<dim3(4, 64), dim3(512), 0, stream>>>(ffh, wcf, bc, sbuf1, 1024);
    // x2 = sbuf1 @ W2^T + b2, fused scan2 -> sbuf2
    gemm_scan<<<dim3(4, 64), dim3(512), 0, stream>>>(sbuf1, w2f, b2, sbuf2, 512);
    // z-GEMM with fused MIL head -> part[8][M]
    gemm_mil<<<dim3(4, 128), blk, 0, stream>>>(sbuf2, m1f, Mb1, uc, part,
                                               512, 512);
    tail_topk<<<dim3(B_), dim3(64), 0, stream>>>(part, uc, out);
}

// Round 10
// 135.782 us; speedup vs baseline: 1.8645x; 1.0481x over previous
//
#include <hip/hip_runtime.h>
#include <math.h>

#define BETA 0.9f
#define THR 1.0f

constexpr int B_ = 64, T_ = 256, F_ = 1024, H_ = 512;
constexpr int M_ = B_ * T_;  // 16384 rows

typedef float f32x4 __attribute__((ext_vector_type(4)));
typedef short short8 __attribute__((ext_vector_type(8)));
typedef _Float16 half8 __attribute__((ext_vector_type(8)));
typedef unsigned short us4 __attribute__((ext_vector_type(4)));
typedef unsigned short ushort_t;

// ---- bf16 helpers (RNE) ----------------------------------------------------
static __device__ __forceinline__ unsigned short f2bf(float x) {
    unsigned b = __builtin_bit_cast(unsigned, x);
    unsigned r = (b + 0x7FFFu + ((b >> 16) & 1u)) >> 16;
    return (unsigned short)r;
}
static __device__ __forceinline__ float bf2f(unsigned short u) {
    unsigned v = ((unsigned)u) << 16;
    return __builtin_bit_cast(float, v);
}
// ---- f16 helpers ------------------------------------------------------------
static __device__ __forceinline__ unsigned short f2h(float x) {
    _Float16 h = (_Float16)x;
    return __builtin_bit_cast(unsigned short, h);
}
static __device__ __forceinline__ float h2f(unsigned short u) {
    return (float)__builtin_bit_cast(_Float16, u);
}
// XOR swizzle on 16B chunks within a 64B row; involution applied on the
// pre-swizzled GLDS source AND the ds_read (rule #21).
static __device__ __forceinline__ int swz(int r) {
    return ((r >> 2) & 3) ^ (r & 3);
}

#define GLDS(srcp, dstp)                                                      \
    __builtin_amdgcn_global_load_lds(                                         \
        (const __attribute__((address_space(1))) unsigned int*)(srcp),        \
        (__attribute__((address_space(3))) unsigned int*)(dstp), 16, 0, 0)

// ---------------------------------------------------------------------------
// Fused f16 GEMM + leaky scan, occupancy-restored geometry.
// C = A @ Bw^T + bias -> LDS x[t][h] f16 -> in-block scan over t -> spikes.
// Tile 256M x 64N, BK=32, 256 threads (4 waves, each 64x64 subtile).
// Grid (H/64, B) = (8,64) = 512 wgs -> 2 blocks/CU (LDS 36.9KB).
// LDS: scan buffer 256x72 f16 (36.9KB); staging aliased in first 20KB
// (A 256x32 @ [0..8192) ushorts, B 64x32 @ [8192..10240)), barrier-separated.
// ---------------------------------------------------------------------------
__global__ __launch_bounds__(256) void gemm_scan(
    const ushort_t* __restrict__ Ap, const ushort_t* __restrict__ Bp,
    const float* __restrict__ bias, ushort_t* __restrict__ Sout, int K) {
    __shared__ ushort_t lds[256 * 72];  // 36864 B

    const int tid = threadIdx.x;
    const int w = tid >> 6, l = tid & 63;
    const int nwg = gridDim.x * gridDim.y;  // 512
    const int flat = blockIdx.y * gridDim.x + blockIdx.x;
    const int wg = (flat & 7) * (nwg >> 3) + (flat >> 3);
    const int n0 = (wg % gridDim.x) * 64;
    const int bIdx = wg / gridDim.x;  // clip index
    const int m0 = bIdx * 256;

    f32x4 acc[4][4];
#pragma unroll
    for (int mi = 0; mi < 4; ++mi)
#pragma unroll
        for (int ni = 0; ni < 4; ++ni) acc[mi][ni] = (f32x4){0.f, 0.f, 0.f, 0.f};

    const int c0 = l >> 4;
    for (int k0 = 0; k0 < K; k0 += 32) {
        __syncthreads();
        // staging: 20 segs of 1KB (A:16, B:4); 5 per wave; pre-swizzled src
#pragma unroll
        for (int j = 0; j < 5; ++j) {
            const int seg = w * 5 + j;  // 0..19
            if (seg < 16) {
                const int r = seg * 16 + (l >> 2);
                GLDS(Ap + (size_t)(m0 + r) * K + k0 + (((l & 3) ^ swz(r)) * 8),
                     &lds[seg * 512]);
            } else {
                const int r = (seg - 16) * 16 + (l >> 2);
                GLDS(Bp + (size_t)(n0 + r) * K + k0 + (((l & 3) ^ swz(r)) * 8),
                     &lds[8192 + (seg - 16) * 512]);
            }
        }
        __syncthreads();

        half8 aa[4], bb[4];
#pragma unroll
        for (int mi = 0; mi < 4; ++mi) {
            const int r = w * 64 + mi * 16 + (l & 15);
            const int off = r * 32 + ((c0 ^ swz(r)) * 8);
            aa[mi] = __builtin_bit_cast(half8, *(const short8*)&lds[off]);
        }
#pragma unroll
        for (int ni = 0; ni < 4; ++ni) {
            const int r = ni * 16 + (l & 15);
            const int off = 8192 + r * 32 + ((c0 ^ swz(r)) * 8);
            bb[ni] = __builtin_bit_cast(half8, *(const short8*)&lds[off]);
        }

#pragma unroll
        for (int mi = 0; mi < 4; ++mi)
#pragma unroll
            for (int ni = 0; ni < 4; ++ni)
                acc[mi][ni] = __builtin_amdgcn_mfma_f32_16x16x32_f16(
                    aa[mi], bb[ni], acc[mi][ni], 0, 0, 0);
    }

    __syncthreads();  // all frag reads done before LDS reuse

    // acc(+bias) -> LDS x[t][h] f16, stride 72
    float bv[4];
#pragma unroll
    for (int ni = 0; ni < 4; ++ni) bv[ni] = bias[n0 + ni * 16 + (l & 15)];
#pragma unroll
    for (int mi = 0; mi < 4; ++mi) {
        const int t0 = w * 64 + mi * 16 + ((l >> 4) << 2);
#pragma unroll
        for (int ni = 0; ni < 4; ++ni) {
            const int h = ni * 16 + (l & 15);
#pragma unroll
            for (int r = 0; r < 4; ++r)
                lds[(t0 + r) * 72 + h] = f2h(acc[mi][ni][r] + bv[ni]);
        }
    }
    __syncthreads();

    // scan: threads 0..63 each own one h column; snntorch Leaky subtract
    if (tid < 64) {
        const int h = tid;
        ushort_t* sp = Sout + (size_t)m0 * 512 + n0 + h;
        float m = 0.f;
#pragma unroll 4
        for (int t = 0; t < T_; ++t) {
            const float xv = h2f(lds[t * 72 + h]);
            const float r = (m - THR > 0.f) ? THR : 0.f;
            m = BETA * m + xv - r;
            sp[(size_t)t * 512] = (m - THR > 0.f) ? (ushort_t)0x3C00 : (ushort_t)0;
        }
    }
}

// ---------------------------------------------------------------------------
// f16 MFMA GEMM (m97 structure), single product, fused MIL head epilogue:
// p = relu(C+bias) dot u over this wave's 64-col strip -> part[strip][row].
// Tile 128x128, BK=32, 4 waves (2x2). Grid (4, 128), nwg%8==0.
// ---------------------------------------------------------------------------
__global__ __launch_bounds__(256) void gemm_mil(
    const ushort_t* __restrict__ Ap, const ushort_t* __restrict__ Bp,
    const float* __restrict__ bias, const float* __restrict__ Uv,
    float* __restrict__ part, int N, int K) {
    __shared__ ushort_t lds[2 * 4096];

    const int tid = threadIdx.x;
    const int w = tid >> 6, l = tid & 63;
    const int nwg = gridDim.x * gridDim.y;
    const int flat = blockIdx.y * gridDim.x + blockIdx.x;
    const int wg = (flat & 7) * (nwg >> 3) + (flat >> 3);
    const int n0 = (wg % gridDim.x) * 128;
    const int m0 = (wg / gridDim.x) * 128;
    const int wr = w >> 1, wc = w & 1;

    f32x4 acc[4][4];
#pragma unroll
    for (int mi = 0; mi < 4; ++mi)
#pragma unroll
        for (int ni = 0; ni < 4; ++ni) acc[mi][ni] = (f32x4){0.f, 0.f, 0.f, 0.f};

    const int c0 = l >> 4;
    for (int k0 = 0; k0 < K; k0 += 32) {
        __syncthreads();
#pragma unroll
        for (int j = 0; j < 4; ++j) {
            const int g = w * 4 + j;  // 0..15
            const int p = g >> 3, seg = g & 7;
            const int r = seg * 16 + (l >> 2);
            const int ch = (l & 3) ^ swz(r);
            const ushort_t* pl = p ? Bp : Ap;
            const int rb = p ? n0 : m0;
            GLDS(pl + (size_t)(rb + r) * K + k0 + ch * 8,
                 &lds[p * 4096 + seg * 512]);
        }
        __syncthreads();

        half8 aa[4], bb[4];
#pragma unroll
        for (int mi = 0; mi < 4; ++mi) {
            const int r = wr * 64 + mi * 16 + (l & 15);
            const int off = r * 32 + ((c0 ^ swz(r)) * 8);
            aa[mi] = __builtin_bit_cast(half8, *(const short8*)&lds[off]);
        }
#pragma unroll
        for (int ni = 0; ni < 4; ++ni) {
            const int r = wc * 64 + ni * 16 + (l & 15);
            const int off = r * 32 + ((c0 ^ swz(r)) * 8);
            bb[ni] = __builtin_bit_cast(half8, *(const short8*)&lds[4096 + off]);
        }

#pragma unroll
        for (int mi = 0; mi < 4; ++mi)
#pragma unroll
            for (int ni = 0; ni < 4; ++ni)
                acc[mi][ni] = __builtin_amdgcn_mfma_f32_16x16x32_f16(
                    aa[mi], bb[ni], acc[mi][ni], 0, 0, 0);
    }

    // fused MIL: per row partial = sum_col relu(acc+bias)*u[col]
    float bv[4], uc[4];
#pragma unroll
    for (int ni = 0; ni < 4; ++ni) {
        const int col = n0 + wc * 64 + ni * 16 + (l & 15);
        bv[ni] = bias[col];
        uc[ni] = Uv[col];
    }
    const int strip = (n0 >> 6) + wc;  // 0..7
#pragma unroll
    for (int mi = 0; mi < 4; ++mi) {
        float p[4];
#pragma unroll
        for (int r = 0; r < 4; ++r) {
            float s = 0.f;
#pragma unroll
            for (int ni = 0; ni < 4; ++ni)
                s += fmaxf(acc[mi][ni][r] + bv[ni], 0.f) * uc[ni];
            p[r] = s;
        }
#pragma unroll
        for (int off = 1; off <= 8; off <<= 1)
#pragma unroll
            for (int r = 0; r < 4; ++r) p[r] += __shfl_xor(p[r], off);
        if ((l & 15) == 0) {
            const int row0 = m0 + wr * 64 + mi * 16 + ((l >> 4) << 2);
#pragma unroll
            for (int r = 0; r < 4; ++r)
                part[(size_t)strip * M_ + row0 + r] = p[r];
        }
    }
}

// ---------------------------------------------------------------------------
// Split-bf16 3-product GEMM (m97 structure) — only for Wc = W1 @ Wf.
// Emits single f16 plane.
// ---------------------------------------------------------------------------
__global__ __launch_bounds__(256) void gemm_bf16_wc(
    const ushort_t* __restrict__ Ah, const ushort_t* __restrict__ Al,
    const ushort_t* __restrict__ Bh, const ushort_t* __restrict__ Bl,
    ushort_t* __restrict__ Cout, int N, int K) {
    __shared__ ushort_t lds[4 * 4096];

    const int tid = threadIdx.x;
    const int w = tid >> 6, l = tid & 63;
    const int nwg = gridDim.x * gridDim.y;
    const int flat = blockIdx.y * gridDim.x + blockIdx.x;
    const int wg = (flat & 7) * (nwg >> 3) + (flat >> 3);
    const int n0 = (wg % gridDim.x) * 128;
    const int m0 = (wg / gridDim.x) * 128;
    const int wr = w >> 1, wc = w & 1;

    f32x4 acc[4][4];
#pragma unroll
    for (int mi = 0; mi < 4; ++mi)
#pragma unroll
        for (int ni = 0; ni < 4; ++ni) acc[mi][ni] = (f32x4){0.f, 0.f, 0.f, 0.f};

    const int c0 = l >> 4;
    for (int k0 = 0; k0 < K; k0 += 32) {
        __syncthreads();
#pragma unroll
        for (int j = 0; j < 8; ++j) {
            const int g = w * 8 + j;
            const int p = g >> 3, seg = g & 7;
            const int r = seg * 16 + (l >> 2);
            const int ch = (l & 3) ^ swz(r);
            const ushort_t* pl = (p == 0) ? Ah : (p == 1) ? Al : (p == 2) ? Bh : Bl;
            const int rb = (p < 2) ? m0 : n0;
            GLDS(pl + (size_t)(rb + r) * K + k0 + ch * 8,
                 &lds[p * 4096 + seg * 512]);
        }
        __syncthreads();

        short8 ah[4], al[4], bh[4], bl[4];
#pragma unroll
        for (int mi = 0; mi < 4; ++mi) {
            const int r = wr * 64 + mi * 16 + (l & 15);
            const int off = r * 32 + ((c0 ^ swz(r)) * 8);
            ah[mi] = *(const short8*)&lds[off];
            al[mi] = *(const short8*)&lds[4096 + off];
        }
#pragma unroll
        for (int ni = 0; ni < 4; ++ni) {
            const int r = wc * 64 + ni * 16 + (l & 15);
            const int off = r * 32 + ((c0 ^ swz(r)) * 8);
            bh[ni] = *(const short8*)&lds[8192 + off];
            bl[ni] = *(const short8*)&lds[12288 + off];
        }
#pragma unroll
        for (int mi = 0; mi < 4; ++mi)
#pragma unroll
            for (int ni = 0; ni < 4; ++ni) {
                acc[mi][ni] = __builtin_amdgcn_mfma_f32_16x16x32_bf16(
                    ah[mi], bh[ni], acc[mi][ni], 0, 0, 0);
                acc[mi][ni] = __builtin_amdgcn_mfma_f32_16x16x32_bf16(
                    ah[mi], bl[ni], acc[mi][ni], 0, 0, 0);
                acc[mi][ni] = __builtin_amdgcn_mfma_f32_16x16x32_bf16(
                    al[mi], bh[ni], acc[mi][ni], 0, 0, 0);
            }
    }

#pragma unroll
    for (int ni = 0; ni < 4; ++ni) {
        const int col = n0 + wc * 64 + ni * 16 + (l & 15);
#pragma unroll
        for (int mi = 0; mi < 4; ++mi) {
            const int row0 = m0 + wr * 64 + mi * 16 + ((l >> 4) << 2);
#pragma unroll
            for (int r = 0; r < 4; ++r)
                Cout[(size_t)(row0 + r) * N + col] = f2h(acc[mi][ni][r]);
        }
    }
}

// ---------------------------------------------------------------------------
// Sectioned prep (one launch):
//   [0,256):    W1 -> bf16 hi/lo planes
//   [256,512):  W2 -> f16
//   [512,768):  Mw1 -> f16
//   [768,896):  bc[j] = b1[j] + W1[j,:]@bf  (wave per j)
//   [896,898):  u[j] = Mw3@Mw2[:,j]; uc[512] = Mw3@Mb2+Mb3
//   [898,1410): Wf -> WfT bf16 hi/lo planes (32x32 transpose tiles)
// ---------------------------------------------------------------------------
__global__ __launch_bounds__(256) void prep_small(
    const float* __restrict__ W1, const float* __restrict__ W2,
    const float* __restrict__ Mw1, const float* __restrict__ bfv,
    const float* __restrict__ b1, const float* __restrict__ Mw2,
    const float* __restrict__ Mb2, const float* __restrict__ Mw3,
    const float* __restrict__ Mb3, const float* __restrict__ Wf,
    ushort_t* __restrict__ w1h, ushort_t* __restrict__ w1l,
    ushort_t* __restrict__ w2f, ushort_t* __restrict__ m1f,
    float* __restrict__ bc, float* __restrict__ uc,
    ushort_t* __restrict__ wfTh, ushort_t* __restrict__ wfTl) {
    __shared__ float tile[32][33];
    const int blk = blockIdx.x;
    const int tid = threadIdx.x;
    if (blk < 256) {
        const int i = blk * 256 + tid;
        f32x4 v = ((const f32x4*)W1)[i];
        us4 h, ll;
#pragma unroll
        for (int e = 0; e < 4; ++e) {
            const unsigned short hb = f2bf(v[e]);
            h[e] = hb;
            ll[e] = f2bf(v[e] - bf2f(hb));
        }
        ((us4*)w1h)[i] = h;
        ((us4*)w1l)[i] = ll;
    } else if (blk < 512) {
        const int i = (blk - 256) * 256 + tid;
        f32x4 v = ((const f32x4*)W2)[i];
        us4 h;
#pragma unroll
        for (int e = 0; e < 4; ++e) h[e] = f2h(v[e]);
        ((us4*)w2f)[i] = h;
    } else if (blk < 768) {
        const int i = (blk - 512) * 256 + tid;
        f32x4 v = ((const f32x4*)Mw1)[i];
        us4 h;
#pragma unroll
        for (int e = 0; e < 4; ++e) h[e] = f2h(v[e]);
        ((us4*)m1f)[i] = h;
    } else if (blk < 896) {
        const int w = tid >> 6, l = tid & 63;
        const int j = (blk - 768) * 4 + w;
        const float* row = W1 + (size_t)j * 512;
        float a = 0.f;
#pragma unroll
        for (int i = 0; i < 8; ++i) a += row[l + i * 64] * bfv[l + i * 64];
#pragma unroll
        for (int off = 32; off >= 1; off >>= 1) a += __shfl_xor(a, off);
        if (l == 0) bc[j] = a + b1[j];
    } else if (blk < 898) {
        const int j = (blk - 896) * 256 + tid;  // 0..511
        float a = 0.f;
        for (int i = 0; i < 32; ++i) a += Mw3[i] * Mw2[(size_t)i * 512 + j];
        uc[j] = a;
        if (j == 0) {
            float c = Mb3[0];
            for (int i = 0; i < 32; ++i) c += Mw3[i] * Mb2[i];
            uc[512] = c;
        }
    } else {
        const int idx = blk - 898;          // 0..511
        const int k0 = (idx & 31) * 32;     // Wf col tile
        const int i0 = (idx >> 5) * 32;     // Wf row tile
        const int tx = tid & 31;
        const int ty = tid >> 5;  // 0..7
#pragma unroll
        for (int e = 0; e < 4; ++e) {
            const int i = ty + e * 8;
            tile[i][tx] = Wf[(size_t)(i0 + i) * 1024 + k0 + tx];
        }
        __syncthreads();
#pragma unroll
        for (int e = 0; e < 4; ++e) {
            const int kk = ty + e * 8;
            const float v = tile[tx][kk];
            const unsigned short h = f2bf(v);
            wfTh[(size_t)(k0 + kk) * 512 + i0 + tx] = h;
            wfTl[(size_t)(k0 + kk) * 512 + i0 + tx] = f2bf(v - bf2f(h));
        }
    }
}

// ---------------------------------------------------------------------------
// f32 -> single f16 plane round (f_f).
// ---------------------------------------------------------------------------
__global__ __launch_bounds__(256) void round_f16(const float* __restrict__ x,
                                                 ushort_t* __restrict__ o,
                                                 int n4) {
    int i = blockIdx.x * 256 + threadIdx.x;
    const int stride = gridDim.x * 256;
    for (; i < n4; i += stride) {
        f32x4 v = ((const f32x4*)x)[i];
        us4 h;
#pragma unroll
        for (int e = 0; e < 4; ++e) h[e] = f2h(v[e]);
        ((us4*)o)[i] = h;
    }
}

// ---------------------------------------------------------------------------
// Tail: pre[row] = sum_{s<8} part[s][row] + c; top-17 on pre (sigmoid
// monotonic), mean of sigmoid(selected). One wave per clip.
// ---------------------------------------------------------------------------
__global__ __launch_bounds__(64) void tail_topk(const float* __restrict__ part,
                                                const float* __restrict__ uc,
                                                float* __restrict__ out) {
    const int b = blockIdx.x;
    const int lane = threadIdx.x;
    const float c = uc[512];
    float v[4];
#pragma unroll
    for (int i = 0; i < 4; ++i) {
        const int row = b * T_ + lane + i * 64;
        float a = 0.f;
#pragma unroll
        for (int s = 0; s < 8; ++s) a += part[(size_t)s * M_ + row];
        v[i] = a + c;
    }
    float sum = 0.f;
    for (int iter = 0; iter < 17; ++iter) {
        float mv = v[0];
        int mslot = 0;
#pragma unroll
        for (int i = 1; i < 4; ++i)
            if (v[i] > mv) { mv = v[i]; mslot = i; }
        float bv = mv;
        int bl = lane, bs = mslot;
#pragma unroll
        for (int off = 32; off >= 1; off >>= 1) {
            const float ov = __shfl_xor(bv, off);
            const int ol = __shfl_xor(bl, off);
            const int os = __shfl_xor(bs, off);
            if (ov > bv || (ov == bv && ol < bl)) { bv = ov; bl = ol; bs = os; }
        }
        sum += 1.f / (1.f + expf(-bv));
        if (lane == bl) v[bs] = -1e30f;
    }
    if (lane == 0) out[b] = sum * (1.f / 17.f);
}

// ---------------------------------------------------------------------------
// Orchestration (7 launches):
//   prep_small (incl. Wf transpose); round_f16(f_f)
//   wcf   <- gemm_bf16_wc(W1 planes @ WfT^T)
//   sbuf1 <- gemm_scan(ffh @ wcf^T + bc)        [x1 + scan1 fused]
//   sbuf2 <- gemm_scan(sbuf1 @ w2f^T + b2)      [x2 + scan2 fused]
//   part  <- gemm_mil(sbuf2 @ m1f^T + Mb1, relu, dot u)
//   out   <- tail_topk(part)
// ---------------------------------------------------------------------------
extern "C" void kernel_launch(void* const* d_in, const int* in_sizes, int n_in,
                              void* d_out, int out_size, void* d_ws, size_t ws_size,
                              hipStream_t stream) {
    const float* f_f = (const float*)d_in[0];
    const float* Wf  = (const float*)d_in[2];
    const float* bf  = (const float*)d_in[3];
    const float* W1  = (const float*)d_in[4];
    const float* b1  = (const float*)d_in[5];
    const float* W2  = (const float*)d_in[6];
    const float* b2  = (const float*)d_in[7];
    const float* Mw1 = (const float*)d_in[8];
    const float* Mb1 = (const float*)d_in[9];
    const float* Mw2 = (const float*)d_in[10];
    const float* Mb2 = (const float*)d_in[11];
    const float* Mw3 = (const float*)d_in[12];
    const float* Mb3 = (const float*)d_in[13];
    float* out = (float*)d_out;

    char* ws = (char*)d_ws;
    const size_t NEf = (size_t)M_ * F_;  // 16.78M elems
    const size_t NE = (size_t)M_ * H_;   // 8.39M elems
    ushort_t* ffh = (ushort_t*)ws;                       // f16 f_f [M,1024]
    ushort_t* sbuf1 = ffh + NEf;                         // f16 spikes 1
    ushort_t* sbuf2 = sbuf1 + NE;                        // f16 spikes 2
    ushort_t* w1h = sbuf2 + NE;                          // bf16 (wc input)
    ushort_t* w1l = w1h + 262144;
    ushort_t* w2f = w1l + 262144;                        // f16 single
    ushort_t* m1f = w2f + 262144;                        // f16 single
    ushort_t* wfTh = m1f + 262144;                       // bf16 [1024,512]
    ushort_t* wfTl = wfTh + 524288;
    ushort_t* wcf = wfTl + 524288;                       // f16 [512,1024]
    float* bc = (float*)(wcf + 524288);
    float* uc = bc + 512;                                // u[512] + c
    float* part = uc + 513 + 63;                         // [8][16384] f32

    const dim3 blk(256);

    prep_small<<<dim3(1410), blk, 0, stream>>>(W1, W2, Mw1, bf, b1, Mw2, Mb2,
                                               Mw3, Mb3, Wf, w1h, w1l, w2f,
                                               m1f, bc, uc, wfTh, wfTl);
    round_f16<<<dim3(2048), blk, 0, stream>>>(f_f, ffh, 4194304);

    // Wc = W1 @ Wf -> f16 [512,1024]
    gemm_bf16_wc<<<dim3(8, 4), blk, 0, stream>>>(w1h, w1l, wfTh, wfTl, wcf,
                                                 1024, 512);
    // x1 = f_f @ Wc^T + bc, fused scan1 -> sbuf1
    gemm_scan<<<dim3(8, 64), blk, 0, stream>>>(ffh, wcf, bc, sbuf1, 1024);
    // x2 = sbuf1 @ W2^T + b2, fused scan2 -> sbuf2
    gemm_scan<<<dim3(8, 64), blk, 0, stream>>>(sbuf1, w2f, b2, sbuf2, 512);
    // z-GEMM with fused MIL head -> part[8][M]
    gemm_mil<<<dim3(4, 128), blk, 0, stream>>>(sbuf2, m1f, Mb1, uc, part,
                                               512, 512);
    tail_topk<<<dim3(B_), dim3(64), 0, stream>>>(part, uc, out);
}

// Round 11
// 124.904 us; speedup vs baseline: 2.0269x; 1.0871x over previous
//
#include <hip/hip_runtime.h>
#include <math.h>

#define BETA 0.9f
#define THR 1.0f

constexpr int B_ = 64, T_ = 256, F_ = 1024, H_ = 512;
constexpr int M_ = B_ * T_;  // 16384 rows

typedef float f32x4 __attribute__((ext_vector_type(4)));
typedef short short8 __attribute__((ext_vector_type(8)));
typedef _Float16 half8 __attribute__((ext_vector_type(8)));
typedef unsigned short us4 __attribute__((ext_vector_type(4)));
typedef unsigned short ushort_t;

// ---- bf16 helpers (RNE) ----------------------------------------------------
static __device__ __forceinline__ unsigned short f2bf(float x) {
    unsigned b = __builtin_bit_cast(unsigned, x);
    unsigned r = (b + 0x7FFFu + ((b >> 16) & 1u)) >> 16;
    return (unsigned short)r;
}
static __device__ __forceinline__ float bf2f(unsigned short u) {
    unsigned v = ((unsigned)u) << 16;
    return __builtin_bit_cast(float, v);
}
// ---- f16 helpers ------------------------------------------------------------
static __device__ __forceinline__ unsigned short f2h(float x) {
    _Float16 h = (_Float16)x;
    return __builtin_bit_cast(unsigned short, h);
}
static __device__ __forceinline__ float h2f(unsigned short u) {
    return (float)__builtin_bit_cast(_Float16, u);
}
// BK=32 swizzle (64B rows, 4 chunks) — used by gemm_bf16_wc only.
static __device__ __forceinline__ int swz(int r) {
    return ((r >> 2) & 3) ^ (r & 3);
}

#define GLDS(srcp, dstp)                                                      \
    __builtin_amdgcn_global_load_lds(                                         \
        (const __attribute__((address_space(1))) unsigned int*)(srcp),        \
        (__attribute__((address_space(3))) unsigned int*)(dstp), 16, 0, 0)

// ---------------------------------------------------------------------------
// Fused f16 GEMM + leaky scan, BK=64.
// C = A @ Bw^T + bias -> LDS x[t][h] f16 -> in-block scan over t -> spikes.
// Tile 256M x 64N, 256 threads (4 waves, each 64x64 subtile), 16 K-iters max.
// Grid (8 strips, 64 clips) = 512 wgs; clip-grouped XCD mapping: all 8
// strips of clip c get flat ids == c (mod 8) -> clip A-panel L2-resident.
// LDS 40KB: A [256r x 64k] @ [0,16384) ushorts (32 segs), B [64 x 64] @
// [16384,20480) (8 segs). 128B rows, chunk swizzle ch ^= (r&7) on both the
// GLDS source and the frag read (rule #21; conflict-free by construction).
// Scan buffer 256x66 ushorts aliases [0,16896) post-barrier.
// ---------------------------------------------------------------------------
__global__ __launch_bounds__(256) void gemm_scan(
    const ushort_t* __restrict__ Ap, const ushort_t* __restrict__ Bp,
    const float* __restrict__ bias, ushort_t* __restrict__ Sout, int K) {
    __shared__ ushort_t lds[20480];  // 40960 B

    const int tid = threadIdx.x;
    const int w = tid >> 6, l = tid & 63;
    const int flat = blockIdx.y * gridDim.x + blockIdx.x;
    // clip-grouped bijective map: clip = ((flat>>6)<<3)|(flat&7), strip = (flat>>3)&7
    const int clip = ((flat >> 6) << 3) | (flat & 7);
    const int strip = (flat >> 3) & 7;
    const int n0 = strip * 64;
    const int m0 = clip * 256;

    f32x4 acc[4][4];
#pragma unroll
    for (int mi = 0; mi < 4; ++mi)
#pragma unroll
        for (int ni = 0; ni < 4; ++ni) acc[mi][ni] = (f32x4){0.f, 0.f, 0.f, 0.f};

    const int c0 = l >> 4;
    const int schunk = (l & 7) ^ ((l >> 3) & 7);  // pre-swizzled source chunk
    for (int k0 = 0; k0 < K; k0 += 64) {
        __syncthreads();
        // staging: 40 segs of 1KB (A:32, B:8); 10 per wave
#pragma unroll
        for (int j = 0; j < 10; ++j) {
            const int seg = w * 10 + j;  // 0..39
            if (seg < 32) {
                const int r = seg * 8 + (l >> 3);
                GLDS(Ap + (size_t)(m0 + r) * K + k0 + schunk * 8,
                     &lds[seg * 512]);
            } else {
                const int r = (seg - 32) * 8 + (l >> 3);
                GLDS(Bp + (size_t)(n0 + r) * K + k0 + schunk * 8,
                     &lds[16384 + (seg - 32) * 512]);
            }
        }
        __syncthreads();

#pragma unroll
        for (int kh = 0; kh < 2; ++kh) {
            half8 aa[4], bb[4];
            const int q = kh * 4 + c0;
#pragma unroll
            for (int mi = 0; mi < 4; ++mi) {
                const int r = w * 64 + mi * 16 + (l & 15);
                const int off = r * 64 + ((q ^ (l & 7)) * 8);
                aa[mi] = __builtin_bit_cast(half8, *(const short8*)&lds[off]);
            }
#pragma unroll
            for (int ni = 0; ni < 4; ++ni) {
                const int r = ni * 16 + (l & 15);
                const int off = 16384 + r * 64 + ((q ^ (l & 7)) * 8);
                bb[ni] = __builtin_bit_cast(half8, *(const short8*)&lds[off]);
            }
#pragma unroll
            for (int mi = 0; mi < 4; ++mi)
#pragma unroll
                for (int ni = 0; ni < 4; ++ni)
                    acc[mi][ni] = __builtin_amdgcn_mfma_f32_16x16x32_f16(
                        aa[mi], bb[ni], acc[mi][ni], 0, 0, 0);
        }
    }

    __syncthreads();  // all frag reads done before LDS reuse

    // acc(+bias) -> LDS x[t][h] f16, stride 66 (odd-dword: bank-spread)
    float bv[4];
#pragma unroll
    for (int ni = 0; ni < 4; ++ni) bv[ni] = bias[n0 + ni * 16 + (l & 15)];
#pragma unroll
    for (int mi = 0; mi < 4; ++mi) {
        const int t0 = w * 64 + mi * 16 + ((l >> 4) << 2);
#pragma unroll
        for (int ni = 0; ni < 4; ++ni) {
            const int h = ni * 16 + (l & 15);
#pragma unroll
            for (int r = 0; r < 4; ++r)
                lds[(t0 + r) * 66 + h] = f2h(acc[mi][ni][r] + bv[ni]);
        }
    }
    __syncthreads();

    // scan: threads 0..63 each own one h column; snntorch Leaky subtract
    if (tid < 64) {
        const int h = tid;
        ushort_t* sp = Sout + (size_t)m0 * 512 + n0 + h;
        float m = 0.f;
#pragma unroll 4
        for (int t = 0; t < T_; ++t) {
            const float xv = h2f(lds[t * 66 + h]);
            const float r = (m - THR > 0.f) ? THR : 0.f;
            m = BETA * m + xv - r;
            sp[(size_t)t * 512] = (m - THR > 0.f) ? (ushort_t)0x3C00 : (ushort_t)0;
        }
    }
}

// ---------------------------------------------------------------------------
// f16 MFMA GEMM, BK=64, fused MIL head epilogue:
// p = relu(C+bias) dot u over this wave's 64-col strip -> part[strip][row].
// Tile 128x128, 4 waves (2x2). Grid (4, 128) = 512 wgs, m-grouped XCD map.
// LDS 32KB: A 16 segs @ [0,8192) ushorts, B 16 segs @ [8192,16384).
// ---------------------------------------------------------------------------
__global__ __launch_bounds__(256) void gemm_mil(
    const ushort_t* __restrict__ Ap, const ushort_t* __restrict__ Bp,
    const float* __restrict__ bias, const float* __restrict__ Uv,
    float* __restrict__ part, int N, int K) {
    __shared__ ushort_t lds[16384];  // 32768 B

    const int tid = threadIdx.x;
    const int w = tid >> 6, l = tid & 63;
    const int flat = blockIdx.y * gridDim.x + blockIdx.x;
    // m-grouped bijective map: mt = ((flat>>5)<<3)|(flat&7), st = (flat>>3)&3
    const int mt = ((flat >> 5) << 3) | (flat & 7);
    const int st = (flat >> 3) & 3;
    const int n0 = st * 128;
    const int m0 = mt * 128;
    const int wr = w >> 1, wc = w & 1;

    f32x4 acc[4][4];
#pragma unroll
    for (int mi = 0; mi < 4; ++mi)
#pragma unroll
        for (int ni = 0; ni < 4; ++ni) acc[mi][ni] = (f32x4){0.f, 0.f, 0.f, 0.f};

    const int c0 = l >> 4;
    const int schunk = (l & 7) ^ ((l >> 3) & 7);
    for (int k0 = 0; k0 < K; k0 += 64) {
        __syncthreads();
        // staging: 32 segs (A:16, B:16); 8 per wave
#pragma unroll
        for (int j = 0; j < 8; ++j) {
            const int g = w * 8 + j;  // 0..31
            const int seg = g & 15;
            const int r = seg * 8 + (l >> 3);
            const ushort_t* pl = (g < 16) ? Ap : Bp;
            const int rb = (g < 16) ? m0 : n0;
            GLDS(pl + (size_t)(rb + r) * K + k0 + schunk * 8, &lds[g * 512]);
        }
        __syncthreads();

#pragma unroll
        for (int kh = 0; kh < 2; ++kh) {
            half8 aa[4], bb[4];
            const int q = kh * 4 + c0;
#pragma unroll
            for (int mi = 0; mi < 4; ++mi) {
                const int r = wr * 64 + mi * 16 + (l & 15);
                const int off = r * 64 + ((q ^ (l & 7)) * 8);
                aa[mi] = __builtin_bit_cast(half8, *(const short8*)&lds[off]);
            }
#pragma unroll
            for (int ni = 0; ni < 4; ++ni) {
                const int r = wc * 64 + ni * 16 + (l & 15);
                const int off = 8192 + r * 64 + ((q ^ (l & 7)) * 8);
                bb[ni] = __builtin_bit_cast(half8, *(const short8*)&lds[off]);
            }
#pragma unroll
            for (int mi = 0; mi < 4; ++mi)
#pragma unroll
                for (int ni = 0; ni < 4; ++ni)
                    acc[mi][ni] = __builtin_amdgcn_mfma_f32_16x16x32_f16(
                        aa[mi], bb[ni], acc[mi][ni], 0, 0, 0);
        }
    }

    // fused MIL: per row partial = sum_col relu(acc+bias)*u[col]
    float bv[4], uc[4];
#pragma unroll
    for (int ni = 0; ni < 4; ++ni) {
        const int col = n0 + wc * 64 + ni * 16 + (l & 15);
        bv[ni] = bias[col];
        uc[ni] = Uv[col];
    }
    const int strip = (n0 >> 6) + wc;  // 0..7
#pragma unroll
    for (int mi = 0; mi < 4; ++mi) {
        float p[4];
#pragma unroll
        for (int r = 0; r < 4; ++r) {
            float s = 0.f;
#pragma unroll
            for (int ni = 0; ni < 4; ++ni)
                s += fmaxf(acc[mi][ni][r] + bv[ni], 0.f) * uc[ni];
            p[r] = s;
        }
#pragma unroll
        for (int off = 1; off <= 8; off <<= 1)
#pragma unroll
            for (int r = 0; r < 4; ++r) p[r] += __shfl_xor(p[r], off);
        if ((l & 15) == 0) {
            const int row0 = m0 + wr * 64 + mi * 16 + ((l >> 4) << 2);
#pragma unroll
            for (int r = 0; r < 4; ++r)
                part[(size_t)strip * M_ + row0 + r] = p[r];
        }
    }
}

// ---------------------------------------------------------------------------
// Split-bf16 3-product GEMM (m97 structure, BK=32) — only for Wc = W1 @ Wf.
// Emits single f16 plane.
// ---------------------------------------------------------------------------
__global__ __launch_bounds__(256) void gemm_bf16_wc(
    const ushort_t* __restrict__ Ah, const ushort_t* __restrict__ Al,
    const ushort_t* __restrict__ Bh, const ushort_t* __restrict__ Bl,
    ushort_t* __restrict__ Cout, int N, int K) {
    __shared__ ushort_t lds[4 * 4096];

    const int tid = threadIdx.x;
    const int w = tid >> 6, l = tid & 63;
    const int nwg = gridDim.x * gridDim.y;
    const int flat = blockIdx.y * gridDim.x + blockIdx.x;
    const int wg = (flat & 7) * (nwg >> 3) + (flat >> 3);
    const int n0 = (wg % gridDim.x) * 128;
    const int m0 = (wg / gridDim.x) * 128;
    const int wr = w >> 1, wc = w & 1;

    f32x4 acc[4][4];
#pragma unroll
    for (int mi = 0; mi < 4; ++mi)
#pragma unroll
        for (int ni = 0; ni < 4; ++ni) acc[mi][ni] = (f32x4){0.f, 0.f, 0.f, 0.f};

    const int c0 = l >> 4;
    for (int k0 = 0; k0 < K; k0 += 32) {
        __syncthreads();
#pragma unroll
        for (int j = 0; j < 8; ++j) {
            const int g = w * 8 + j;
            const int p = g >> 3, seg = g & 7;
            const int r = seg * 16 + (l >> 2);
            const int ch = (l & 3) ^ swz(r);
            const ushort_t* pl = (p == 0) ? Ah : (p == 1) ? Al : (p == 2) ? Bh : Bl;
            const int rb = (p < 2) ? m0 : n0;
            GLDS(pl + (size_t)(rb + r) * K + k0 + ch * 8,
                 &lds[p * 4096 + seg * 512]);
        }
        __syncthreads();

        short8 ah[4], al[4], bh[4], bl[4];
#pragma unroll
        for (int mi = 0; mi < 4; ++mi) {
            const int r = wr * 64 + mi * 16 + (l & 15);
            const int off = r * 32 + ((c0 ^ swz(r)) * 8);
            ah[mi] = *(const short8*)&lds[off];
            al[mi] = *(const short8*)&lds[4096 + off];
        }
#pragma unroll
        for (int ni = 0; ni < 4; ++ni) {
            const int r = wc * 64 + ni * 16 + (l & 15);
            const int off = r * 32 + ((c0 ^ swz(r)) * 8);
            bh[ni] = *(const short8*)&lds[8192 + off];
            bl[ni] = *(const short8*)&lds[12288 + off];
        }
#pragma unroll
        for (int mi = 0; mi < 4; ++mi)
#pragma unroll
            for (int ni = 0; ni < 4; ++ni) {
                acc[mi][ni] = __builtin_amdgcn_mfma_f32_16x16x32_bf16(
                    ah[mi], bh[ni], acc[mi][ni], 0, 0, 0);
                acc[mi][ni] = __builtin_amdgcn_mfma_f32_16x16x32_bf16(
                    ah[mi], bl[ni], acc[mi][ni], 0, 0, 0);
                acc[mi][ni] = __builtin_amdgcn_mfma_f32_16x16x32_bf16(
                    al[mi], bh[ni], acc[mi][ni], 0, 0, 0);
            }
    }

#pragma unroll
    for (int ni = 0; ni < 4; ++ni) {
        const int col = n0 + wc * 64 + ni * 16 + (l & 15);
#pragma unroll
        for (int mi = 0; mi < 4; ++mi) {
            const int row0 = m0 + wr * 64 + mi * 16 + ((l >> 4) << 2);
#pragma unroll
            for (int r = 0; r < 4; ++r)
                Cout[(size_t)(row0 + r) * N + col] = f2h(acc[mi][ni][r]);
        }
    }
}

// ---------------------------------------------------------------------------
// Sectioned prep (one launch):
//   [0,256):    W1 -> bf16 hi/lo planes
//   [256,512):  W2 -> f16
//   [512,768):  Mw1 -> f16
//   [768,896):  bc[j] = b1[j] + W1[j,:]@bf  (wave per j)
//   [896,898):  u[j] = Mw3@Mw2[:,j]; uc[512] = Mw3@Mb2+Mb3
//   [898,1410): Wf -> WfT bf16 hi/lo planes (32x32 transpose tiles)
// ---------------------------------------------------------------------------
__global__ __launch_bounds__(256) void prep_small(
    const float* __restrict__ W1, const float* __restrict__ W2,
    const float* __restrict__ Mw1, const float* __restrict__ bfv,
    const float* __restrict__ b1, const float* __restrict__ Mw2,
    const float* __restrict__ Mb2, const float* __restrict__ Mw3,
    const float* __restrict__ Mb3, const float* __restrict__ Wf,
    ushort_t* __restrict__ w1h, ushort_t* __restrict__ w1l,
    ushort_t* __restrict__ w2f, ushort_t* __restrict__ m1f,
    float* __restrict__ bc, float* __restrict__ uc,
    ushort_t* __restrict__ wfTh, ushort_t* __restrict__ wfTl) {
    __shared__ float tile[32][33];
    const int blk = blockIdx.x;
    const int tid = threadIdx.x;
    if (blk < 256) {
        const int i = blk * 256 + tid;
        f32x4 v = ((const f32x4*)W1)[i];
        us4 h, ll;
#pragma unroll
        for (int e = 0; e < 4; ++e) {
            const unsigned short hb = f2bf(v[e]);
            h[e] = hb;
            ll[e] = f2bf(v[e] - bf2f(hb));
        }
        ((us4*)w1h)[i] = h;
        ((us4*)w1l)[i] = ll;
    } else if (blk < 512) {
        const int i = (blk - 256) * 256 + tid;
        f32x4 v = ((const f32x4*)W2)[i];
        us4 h;
#pragma unroll
        for (int e = 0; e < 4; ++e) h[e] = f2h(v[e]);
        ((us4*)w2f)[i] = h;
    } else if (blk < 768) {
        const int i = (blk - 512) * 256 + tid;
        f32x4 v = ((const f32x4*)Mw1)[i];
        us4 h;
#pragma unroll
        for (int e = 0; e < 4; ++e) h[e] = f2h(v[e]);
        ((us4*)m1f)[i] = h;
    } else if (blk < 896) {
        const int w = tid >> 6, l = tid & 63;
        const int j = (blk - 768) * 4 + w;
        const float* row = W1 + (size_t)j * 512;
        float a = 0.f;
#pragma unroll
        for (int i = 0; i < 8; ++i) a += row[l + i * 64] * bfv[l + i * 64];
#pragma unroll
        for (int off = 32; off >= 1; off >>= 1) a += __shfl_xor(a, off);
        if (l == 0) bc[j] = a + b1[j];
    } else if (blk < 898) {
        const int j = (blk - 896) * 256 + tid;  // 0..511
        float a = 0.f;
        for (int i = 0; i < 32; ++i) a += Mw3[i] * Mw2[(size_t)i * 512 + j];
        uc[j] = a;
        if (j == 0) {
            float c = Mb3[0];
            for (int i = 0; i < 32; ++i) c += Mw3[i] * Mb2[i];
            uc[512] = c;
        }
    } else {
        const int idx = blk - 898;          // 0..511
        const int k0 = (idx & 31) * 32;     // Wf col tile
        const int i0 = (idx >> 5) * 32;     // Wf row tile
        const int tx = tid & 31;
        const int ty = tid >> 5;  // 0..7
#pragma unroll
        for (int e = 0; e < 4; ++e) {
            const int i = ty + e * 8;
            tile[i][tx] = Wf[(size_t)(i0 + i) * 1024 + k0 + tx];
        }
        __syncthreads();
#pragma unroll
        for (int e = 0; e < 4; ++e) {
            const int kk = ty + e * 8;
            const float v = tile[tx][kk];
            const unsigned short h = f2bf(v);
            wfTh[(size_t)(k0 + kk) * 512 + i0 + tx] = h;
            wfTl[(size_t)(k0 + kk) * 512 + i0 + tx] = f2bf(v - bf2f(h));
        }
    }
}

// ---------------------------------------------------------------------------
// f32 -> single f16 plane round (f_f).
// ---------------------------------------------------------------------------
__global__ __launch_bounds__(256) void round_f16(const float* __restrict__ x,
                                                 ushort_t* __restrict__ o,
                                                 int n4) {
    int i = blockIdx.x * 256 + threadIdx.x;
    const int stride = gridDim.x * 256;
    for (; i < n4; i += stride) {
        f32x4 v = ((const f32x4*)x)[i];
        us4 h;
#pragma unroll
        for (int e = 0; e < 4; ++e) h[e] = f2h(v[e]);
        ((us4*)o)[i] = h;
    }
}

// ---------------------------------------------------------------------------
// Tail: pre[row] = sum_{s<8} part[s][row] + c; top-17 on pre (sigmoid
// monotonic), mean of sigmoid(selected). One wave per clip.
// ---------------------------------------------------------------------------
__global__ __launch_bounds__(64) void tail_topk(const float* __restrict__ part,
                                                const float* __restrict__ uc,
                                                float* __restrict__ out) {
    const int b = blockIdx.x;
    const int lane = threadIdx.x;
    const float c = uc[512];
    float v[4];
#pragma unroll
    for (int i = 0; i < 4; ++i) {
        const int row = b * T_ + lane + i * 64;
        float a = 0.f;
#pragma unroll
        for (int s = 0; s < 8; ++s) a += part[(size_t)s * M_ + row];
        v[i] = a + c;
    }
    float sum = 0.f;
    for (int iter = 0; iter < 17; ++iter) {
        float mv = v[0];
        int mslot = 0;
#pragma unroll
        for (int i = 1; i < 4; ++i)
            if (v[i] > mv) { mv = v[i]; mslot = i; }
        float bv = mv;
        int bl = lane, bs = mslot;
#pragma unroll
        for (int off = 32; off >= 1; off >>= 1) {
            const float ov = __shfl_xor(bv, off);
            const int ol = __shfl_xor(bl, off);
            const int os = __shfl_xor(bs, off);
            if (ov > bv || (ov == bv && ol < bl)) { bv = ov; bl = ol; bs = os; }
        }
        sum += 1.f / (1.f + expf(-bv));
        if (lane == bl) v[bs] = -1e30f;
    }
    if (lane == 0) out[b] = sum * (1.f / 17.f);
}

// ---------------------------------------------------------------------------
// Orchestration (7 launches):
//   prep_small (incl. Wf transpose); round_f16(f_f)
//   wcf   <- gemm_bf16_wc(W1 planes @ WfT^T)
//   sbuf1 <- gemm_scan(ffh @ wcf^T + bc)        [x1 + scan1 fused, BK=64]
//   sbuf2 <- gemm_scan(sbuf1 @ w2f^T + b2)      [x2 + scan2 fused, BK=64]
//   part  <- gemm_mil(sbuf2 @ m1f^T + Mb1, relu, dot u)   [BK=64]
//   out   <- tail_topk(part)
// ---------------------------------------------------------------------------
extern "C" void kernel_launch(void* const* d_in, const int* in_sizes, int n_in,
                              void* d_out, int out_size, void* d_ws, size_t ws_size,
                              hipStream_t stream) {
    const float* f_f = (const float*)d_in[0];
    const float* Wf  = (const float*)d_in[2];
    const float* bf  = (const float*)d_in[3];
    const float* W1  = (const float*)d_in[4];
    const float* b1  = (const float*)d_in[5];
    const float* W2  = (const float*)d_in[6];
    const float* b2  = (const float*)d_in[7];
    const float* Mw1 = (const float*)d_in[8];
    const float* Mb1 = (const float*)d_in[9];
    const float* Mw2 = (const float*)d_in[10];
    const float* Mb2 = (const float*)d_in[11];
    const float* Mw3 = (const float*)d_in[12];
    const float* Mb3 = (const float*)d_in[13];
    float* out = (float*)d_out;

    char* ws = (char*)d_ws;
    const size_t NEf = (size_t)M_ * F_;  // 16.78M elems
    const size_t NE = (size_t)M_ * H_;   // 8.39M elems
    ushort_t* ffh = (ushort_t*)ws;                       // f16 f_f [M,1024]
    ushort_t* sbuf1 = ffh + NEf;                         // f16 spikes 1
    ushort_t* sbuf2 = sbuf1 + NE;                        // f16 spikes 2
    ushort_t* w1h = sbuf2 + NE;                          // bf16 (wc input)
    ushort_t* w1l = w1h + 262144;
    ushort_t* w2f = w1l + 262144;                        // f16 single
    ushort_t* m1f = w2f + 262144;                        // f16 single
    ushort_t* wfTh = m1f + 262144;                       // bf16 [1024,512]
    ushort_t* wfTl = wfTh + 524288;
    ushort_t* wcf = wfTl + 524288;                       // f16 [512,1024]
    float* bc = (float*)(wcf + 524288);
    float* uc = bc + 512;                                // u[512] + c
    float* part = uc + 513 + 63;                         // [8][16384] f32

    const dim3 blk(256);

    prep_small<<<dim3(1410), blk, 0, stream>>>(W1, W2, Mw1, bf, b1, Mw2, Mb2,
                                               Mw3, Mb3, Wf, w1h, w1l, w2f,
                                               m1f, bc, uc, wfTh, wfTl);
    round_f16<<<dim3(2048), blk, 0, stream>>>(f_f, ffh, 4194304);

    // Wc = W1 @ Wf -> f16 [512,1024]
    gemm_bf16_wc<<<dim3(8, 4), blk, 0, stream>>>(w1h, w1l, wfTh, wfTl, wcf,
                                                 1024, 512);
    // x1 = f_f @ Wc^T + bc, fused scan1 -> sbuf1
    gemm_scan<<<dim3(8, 64), blk, 0, stream>>>(ffh, wcf, bc, sbuf1, 1024);
    // x2 = sbuf1 @ W2^T + b2, fused scan2 -> sbuf2
    gemm_scan<<<dim3(8, 64), blk, 0, stream>>>(sbuf1, w2f, b2, sbuf2, 512);
    // z-GEMM with fused MIL head -> part[8][M]
    gemm_mil<<<dim3(4, 128), blk, 0, stream>>>(sbuf2, m1f, Mb1, uc, part,
                                               512, 512);
    tail_topk<<<dim3(B_), dim3(64), 0, stream>>>(part, uc, out);
}

// Round 12
// 119.748 us; speedup vs baseline: 2.1142x; 1.0431x over previous
//
#include <hip/hip_runtime.h>
#include <math.h>

#define BETA 0.9f
#define THR 1.0f

constexpr int B_ = 64, T_ = 256, F_ = 1024, H_ = 512;
constexpr int M_ = B_ * T_;  // 16384 rows

typedef float f32x4 __attribute__((ext_vector_type(4)));
typedef short short8 __attribute__((ext_vector_type(8)));
typedef _Float16 half8 __attribute__((ext_vector_type(8)));
typedef unsigned short us4 __attribute__((ext_vector_type(4)));
typedef unsigned short ushort_t;

// ---- bf16 helpers (RNE) ----------------------------------------------------
static __device__ __forceinline__ unsigned short f2bf(float x) {
    unsigned b = __builtin_bit_cast(unsigned, x);
    unsigned r = (b + 0x7FFFu + ((b >> 16) & 1u)) >> 16;
    return (unsigned short)r;
}
static __device__ __forceinline__ float bf2f(unsigned short u) {
    unsigned v = ((unsigned)u) << 16;
    return __builtin_bit_cast(float, v);
}
// ---- f16 helpers ------------------------------------------------------------
static __device__ __forceinline__ unsigned short f2h(float x) {
    _Float16 h = (_Float16)x;
    return __builtin_bit_cast(unsigned short, h);
}
static __device__ __forceinline__ float h2f(unsigned short u) {
    return (float)__builtin_bit_cast(_Float16, u);
}
// BK=32 swizzle (64B rows, 4 chunks) — used by gemm_bf16_wc only.
static __device__ __forceinline__ int swz(int r) {
    return ((r >> 2) & 3) ^ (r & 3);
}

#define GLDS(srcp, dstp)                                                      \
    __builtin_amdgcn_global_load_lds(                                         \
        (const __attribute__((address_space(1))) unsigned int*)(srcp),        \
        (__attribute__((address_space(3))) unsigned int*)(dstp), 16, 0, 0)

// ---------------------------------------------------------------------------
// Fused f16 GEMM + leaky scan, BK=64, 2-phase double-buffered pipeline:
//   prologue: stage(buf0, t=0)
//   iter t:   barrier (drains stage(t)); stage(buf^1, t+1); ds_read+MFMA(t)
// Loads for t+1 fly under MFMA(t); the next barrier's vmcnt(0) finds them
// landed (T3-minimum recipe). One barrier per K-step.
// Tile 256M x 64N, 256 threads (4 waves, each 64x64 subtile).
// Grid (8 strips, 64 clips) = 512 wgs; clip-grouped XCD mapping.
// LDS 80KB = 2 x 20480 ushorts (A 32 segs + B 8 segs per buffer); still
// 2 blocks/CU. Scan buffer 256x66 ushorts aliases buf0 [0,16896); the last
// K-tile (nt even) always computes from buf1 -> no collision.
// ---------------------------------------------------------------------------
__global__ __launch_bounds__(256) void gemm_scan(
    const ushort_t* __restrict__ Ap, const ushort_t* __restrict__ Bp,
    const float* __restrict__ bias, ushort_t* __restrict__ Sout, int K) {
    constexpr int BUF = 20480;  // ushorts per buffer (40KB)
    __shared__ ushort_t lds[2 * BUF];

    const int tid = threadIdx.x;
    const int w = tid >> 6, l = tid & 63;
    const int flat = blockIdx.y * gridDim.x + blockIdx.x;
    // clip-grouped bijective map: all 8 strips of a clip share an XCD
    const int clip = ((flat >> 6) << 3) | (flat & 7);
    const int strip = (flat >> 3) & 7;
    const int n0 = strip * 64;
    const int m0 = clip * 256;

    f32x4 acc[4][4];
#pragma unroll
    for (int mi = 0; mi < 4; ++mi)
#pragma unroll
        for (int ni = 0; ni < 4; ++ni) acc[mi][ni] = (f32x4){0.f, 0.f, 0.f, 0.f};

    const int c0 = l >> 4;
    const int schunk = (l & 7) ^ ((l >> 3) & 7);  // pre-swizzled source chunk

    auto stage = [&](int buf, int k0) {
#pragma unroll
        for (int j = 0; j < 10; ++j) {
            const int seg = w * 10 + j;  // 0..39
            if (seg < 32) {
                const int r = seg * 8 + (l >> 3);
                GLDS(Ap + (size_t)(m0 + r) * K + k0 + schunk * 8,
                     &lds[buf + seg * 512]);
            } else {
                const int r = (seg - 32) * 8 + (l >> 3);
                GLDS(Bp + (size_t)(n0 + r) * K + k0 + schunk * 8,
                     &lds[buf + 16384 + (seg - 32) * 512]);
            }
        }
    };

    const int nt = K / 64;
    stage(0, 0);
    for (int t = 0; t < nt; ++t) {
        const int cur = (t & 1) * BUF;
        const int nxt = BUF - cur;
        __syncthreads();  // drains stage(t) loads; protects buffer reuse
        if (t + 1 < nt) stage(nxt, (t + 1) * 64);

#pragma unroll
        for (int kh = 0; kh < 2; ++kh) {
            half8 aa[4], bb[4];
            const int q = kh * 4 + c0;
#pragma unroll
            for (int mi = 0; mi < 4; ++mi) {
                const int r = w * 64 + mi * 16 + (l & 15);
                const int off = cur + r * 64 + ((q ^ (l & 7)) * 8);
                aa[mi] = __builtin_bit_cast(half8, *(const short8*)&lds[off]);
            }
#pragma unroll
            for (int ni = 0; ni < 4; ++ni) {
                const int r = ni * 16 + (l & 15);
                const int off = cur + 16384 + r * 64 + ((q ^ (l & 7)) * 8);
                bb[ni] = __builtin_bit_cast(half8, *(const short8*)&lds[off]);
            }
#pragma unroll
            for (int mi = 0; mi < 4; ++mi)
#pragma unroll
                for (int ni = 0; ni < 4; ++ni)
                    acc[mi][ni] = __builtin_amdgcn_mfma_f32_16x16x32_f16(
                        aa[mi], bb[ni], acc[mi][ni], 0, 0, 0);
        }
    }
    // last compute read buf1; epilogue writes buf0 region (disjoint) — safe.

    // acc(+bias) -> LDS x[t][h] f16, stride 66 (odd-dword: bank-spread)
    float bv[4];
#pragma unroll
    for (int ni = 0; ni < 4; ++ni) bv[ni] = bias[n0 + ni * 16 + (l & 15)];
#pragma unroll
    for (int mi = 0; mi < 4; ++mi) {
        const int t0 = w * 64 + mi * 16 + ((l >> 4) << 2);
#pragma unroll
        for (int ni = 0; ni < 4; ++ni) {
            const int h = ni * 16 + (l & 15);
#pragma unroll
            for (int r = 0; r < 4; ++r)
                lds[(t0 + r) * 66 + h] = f2h(acc[mi][ni][r] + bv[ni]);
        }
    }
    __syncthreads();

    // scan: threads 0..63 each own one h column; snntorch Leaky subtract
    if (tid < 64) {
        const int h = tid;
        ushort_t* sp = Sout + (size_t)m0 * 512 + n0 + h;
        float m = 0.f;
#pragma unroll 4
        for (int t = 0; t < T_; ++t) {
            const float xv = h2f(lds[t * 66 + h]);
            const float r = (m - THR > 0.f) ? THR : 0.f;
            m = BETA * m + xv - r;
            sp[(size_t)t * 512] = (m - THR > 0.f) ? (ushort_t)0x3C00 : (ushort_t)0;
        }
    }
}

// ---------------------------------------------------------------------------
// f16 MFMA GEMM, BK=64, 2-phase double-buffered, fused MIL head epilogue:
// p = relu(C+bias) dot u over this wave's 64-col strip -> part[strip][row].
// Tile 128x128, 4 waves (2x2). Grid (4, 128) = 512 wgs, m-grouped XCD map.
// LDS 64KB = 2 x 16384 ushorts (A 16 + B 16 segs per buffer); 2 blocks/CU.
// ---------------------------------------------------------------------------
__global__ __launch_bounds__(256) void gemm_mil(
    const ushort_t* __restrict__ Ap, const ushort_t* __restrict__ Bp,
    const float* __restrict__ bias, const float* __restrict__ Uv,
    float* __restrict__ part, int N, int K) {
    constexpr int BUF = 16384;  // ushorts per buffer (32KB)
    __shared__ ushort_t lds[2 * BUF];

    const int tid = threadIdx.x;
    const int w = tid >> 6, l = tid & 63;
    const int flat = blockIdx.y * gridDim.x + blockIdx.x;
    const int mt = ((flat >> 5) << 3) | (flat & 7);
    const int st = (flat >> 3) & 3;
    const int n0 = st * 128;
    const int m0 = mt * 128;
    const int wr = w >> 1, wc = w & 1;

    f32x4 acc[4][4];
#pragma unroll
    for (int mi = 0; mi < 4; ++mi)
#pragma unroll
        for (int ni = 0; ni < 4; ++ni) acc[mi][ni] = (f32x4){0.f, 0.f, 0.f, 0.f};

    const int c0 = l >> 4;
    const int schunk = (l & 7) ^ ((l >> 3) & 7);

    auto stage = [&](int buf, int k0) {
#pragma unroll
        for (int j = 0; j < 8; ++j) {
            const int g = w * 8 + j;  // 0..31
            const int seg = g & 15;
            const int r = seg * 8 + (l >> 3);
            const ushort_t* pl = (g < 16) ? Ap : Bp;
            const int rb = (g < 16) ? m0 : n0;
            GLDS(pl + (size_t)(rb + r) * K + k0 + schunk * 8,
                 &lds[buf + g * 512]);
        }
    };

    const int nt = K / 64;
    stage(0, 0);
    for (int t = 0; t < nt; ++t) {
        const int cur = (t & 1) * BUF;
        const int nxt = BUF - cur;
        __syncthreads();
        if (t + 1 < nt) stage(nxt, (t + 1) * 64);

#pragma unroll
        for (int kh = 0; kh < 2; ++kh) {
            half8 aa[4], bb[4];
            const int q = kh * 4 + c0;
#pragma unroll
            for (int mi = 0; mi < 4; ++mi) {
                const int r = wr * 64 + mi * 16 + (l & 15);
                const int off = cur + r * 64 + ((q ^ (l & 7)) * 8);
                aa[mi] = __builtin_bit_cast(half8, *(const short8*)&lds[off]);
            }
#pragma unroll
            for (int ni = 0; ni < 4; ++ni) {
                const int r = wc * 64 + ni * 16 + (l & 15);
                const int off = cur + 8192 + r * 64 + ((q ^ (l & 7)) * 8);
                bb[ni] = __builtin_bit_cast(half8, *(const short8*)&lds[off]);
            }
#pragma unroll
            for (int mi = 0; mi < 4; ++mi)
#pragma unroll
                for (int ni = 0; ni < 4; ++ni)
                    acc[mi][ni] = __builtin_amdgcn_mfma_f32_16x16x32_f16(
                        aa[mi], bb[ni], acc[mi][ni], 0, 0, 0);
        }
    }

    // fused MIL: per row partial = sum_col relu(acc+bias)*u[col]
    float bv[4], uc[4];
#pragma unroll
    for (int ni = 0; ni < 4; ++ni) {
        const int col = n0 + wc * 64 + ni * 16 + (l & 15);
        bv[ni] = bias[col];
        uc[ni] = Uv[col];
    }
    const int strip = (n0 >> 6) + wc;  // 0..7
#pragma unroll
    for (int mi = 0; mi < 4; ++mi) {
        float p[4];
#pragma unroll
        for (int r = 0; r < 4; ++r) {
            float s = 0.f;
#pragma unroll
            for (int ni = 0; ni < 4; ++ni)
                s += fmaxf(acc[mi][ni][r] + bv[ni], 0.f) * uc[ni];
            p[r] = s;
        }
#pragma unroll
        for (int off = 1; off <= 8; off <<= 1)
#pragma unroll
            for (int r = 0; r < 4; ++r) p[r] += __shfl_xor(p[r], off);
        if ((l & 15) == 0) {
            const int row0 = m0 + wr * 64 + mi * 16 + ((l >> 4) << 2);
#pragma unroll
            for (int r = 0; r < 4; ++r)
                part[(size_t)strip * M_ + row0 + r] = p[r];
        }
    }
}

// ---------------------------------------------------------------------------
// Split-bf16 3-product GEMM (m97 structure, BK=32) — only for Wc = W1 @ Wf.
// Emits single f16 plane.
// ---------------------------------------------------------------------------
__global__ __launch_bounds__(256) void gemm_bf16_wc(
    const ushort_t* __restrict__ Ah, const ushort_t* __restrict__ Al,
    const ushort_t* __restrict__ Bh, const ushort_t* __restrict__ Bl,
    ushort_t* __restrict__ Cout, int N, int K) {
    __shared__ ushort_t lds[4 * 4096];

    const int tid = threadIdx.x;
    const int w = tid >> 6, l = tid & 63;
    const int nwg = gridDim.x * gridDim.y;
    const int flat = blockIdx.y * gridDim.x + blockIdx.x;
    const int wg = (flat & 7) * (nwg >> 3) + (flat >> 3);
    const int n0 = (wg % gridDim.x) * 128;
    const int m0 = (wg / gridDim.x) * 128;
    const int wr = w >> 1, wc = w & 1;

    f32x4 acc[4][4];
#pragma unroll
    for (int mi = 0; mi < 4; ++mi)
#pragma unroll
        for (int ni = 0; ni < 4; ++ni) acc[mi][ni] = (f32x4){0.f, 0.f, 0.f, 0.f};

    const int c0 = l >> 4;
    for (int k0 = 0; k0 < K; k0 += 32) {
        __syncthreads();
#pragma unroll
        for (int j = 0; j < 8; ++j) {
            const int g = w * 8 + j;
            const int p = g >> 3, seg = g & 7;
            const int r = seg * 16 + (l >> 2);
            const int ch = (l & 3) ^ swz(r);
            const ushort_t* pl = (p == 0) ? Ah : (p == 1) ? Al : (p == 2) ? Bh : Bl;
            const int rb = (p < 2) ? m0 : n0;
            GLDS(pl + (size_t)(rb + r) * K + k0 + ch * 8,
                 &lds[p * 4096 + seg * 512]);
        }
        __syncthreads();

        short8 ah[4], al[4], bh[4], bl[4];
#pragma unroll
        for (int mi = 0; mi < 4; ++mi) {
            const int r = wr * 64 + mi * 16 + (l & 15);
            const int off = r * 32 + ((c0 ^ swz(r)) * 8);
            ah[mi] = *(const short8*)&lds[off];
            al[mi] = *(const short8*)&lds[4096 + off];
        }
#pragma unroll
        for (int ni = 0; ni < 4; ++ni) {
            const int r = wc * 64 + ni * 16 + (l & 15);
            const int off = r * 32 + ((c0 ^ swz(r)) * 8);
            bh[ni] = *(const short8*)&lds[8192 + off];
            bl[ni] = *(const short8*)&lds[12288 + off];
        }
#pragma unroll
        for (int mi = 0; mi < 4; ++mi)
#pragma unroll
            for (int ni = 0; ni < 4; ++ni) {
                acc[mi][ni] = __builtin_amdgcn_mfma_f32_16x16x32_bf16(
                    ah[mi], bh[ni], acc[mi][ni], 0, 0, 0);
                acc[mi][ni] = __builtin_amdgcn_mfma_f32_16x16x32_bf16(
                    ah[mi], bl[ni], acc[mi][ni], 0, 0, 0);
                acc[mi][ni] = __builtin_amdgcn_mfma_f32_16x16x32_bf16(
                    al[mi], bh[ni], acc[mi][ni], 0, 0, 0);
            }
    }

#pragma unroll
    for (int ni = 0; ni < 4; ++ni) {
        const int col = n0 + wc * 64 + ni * 16 + (l & 15);
#pragma unroll
        for (int mi = 0; mi < 4; ++mi) {
            const int row0 = m0 + wr * 64 + mi * 16 + ((l >> 4) << 2);
#pragma unroll
            for (int r = 0; r < 4; ++r)
                Cout[(size_t)(row0 + r) * N + col] = f2h(acc[mi][ni][r]);
        }
    }
}

// ---------------------------------------------------------------------------
// Sectioned prep (one launch, 3458 blocks):
//   [0,256):      W1 -> bf16 hi/lo planes
//   [256,512):    W2 -> f16
//   [512,768):    Mw1 -> f16
//   [768,896):    bc[j] = b1[j] + W1[j,:]@bf  (wave per j)
//   [896,898):    u[j] = Mw3@Mw2[:,j]; uc[512] = Mw3@Mb2+Mb3
//   [898,1410):   Wf -> WfT bf16 hi/lo planes (32x32 transpose tiles)
//   [1410,3458):  f_f -> f16 plane (grid-stride over 4194304 f32x4)
// ---------------------------------------------------------------------------
__global__ __launch_bounds__(256) void prep_small(
    const float* __restrict__ W1, const float* __restrict__ W2,
    const float* __restrict__ Mw1, const float* __restrict__ bfv,
    const float* __restrict__ b1, const float* __restrict__ Mw2,
    const float* __restrict__ Mb2, const float* __restrict__ Mw3,
    const float* __restrict__ Mb3, const float* __restrict__ Wf,
    const float* __restrict__ f_f, ushort_t* __restrict__ w1h,
    ushort_t* __restrict__ w1l, ushort_t* __restrict__ w2f,
    ushort_t* __restrict__ m1f, float* __restrict__ bc,
    float* __restrict__ uc, ushort_t* __restrict__ wfTh,
    ushort_t* __restrict__ wfTl, ushort_t* __restrict__ ffh) {
    __shared__ float tile[32][33];
    const int blk = blockIdx.x;
    const int tid = threadIdx.x;
    if (blk < 256) {
        const int i = blk * 256 + tid;
        f32x4 v = ((const f32x4*)W1)[i];
        us4 h, ll;
#pragma unroll
        for (int e = 0; e < 4; ++e) {
            const unsigned short hb = f2bf(v[e]);
            h[e] = hb;
            ll[e] = f2bf(v[e] - bf2f(hb));
        }
        ((us4*)w1h)[i] = h;
        ((us4*)w1l)[i] = ll;
    } else if (blk < 512) {
        const int i = (blk - 256) * 256 + tid;
        f32x4 v = ((const f32x4*)W2)[i];
        us4 h;
#pragma unroll
        for (int e = 0; e < 4; ++e) h[e] = f2h(v[e]);
        ((us4*)w2f)[i] = h;
    } else if (blk < 768) {
        const int i = (blk - 512) * 256 + tid;
        f32x4 v = ((const f32x4*)Mw1)[i];
        us4 h;
#pragma unroll
        for (int e = 0; e < 4; ++e) h[e] = f2h(v[e]);
        ((us4*)m1f)[i] = h;
    } else if (blk < 896) {
        const int w = tid >> 6, l = tid & 63;
        const int j = (blk - 768) * 4 + w;
        const float* row = W1 + (size_t)j * 512;
        float a = 0.f;
#pragma unroll
        for (int i = 0; i < 8; ++i) a += row[l + i * 64] * bfv[l + i * 64];
#pragma unroll
        for (int off = 32; off >= 1; off >>= 1) a += __shfl_xor(a, off);
        if (l == 0) bc[j] = a + b1[j];
    } else if (blk < 898) {
        const int j = (blk - 896) * 256 + tid;  // 0..511
        float a = 0.f;
        for (int i = 0; i < 32; ++i) a += Mw3[i] * Mw2[(size_t)i * 512 + j];
        uc[j] = a;
        if (j == 0) {
            float c = Mb3[0];
            for (int i = 0; i < 32; ++i) c += Mw3[i] * Mb2[i];
            uc[512] = c;
        }
    } else if (blk < 1410) {
        const int idx = blk - 898;          // 0..511
        const int k0 = (idx & 31) * 32;     // Wf col tile
        const int i0 = (idx >> 5) * 32;     // Wf row tile
        const int tx = tid & 31;
        const int ty = tid >> 5;  // 0..7
#pragma unroll
        for (int e = 0; e < 4; ++e) {
            const int i = ty + e * 8;
            tile[i][tx] = Wf[(size_t)(i0 + i) * 1024 + k0 + tx];
        }
        __syncthreads();
#pragma unroll
        for (int e = 0; e < 4; ++e) {
            const int kk = ty + e * 8;
            const float v = tile[tx][kk];
            const unsigned short h = f2bf(v);
            wfTh[(size_t)(k0 + kk) * 512 + i0 + tx] = h;
            wfTl[(size_t)(k0 + kk) * 512 + i0 + tx] = f2bf(v - bf2f(h));
        }
    } else {
        constexpr int n4 = 4194304;
        const int base = (blk - 1410) * 256 + tid;
        for (int i = base; i < n4; i += 2048 * 256) {
            f32x4 v = ((const f32x4*)f_f)[i];
            us4 h;
#pragma unroll
            for (int e = 0; e < 4; ++e) h[e] = f2h(v[e]);
            ((us4*)ffh)[i] = h;
        }
    }
}

// ---------------------------------------------------------------------------
// Tail: pre[row] = sum_{s<8} part[s][row] + c; top-17 on pre (sigmoid
// monotonic), mean of sigmoid(selected). One wave per clip.
// ---------------------------------------------------------------------------
__global__ __launch_bounds__(64) void tail_topk(const float* __restrict__ part,
                                                const float* __restrict__ uc,
                                                float* __restrict__ out) {
    const int b = blockIdx.x;
    const int lane = threadIdx.x;
    const float c = uc[512];
    float v[4];
#pragma unroll
    for (int i = 0; i < 4; ++i) {
        const int row = b * T_ + lane + i * 64;
        float a = 0.f;
#pragma unroll
        for (int s = 0; s < 8; ++s) a += part[(size_t)s * M_ + row];
        v[i] = a + c;
    }
    float sum = 0.f;
    for (int iter = 0; iter < 17; ++iter) {
        float mv = v[0];
        int mslot = 0;
#pragma unroll
        for (int i = 1; i < 4; ++i)
            if (v[i] > mv) { mv = v[i]; mslot = i; }
        float bv = mv;
        int bl = lane, bs = mslot;
#pragma unroll
        for (int off = 32; off >= 1; off >>= 1) {
            const float ov = __shfl_xor(bv, off);
            const int ol = __shfl_xor(bl, off);
            const int os = __shfl_xor(bs, off);
            if (ov > bv || (ov == bv && ol < bl)) { bv = ov; bl = ol; bs = os; }
        }
        sum += 1.f / (1.f + expf(-bv));
        if (lane == bl) v[bs] = -1e30f;
    }
    if (lane == 0) out[b] = sum * (1.f / 17.f);
}

// ---------------------------------------------------------------------------
// Orchestration (6 launches):
//   prep_small (weights + Wf transpose + f_f round)
//   wcf   <- gemm_bf16_wc(W1 planes @ WfT^T)
//   sbuf1 <- gemm_scan(ffh @ wcf^T + bc)        [x1 + scan1, BK=64, dbuf]
//   sbuf2 <- gemm_scan(sbuf1 @ w2f^T + b2)      [x2 + scan2, BK=64, dbuf]
//   part  <- gemm_mil(sbuf2 @ m1f^T + Mb1)      [BK=64, dbuf, MIL fused]
//   out   <- tail_topk(part)
// ---------------------------------------------------------------------------
extern "C" void kernel_launch(void* const* d_in, const int* in_sizes, int n_in,
                              void* d_out, int out_size, void* d_ws, size_t ws_size,
                              hipStream_t stream) {
    const float* f_f = (const float*)d_in[0];
    const float* Wf  = (const float*)d_in[2];
    const float* bf  = (const float*)d_in[3];
    const float* W1  = (const float*)d_in[4];
    const float* b1  = (const float*)d_in[5];
    const float* W2  = (const float*)d_in[6];
    const float* b2  = (const float*)d_in[7];
    const float* Mw1 = (const float*)d_in[8];
    const float* Mb1 = (const float*)d_in[9];
    const float* Mw2 = (const float*)d_in[10];
    const float* Mb2 = (const float*)d_in[11];
    const float* Mw3 = (const float*)d_in[12];
    const float* Mb3 = (const float*)d_in[13];
    float* out = (float*)d_out;

    char* ws = (char*)d_ws;
    const size_t NEf = (size_t)M_ * F_;  // 16.78M elems
    const size_t NE = (size_t)M_ * H_;   // 8.39M elems
    ushort_t* ffh = (ushort_t*)ws;                       // f16 f_f [M,1024]
    ushort_t* sbuf1 = ffh + NEf;                         // f16 spikes 1
    ushort_t* sbuf2 = sbuf1 + NE;                        // f16 spikes 2
    ushort_t* w1h = sbuf2 + NE;                          // bf16 (wc input)
    ushort_t* w1l = w1h + 262144;
    ushort_t* w2f = w1l + 262144;                        // f16 single
    ushort_t* m1f = w2f + 262144;                        // f16 single
    ushort_t* wfTh = m1f + 262144;                       // bf16 [1024,512]
    ushort_t* wfTl = wfTh + 524288;
    ushort_t* wcf = wfTl + 524288;                       // f16 [512,1024]
    float* bc = (float*)(wcf + 524288);
    float* uc = bc + 512;                                // u[512] + c
    float* part = uc + 513 + 63;                         // [8][16384] f32

    const dim3 blk(256);

    prep_small<<<dim3(3458), blk, 0, stream>>>(W1, W2, Mw1, bf, b1, Mw2, Mb2,
                                               Mw3, Mb3, Wf, f_f, w1h, w1l,
                                               w2f, m1f, bc, uc, wfTh, wfTl,
                                               ffh);

    // Wc = W1 @ Wf -> f16 [512,1024]
    gemm_bf16_wc<<<dim3(8, 4), blk, 0, stream>>>(w1h, w1l, wfTh, wfTl, wcf,
                                                 1024, 512);
    // x1 = f_f @ Wc^T + bc, fused scan1 -> sbuf1
    gemm_scan<<<dim3(8, 64), blk, 0, stream>>>(ffh, wcf, bc, sbuf1, 1024);
    // x2 = sbuf1 @ W2^T + b2, fused scan2 -> sbuf2
    gemm_scan<<<dim3(8, 64), blk, 0, stream>>>(sbuf1, w2f, b2, sbuf2, 512);
    // z-GEMM with fused MIL head -> part[8][M]
    gemm_mil<<<dim3(4, 128), blk, 0, stream>>>(sbuf2, m1f, Mb1, uc, part,
                                               512, 512);
    tail_topk<<<dim3(B_), dim3(64), 0, stream>>>(part, uc, out);
}

// Round 13
// 114.289 us; speedup vs baseline: 2.2152x; 1.0478x over previous
//
#include <hip/hip_runtime.h>
#include <math.h>

#define BETA 0.9f
#define THR 1.0f

constexpr int B_ = 64, T_ = 256, F_ = 1024, H_ = 512;
constexpr int M_ = B_ * T_;  // 16384 rows

typedef float f32x4 __attribute__((ext_vector_type(4)));
typedef short short8 __attribute__((ext_vector_type(8)));
typedef _Float16 half8 __attribute__((ext_vector_type(8)));
typedef unsigned short us4 __attribute__((ext_vector_type(4)));
typedef unsigned short us8 __attribute__((ext_vector_type(8)));
typedef unsigned short ushort_t;

// ---- bf16 helpers (RNE) ----------------------------------------------------
static __device__ __forceinline__ unsigned short f2bf(float x) {
    unsigned b = __builtin_bit_cast(unsigned, x);
    unsigned r = (b + 0x7FFFu + ((b >> 16) & 1u)) >> 16;
    return (unsigned short)r;
}
static __device__ __forceinline__ float bf2f(unsigned short u) {
    unsigned v = ((unsigned)u) << 16;
    return __builtin_bit_cast(float, v);
}
// ---- f16 helpers ------------------------------------------------------------
static __device__ __forceinline__ unsigned short f2h(float x) {
    _Float16 h = (_Float16)x;
    return __builtin_bit_cast(unsigned short, h);
}
static __device__ __forceinline__ float h2f(unsigned short u) {
    return (float)__builtin_bit_cast(_Float16, u);
}
// BK=32 swizzle (64B rows, 4 chunks) — used by gemm_bf16_wc only.
static __device__ __forceinline__ int swz(int r) {
    return ((r >> 2) & 3) ^ (r & 3);
}

#define GLDS(srcp, dstp)                                                      \
    __builtin_amdgcn_global_load_lds(                                         \
        (const __attribute__((address_space(1))) unsigned int*)(srcp),        \
        (__attribute__((address_space(3))) unsigned int*)(dstp), 16, 0, 0)

// ---------------------------------------------------------------------------
// Fused f16 GEMM + leaky scan, BK=64, 2-phase double-buffered.
// AF32=0: A is f16, staged via GLDS (pre-swizzled source).
// AF32=1: A is f32 (f_f direct): reg-load early (T14), convert f2h + swizzled
//         ds_write_b128 AFTER the MFMA phase — conversion hides under MFMA,
//         eliminating the separate f_f round pass and its 100 MB of traffic.
// Tile 256M x 64N, 256 threads (4 waves, each 64x64 subtile).
// Grid (8 strips, 64 clips) = 512 wgs; clip-grouped XCD mapping.
// LDS 80KB = 2 x 20480 ushorts (A 32 segs + B 8 segs per buffer);
// 2 blocks/CU (160KB exactly). Scan buffer 256x66 ushorts aliases buf0;
// last K-tile (nt even) computes from buf1 -> no collision.
// ---------------------------------------------------------------------------
template <int AF32>
__global__ __launch_bounds__(256, 2) void gemm_scan(
    const void* __restrict__ Asrc, const ushort_t* __restrict__ Bp,
    const float* __restrict__ bias, ushort_t* __restrict__ Sout, int K) {
    constexpr int BUF = 20480;  // ushorts per buffer (40KB)
    __shared__ ushort_t lds[2 * BUF];

    const int tid = threadIdx.x;
    const int w = tid >> 6, l = tid & 63;
    const int flat = blockIdx.y * gridDim.x + blockIdx.x;
    // clip-grouped bijective map: all 8 strips of a clip share an XCD
    const int clip = ((flat >> 6) << 3) | (flat & 7);
    const int strip = (flat >> 3) & 7;
    const int n0 = strip * 64;
    const int m0 = clip * 256;

    f32x4 acc[4][4];
#pragma unroll
    for (int mi = 0; mi < 4; ++mi)
#pragma unroll
        for (int ni = 0; ni < 4; ++ni) acc[mi][ni] = (f32x4){0.f, 0.f, 0.f, 0.f};

    const int c0 = l >> 4;
    const int schunk = (l & 7) ^ ((l >> 3) & 7);  // pre-swizzled source chunk

    // AF32 staging state: 8 chunks of 8 f32 (2 f32x4 each) per thread.
    f32x4 areg[8][2];

    auto stageB = [&](int buf, int k0) {
#pragma unroll
        for (int j = 0; j < 2; ++j) {
            const int seg = w * 2 + j;  // 0..7
            const int r = seg * 8 + (l >> 3);
            GLDS((const ushort_t*)Bp + (size_t)(n0 + r) * K + k0 + schunk * 8,
                 &lds[buf + 16384 + seg * 512]);
        }
    };
    auto stageA16 = [&](int buf, int k0) {
#pragma unroll
        for (int j = 0; j < 8; ++j) {
            const int seg = w * 8 + j;  // 0..31
            const int r = seg * 8 + (l >> 3);
            GLDS((const ushort_t*)Asrc + (size_t)(m0 + r) * K + k0 + schunk * 8,
                 &lds[buf + seg * 512]);
        }
    };
    auto loadA32 = [&](int k0) {  // issue 16B f32 loads (coalesced 256B/8 lanes)
#pragma unroll
        for (int j = 0; j < 8; ++j) {
            const int r = j * 32 + w * 8 + (l >> 3);
            const float* src =
                (const float*)Asrc + (size_t)(m0 + r) * K + k0 + (l & 7) * 8;
            areg[j][0] = *(const f32x4*)src;
            areg[j][1] = *(const f32x4*)(src + 4);
        }
    };
    auto writeA32 = [&](int buf) {  // convert + swizzled 16B ds_write
#pragma unroll
        for (int j = 0; j < 8; ++j) {
            const int r = j * 32 + w * 8 + (l >> 3);
            us8 hv;
#pragma unroll
            for (int e = 0; e < 4; ++e) {
                hv[e] = f2h(areg[j][0][e]);
                hv[e + 4] = f2h(areg[j][1][e]);
            }
            const int pos = (l & 7) ^ (r & 7);
            *(us8*)&lds[buf + r * 64 + pos * 8] = hv;
        }
    };

    const int nt = K / 64;
    // prologue: fill buffer 0
    if constexpr (AF32) {
        loadA32(0);
        writeA32(0);
    } else {
        stageA16(0, 0);
    }
    stageB(0, 0);

    for (int t = 0; t < nt; ++t) {
        const int cur = (t & 1) * BUF;
        const int nxt = BUF - cur;
        __syncthreads();  // drains stage(t); protects buffer reuse
        const bool more = (t + 1 < nt);
        if (more) {
            if constexpr (AF32) loadA32((t + 1) * 64);
            else stageA16(nxt, (t + 1) * 64);
            stageB(nxt, (t + 1) * 64);
        }

#pragma unroll
        for (int kh = 0; kh < 2; ++kh) {
            half8 aa[4], bb[4];
            const int q = kh * 4 + c0;
#pragma unroll
            for (int mi = 0; mi < 4; ++mi) {
                const int r = w * 64 + mi * 16 + (l & 15);
                const int off = cur + r * 64 + ((q ^ (l & 7)) * 8);
                aa[mi] = __builtin_bit_cast(half8, *(const short8*)&lds[off]);
            }
#pragma unroll
            for (int ni = 0; ni < 4; ++ni) {
                const int r = ni * 16 + (l & 15);
                const int off = cur + 16384 + r * 64 + ((q ^ (l & 7)) * 8);
                bb[ni] = __builtin_bit_cast(half8, *(const short8*)&lds[off]);
            }
#pragma unroll
            for (int mi = 0; mi < 4; ++mi)
#pragma unroll
                for (int ni = 0; ni < 4; ++ni)
                    acc[mi][ni] = __builtin_amdgcn_mfma_f32_16x16x32_f16(
                        aa[mi], bb[ni], acc[mi][ni], 0, 0, 0);
        }

        if constexpr (AF32) {
            if (more) writeA32(nxt);  // write-late: after MFMA, before barrier
        }
    }
    // last compute read buf1; epilogue writes buf0 region (disjoint) — safe.

    // acc(+bias) -> LDS x[t][h] f16, stride 66 (odd-dword: bank-spread)
    float bv[4];
#pragma unroll
    for (int ni = 0; ni < 4; ++ni) bv[ni] = bias[n0 + ni * 16 + (l & 15)];
#pragma unroll
    for (int mi = 0; mi < 4; ++mi) {
        const int t0 = w * 64 + mi * 16 + ((l >> 4) << 2);
#pragma unroll
        for (int ni = 0; ni < 4; ++ni) {
            const int h = ni * 16 + (l & 15);
#pragma unroll
            for (int r = 0; r < 4; ++r)
                lds[(t0 + r) * 66 + h] = f2h(acc[mi][ni][r] + bv[ni]);
        }
    }
    __syncthreads();

    // scan: threads 0..63 each own one h column; snntorch Leaky subtract
    if (tid < 64) {
        const int h = tid;
        ushort_t* sp = Sout + (size_t)m0 * 512 + n0 + h;
        float m = 0.f;
#pragma unroll 4
        for (int t = 0; t < T_; ++t) {
            const float xv = h2f(lds[t * 66 + h]);
            const float r = (m - THR > 0.f) ? THR : 0.f;
            m = BETA * m + xv - r;
            sp[(size_t)t * 512] = (m - THR > 0.f) ? (ushort_t)0x3C00 : (ushort_t)0;
        }
    }
}

// ---------------------------------------------------------------------------
// f16 MFMA GEMM, BK=64, 2-phase double-buffered, fused MIL head epilogue:
// p = relu(C+bias) dot u over this wave's 64-col strip -> part[strip][row].
// Tile 128x128, 4 waves (2x2). Grid (4, 128) = 512 wgs, m-grouped XCD map.
// LDS 64KB = 2 x 16384 ushorts (A 16 + B 16 segs per buffer); 2 blocks/CU.
// ---------------------------------------------------------------------------
__global__ __launch_bounds__(256) void gemm_mil(
    const ushort_t* __restrict__ Ap, const ushort_t* __restrict__ Bp,
    const float* __restrict__ bias, const float* __restrict__ Uv,
    float* __restrict__ part, int N, int K) {
    constexpr int BUF = 16384;  // ushorts per buffer (32KB)
    __shared__ ushort_t lds[2 * BUF];

    const int tid = threadIdx.x;
    const int w = tid >> 6, l = tid & 63;
    const int flat = blockIdx.y * gridDim.x + blockIdx.x;
    const int mt = ((flat >> 5) << 3) | (flat & 7);
    const int st = (flat >> 3) & 3;
    const int n0 = st * 128;
    const int m0 = mt * 128;
    const int wr = w >> 1, wc = w & 1;

    f32x4 acc[4][4];
#pragma unroll
    for (int mi = 0; mi < 4; ++mi)
#pragma unroll
        for (int ni = 0; ni < 4; ++ni) acc[mi][ni] = (f32x4){0.f, 0.f, 0.f, 0.f};

    const int c0 = l >> 4;
    const int schunk = (l & 7) ^ ((l >> 3) & 7);

    auto stage = [&](int buf, int k0) {
#pragma unroll
        for (int j = 0; j < 8; ++j) {
            const int g = w * 8 + j;  // 0..31
            const int seg = g & 15;
            const int r = seg * 8 + (l >> 3);
            const ushort_t* pl = (g < 16) ? Ap : Bp;
            const int rb = (g < 16) ? m0 : n0;
            GLDS(pl + (size_t)(rb + r) * K + k0 + schunk * 8,
                 &lds[buf + g * 512]);
        }
    };

    const int nt = K / 64;
    stage(0, 0);
    for (int t = 0; t < nt; ++t) {
        const int cur = (t & 1) * BUF;
        const int nxt = BUF - cur;
        __syncthreads();
        if (t + 1 < nt) stage(nxt, (t + 1) * 64);

#pragma unroll
        for (int kh = 0; kh < 2; ++kh) {
            half8 aa[4], bb[4];
            const int q = kh * 4 + c0;
#pragma unroll
            for (int mi = 0; mi < 4; ++mi) {
                const int r = wr * 64 + mi * 16 + (l & 15);
                const int off = cur + r * 64 + ((q ^ (l & 7)) * 8);
                aa[mi] = __builtin_bit_cast(half8, *(const short8*)&lds[off]);
            }
#pragma unroll
            for (int ni = 0; ni < 4; ++ni) {
                const int r = wc * 64 + ni * 16 + (l & 15);
                const int off = cur + 8192 + r * 64 + ((q ^ (l & 7)) * 8);
                bb[ni] = __builtin_bit_cast(half8, *(const short8*)&lds[off]);
            }
#pragma unroll
            for (int mi = 0; mi < 4; ++mi)
#pragma unroll
                for (int ni = 0; ni < 4; ++ni)
                    acc[mi][ni] = __builtin_amdgcn_mfma_f32_16x16x32_f16(
                        aa[mi], bb[ni], acc[mi][ni], 0, 0, 0);
        }
    }

    // fused MIL: per row partial = sum_col relu(acc+bias)*u[col]
    float bv[4], uc[4];
#pragma unroll
    for (int ni = 0; ni < 4; ++ni) {
        const int col = n0 + wc * 64 + ni * 16 + (l & 15);
        bv[ni] = bias[col];
        uc[ni] = Uv[col];
    }
    const int strip = (n0 >> 6) + wc;  // 0..7
#pragma unroll
    for (int mi = 0; mi < 4; ++mi) {
        float p[4];
#pragma unroll
        for (int r = 0; r < 4; ++r) {
            float s = 0.f;
#pragma unroll
            for (int ni = 0; ni < 4; ++ni)
                s += fmaxf(acc[mi][ni][r] + bv[ni], 0.f) * uc[ni];
            p[r] = s;
        }
#pragma unroll
        for (int off = 1; off <= 8; off <<= 1)
#pragma unroll
            for (int r = 0; r < 4; ++r) p[r] += __shfl_xor(p[r], off);
        if ((l & 15) == 0) {
            const int row0 = m0 + wr * 64 + mi * 16 + ((l >> 4) << 2);
#pragma unroll
            for (int r = 0; r < 4; ++r)
                part[(size_t)strip * M_ + row0 + r] = p[r];
        }
    }
}

// ---------------------------------------------------------------------------
// Split-bf16 3-product GEMM (m97 structure, BK=32) — only for Wc = W1 @ Wf.
// Emits single f16 plane.
// ---------------------------------------------------------------------------
__global__ __launch_bounds__(256) void gemm_bf16_wc(
    const ushort_t* __restrict__ Ah, const ushort_t* __restrict__ Al,
    const ushort_t* __restrict__ Bh, const ushort_t* __restrict__ Bl,
    ushort_t* __restrict__ Cout, int N, int K) {
    __shared__ ushort_t lds[4 * 4096];

    const int tid = threadIdx.x;
    const int w = tid >> 6, l = tid & 63;
    const int nwg = gridDim.x * gridDim.y;
    const int flat = blockIdx.y * gridDim.x + blockIdx.x;
    const int wg = (flat & 7) * (nwg >> 3) + (flat >> 3);
    const int n0 = (wg % gridDim.x) * 128;
    const int m0 = (wg / gridDim.x) * 128;
    const int wr = w >> 1, wc = w & 1;

    f32x4 acc[4][4];
#pragma unroll
    for (int mi = 0; mi < 4; ++mi)
#pragma unroll
        for (int ni = 0; ni < 4; ++ni) acc[mi][ni] = (f32x4){0.f, 0.f, 0.f, 0.f};

    const int c0 = l >> 4;
    for (int k0 = 0; k0 < K; k0 += 32) {
        __syncthreads();
#pragma unroll
        for (int j = 0; j < 8; ++j) {
            const int g = w * 8 + j;
            const int p = g >> 3, seg = g & 7;
            const int r = seg * 16 + (l >> 2);
            const int ch = (l & 3) ^ swz(r);
            const ushort_t* pl = (p == 0) ? Ah : (p == 1) ? Al : (p == 2) ? Bh : Bl;
            const int rb = (p < 2) ? m0 : n0;
            GLDS(pl + (size_t)(rb + r) * K + k0 + ch * 8,
                 &lds[p * 4096 + seg * 512]);
        }
        __syncthreads();

        short8 ah[4], al[4], bh[4], bl[4];
#pragma unroll
        for (int mi = 0; mi < 4; ++mi) {
            const int r = wr * 64 + mi * 16 + (l & 15);
            const int off = r * 32 + ((c0 ^ swz(r)) * 8);
            ah[mi] = *(const short8*)&lds[off];
            al[mi] = *(const short8*)&lds[4096 + off];
        }
#pragma unroll
        for (int ni = 0; ni < 4; ++ni) {
            const int r = wc * 64 + ni * 16 + (l & 15);
            const int off = r * 32 + ((c0 ^ swz(r)) * 8);
            bh[ni] = *(const short8*)&lds[8192 + off];
            bl[ni] = *(const short8*)&lds[12288 + off];
        }
#pragma unroll
        for (int mi = 0; mi < 4; ++mi)
#pragma unroll
            for (int ni = 0; ni < 4; ++ni) {
                acc[mi][ni] = __builtin_amdgcn_mfma_f32_16x16x32_bf16(
                    ah[mi], bh[ni], acc[mi][ni], 0, 0, 0);
                acc[mi][ni] = __builtin_amdgcn_mfma_f32_16x16x32_bf16(
                    ah[mi], bl[ni], acc[mi][ni], 0, 0, 0);
                acc[mi][ni] = __builtin_amdgcn_mfma_f32_16x16x32_bf16(
                    al[mi], bh[ni], acc[mi][ni], 0, 0, 0);
            }
    }

#pragma unroll
    for (int ni = 0; ni < 4; ++ni) {
        const int col = n0 + wc * 64 + ni * 16 + (l & 15);
#pragma unroll
        for (int mi = 0; mi < 4; ++mi) {
            const int row0 = m0 + wr * 64 + mi * 16 + ((l >> 4) << 2);
#pragma unroll
            for (int r = 0; r < 4; ++r)
                Cout[(size_t)(row0 + r) * N + col] = f2h(acc[mi][ni][r]);
        }
    }
}

// ---------------------------------------------------------------------------
// Sectioned prep (one launch, 1410 blocks):
//   [0,256):      W1 -> bf16 hi/lo planes
//   [256,512):    W2 -> f16
//   [512,768):    Mw1 -> f16
//   [768,896):    bc[j] = b1[j] + W1[j,:]@bf  (wave per j)
//   [896,898):    u[j] = Mw3@Mw2[:,j]; uc[512] = Mw3@Mb2+Mb3
//   [898,1410):   Wf -> WfT bf16 hi/lo planes (32x32 transpose tiles)
// (f_f conversion now fused into gemm_scan<1>.)
// ---------------------------------------------------------------------------
__global__ __launch_bounds__(256) void prep_small(
    const float* __restrict__ W1, const float* __restrict__ W2,
    const float* __restrict__ Mw1, const float* __restrict__ bfv,
    const float* __restrict__ b1, const float* __restrict__ Mw2,
    const float* __restrict__ Mb2, const float* __restrict__ Mw3,
    const float* __restrict__ Mb3, const float* __restrict__ Wf,
    ushort_t* __restrict__ w1h, ushort_t* __restrict__ w1l,
    ushort_t* __restrict__ w2f, ushort_t* __restrict__ m1f,
    float* __restrict__ bc, float* __restrict__ uc,
    ushort_t* __restrict__ wfTh, ushort_t* __restrict__ wfTl) {
    __shared__ float tile[32][33];
    const int blk = blockIdx.x;
    const int tid = threadIdx.x;
    if (blk < 256) {
        const int i = blk * 256 + tid;
        f32x4 v = ((const f32x4*)W1)[i];
        us4 h, ll;
#pragma unroll
        for (int e = 0; e < 4; ++e) {
            const unsigned short hb = f2bf(v[e]);
            h[e] = hb;
            ll[e] = f2bf(v[e] - bf2f(hb));
        }
        ((us4*)w1h)[i] = h;
        ((us4*)w1l)[i] = ll;
    } else if (blk < 512) {
        const int i = (blk - 256) * 256 + tid;
        f32x4 v = ((const f32x4*)W2)[i];
        us4 h;
#pragma unroll
        for (int e = 0; e < 4; ++e) h[e] = f2h(v[e]);
        ((us4*)w2f)[i] = h;
    } else if (blk < 768) {
        const int i = (blk - 512) * 256 + tid;
        f32x4 v = ((const f32x4*)Mw1)[i];
        us4 h;
#pragma unroll
        for (int e = 0; e < 4; ++e) h[e] = f2h(v[e]);
        ((us4*)m1f)[i] = h;
    } else if (blk < 896) {
        const int w = tid >> 6, l = tid & 63;
        const int j = (blk - 768) * 4 + w;
        const float* row = W1 + (size_t)j * 512;
        float a = 0.f;
#pragma unroll
        for (int i = 0; i < 8; ++i) a += row[l + i * 64] * bfv[l + i * 64];
#pragma unroll
        for (int off = 32; off >= 1; off >>= 1) a += __shfl_xor(a, off);
        if (l == 0) bc[j] = a + b1[j];
    } else if (blk < 898) {
        const int j = (blk - 896) * 256 + tid;  // 0..511
        float a = 0.f;
        for (int i = 0; i < 32; ++i) a += Mw3[i] * Mw2[(size_t)i * 512 + j];
        uc[j] = a;
        if (j == 0) {
            float c = Mb3[0];
            for (int i = 0; i < 32; ++i) c += Mw3[i] * Mb2[i];
            uc[512] = c;
        }
    } else {
        const int idx = blk - 898;          // 0..511
        const int k0 = (idx & 31) * 32;     // Wf col tile
        const int i0 = (idx >> 5) * 32;     // Wf row tile
        const int tx = tid & 31;
        const int ty = tid >> 5;  // 0..7
#pragma unroll
        for (int e = 0; e < 4; ++e) {
            const int i = ty + e * 8;
            tile[i][tx] = Wf[(size_t)(i0 + i) * 1024 + k0 + tx];
        }
        __syncthreads();
#pragma unroll
        for (int e = 0; e < 4; ++e) {
            const int kk = ty + e * 8;
            const float v = tile[tx][kk];
            const unsigned short h = f2bf(v);
            wfTh[(size_t)(k0 + kk) * 512 + i0 + tx] = h;
            wfTl[(size_t)(k0 + kk) * 512 + i0 + tx] = f2bf(v - bf2f(h));
        }
    }
}

// ---------------------------------------------------------------------------
// Tail: pre[row] = sum_{s<8} part[s][row] + c; top-17 on pre (sigmoid
// monotonic), mean of sigmoid(selected). One wave per clip.
// ---------------------------------------------------------------------------
__global__ __launch_bounds__(64) void tail_topk(const float* __restrict__ part,
                                                const float* __restrict__ uc,
                                                float* __restrict__ out) {
    const int b = blockIdx.x;
    const int lane = threadIdx.x;
    const float c = uc[512];
    float v[4];
#pragma unroll
    for (int i = 0; i < 4; ++i) {
        const int row = b * T_ + lane + i * 64;
        float a = 0.f;
#pragma unroll
        for (int s = 0; s < 8; ++s) a += part[(size_t)s * M_ + row];
        v[i] = a + c;
    }
    float sum = 0.f;
    for (int iter = 0; iter < 17; ++iter) {
        float mv = v[0];
        int mslot = 0;
#pragma unroll
        for (int i = 1; i < 4; ++i)
            if (v[i] > mv) { mv = v[i]; mslot = i; }
        float bv = mv;
        int bl = lane, bs = mslot;
#pragma unroll
        for (int off = 32; off >= 1; off >>= 1) {
            const float ov = __shfl_xor(bv, off);
            const int ol = __shfl_xor(bl, off);
            const int os = __shfl_xor(bs, off);
            if (ov > bv || (ov == bv && ol < bl)) { bv = ov; bl = ol; bs = os; }
        }
        sum += 1.f / (1.f + expf(-bv));
        if (lane == bl) v[bs] = -1e30f;
    }
    if (lane == 0) out[b] = sum * (1.f / 17.f);
}

// ---------------------------------------------------------------------------
// Orchestration (6 launches):
//   prep_small (weights + Wf transpose)
//   wcf   <- gemm_bf16_wc(W1 planes @ WfT^T)
//   sbuf1 <- gemm_scan<1>(f_f(f32) @ wcf^T + bc)  [x1 + scan1, in-kernel cvt]
//   sbuf2 <- gemm_scan<0>(sbuf1 @ w2f^T + b2)     [x2 + scan2]
//   part  <- gemm_mil(sbuf2 @ m1f^T + Mb1)        [MIL fused]
//   out   <- tail_topk(part)
// ---------------------------------------------------------------------------
extern "C" void kernel_launch(void* const* d_in, const int* in_sizes, int n_in,
                              void* d_out, int out_size, void* d_ws, size_t ws_size,
                              hipStream_t stream) {
    const float* f_f = (const float*)d_in[0];
    const float* Wf  = (const float*)d_in[2];
    const float* bf  = (const float*)d_in[3];
    const float* W1  = (const float*)d_in[4];
    const float* b1  = (const float*)d_in[5];
    const float* W2  = (const float*)d_in[6];
    const float* b2  = (const float*)d_in[7];
    const float* Mw1 = (const float*)d_in[8];
    const float* Mb1 = (const float*)d_in[9];
    const float* Mw2 = (const float*)d_in[10];
    const float* Mb2 = (const float*)d_in[11];
    const float* Mw3 = (const float*)d_in[12];
    const float* Mb3 = (const float*)d_in[13];
    float* out = (float*)d_out;

    char* ws = (char*)d_ws;
    const size_t NE = (size_t)M_ * H_;   // 8.39M elems
    ushort_t* sbuf1 = (ushort_t*)ws;                     // f16 spikes 1
    ushort_t* sbuf2 = sbuf1 + NE;                        // f16 spikes 2
    ushort_t* w1h = sbuf2 + NE;                          // bf16 (wc input)
    ushort_t* w1l = w1h + 262144;
    ushort_t* w2f = w1l + 262144;                        // f16 single
    ushort_t* m1f = w2f + 262144;                        // f16 single
    ushort_t* wfTh = m1f + 262144;                       // bf16 [1024,512]
    ushort_t* wfTl = wfTh + 524288;
    ushort_t* wcf = wfTl + 524288;                       // f16 [512,1024]
    float* bc = (float*)(wcf + 524288);
    float* uc = bc + 512;                                // u[512] + c
    float* part = uc + 513 + 63;                         // [8][16384] f32

    const dim3 blk(256);

    prep_small<<<dim3(1410), blk, 0, stream>>>(W1, W2, Mw1, bf, b1, Mw2, Mb2,
                                               Mw3, Mb3, Wf, w1h, w1l, w2f,
                                               m1f, bc, uc, wfTh, wfTl);

    // Wc = W1 @ Wf -> f16 [512,1024]
    gemm_bf16_wc<<<dim3(8, 4), blk, 0, stream>>>(w1h, w1l, wfTh, wfTl, wcf,
                                                 1024, 512);
    // x1 = f_f @ Wc^T + bc, fused scan1 -> sbuf1 (f32 A, in-kernel convert)
    gemm_scan<1><<<dim3(8, 64), blk, 0, stream>>>(f_f, wcf, bc, sbuf1, 1024);
    // x2 = sbuf1 @ W2^T + b2, fused scan2 -> sbuf2
    gemm_scan<0><<<dim3(8, 64), blk, 0, stream>>>(sbuf1, w2f, b2, sbuf2, 512);
    // z-GEMM with fused MIL head -> part[8][M]
    gemm_mil<<<dim3(4, 128), blk, 0, stream>>>(sbuf2, m1f, Mb1, uc, part,
                                               512, 512);
    tail_topk<<<dim3(B_), dim3(64), 0, stream>>>(part, uc, out);
}